// Round 7
// baseline (449.914 us; speedup 1.0000x reference)
//
#include <hip/hip_runtime.h>
#include <cmath>

typedef __bf16 bf16;
typedef __bf16 bf16x8 __attribute__((ext_vector_type(8)));
typedef __bf16 bf16x4 __attribute__((ext_vector_type(4)));
typedef float  f32x4  __attribute__((ext_vector_type(4)));
typedef unsigned int u32x4 __attribute__((ext_vector_type(4)));

#define MFMA16(a, b, c) __builtin_amdgcn_mfma_f32_16x16x32_bf16((a), (b), (c), 0, 0, 0)
#define LOG2E 1.44269504088896f

static __device__ __forceinline__ void gl_lds16(const void* g, void* l) {
    __builtin_amdgcn_global_load_lds((const __attribute__((address_space(1))) void*)g,
                                     (__attribute__((address_space(3))) void*)l, 16, 0, 0);
}

static __device__ __forceinline__ bf16x8 bneg8(bf16x8 x) {
    u32x4 u = __builtin_bit_cast(u32x4, x);
    u = u ^ 0x80008000u;
    return __builtin_bit_cast(bf16x8, u);
}

static __device__ __forceinline__ f32x4 zero4() {
    return f32x4{0.0f, 0.0f, 0.0f, 0.0f};
}

// ---------------------------------------------------------------------------
// small utility kernels
// ---------------------------------------------------------------------------
__global__ void fill_kernel(float* p, float v, int n) {
    for (int i = blockIdx.x * blockDim.x + threadIdx.x; i < n; i += gridDim.x * blockDim.x)
        p[i] = v;
}

// fused 8-way f32 -> bf16 weight conversion (all sizes % 1024 == 0)
struct Cvt8 {
    const float* s[8];
    bf16* d[8];
    int boff[9];
};
__global__ __launch_bounds__(256) void cvt8_kernel(Cvt8 c) {
    int blk = blockIdx.x;
    int seg = 0;
#pragma unroll
    for (int k = 0; k < 7; ++k)
        if (blk >= c.boff[k + 1]) seg = k + 1;
    const int local = blk - c.boff[seg];
    const int i = local * 1024 + threadIdx.x * 4;
    const float4 v = *(const float4*)(c.s[seg] + i);
    bf16x4 o;
    o[0] = (bf16)v.x; o[1] = (bf16)v.y; o[2] = (bf16)v.z; o[3] = (bf16)v.w;
    *(bf16x4*)(c.d[seg] + i) = o;
}

// ---------------------------------------------------------------------------
// complex magnitude layernorm. ILV=true: xa is interleaved float2 [row][768][2]
// ---------------------------------------------------------------------------
template <bool ILV>
__global__ __launch_bounds__(256) void cln_kernel(
    const float* __restrict__ xa, const float* __restrict__ xb,
    const float* __restrict__ gamma, const float* __restrict__ beta,
    bf16* __restrict__ nr, bf16* __restrict__ ni) {
    __shared__ float red[4];
    const int t = threadIdx.x;
    const size_t base = (size_t)blockIdx.x * 768;

    float r[3], im[3], mg[3];
#pragma unroll
    for (int j = 0; j < 3; ++j) {
        const int f = t + j * 256;
        if (ILV) {
            const float2 v = ((const float2*)xa)[base + f];
            r[j] = v.x;
            im[j] = v.y;
        } else {
            r[j] = xa[base + f];
            im[j] = xb[base + f];
        }
        mg[j] = __builtin_amdgcn_sqrtf(r[j] * r[j] + im[j] * im[j] + 1e-6f);
    }
    float s = mg[0] + mg[1] + mg[2];
#pragma unroll
    for (int m = 32; m >= 1; m >>= 1) s += __shfl_xor(s, m);
    if ((t & 63) == 0) red[t >> 6] = s;
    __syncthreads();
    const float mean = (red[0] + red[1] + red[2] + red[3]) * (1.0f / 768.0f);
    __syncthreads();

    float v2 = 0.0f;
#pragma unroll
    for (int j = 0; j < 3; ++j) {
        const float d = mg[j] - mean;
        v2 += d * d;
    }
#pragma unroll
    for (int m = 32; m >= 1; m >>= 1) v2 += __shfl_xor(v2, m);
    if ((t & 63) == 0) red[t >> 6] = v2;
    __syncthreads();
    const float var = (red[0] + red[1] + red[2] + red[3]) * (1.0f / 768.0f);
    const float rstd = rsqrtf(var + 1e-6f);

#pragma unroll
    for (int j = 0; j < 3; ++j) {
        const int f = t + j * 256;
        const float sc = (mg[j] - mean) * rstd / (mg[j] + 1e-6f);
        nr[base + f] = (bf16)(gamma[2 * f] * (r[j] * sc) + beta[2 * f]);
        ni[base + f] = (bf16)(gamma[2 * f + 1] * (im[j] * sc) + beta[2 * f + 1]);
    }
}

// ---------------------------------------------------------------------------
// complex GEMM (NT), tile-parametrized (BM x BN), global_load_lds staging,
// XCD-aware block swizzle. 4 waves in 2x2; per-wave sub-tile (BM/2)x(BN/2).
// ---------------------------------------------------------------------------
template <int BM, int BN, int MODE, int OCC>
__global__ __launch_bounds__(256, OCC) void cgemm_kernel(
    const bf16* __restrict__ Ar, const bf16* __restrict__ Ai,
    const bf16* __restrict__ Wr, const bf16* __restrict__ Wi,
    const float* __restrict__ br, const float* __restrict__ bi,
    const float* __restrict__ resr, const float* __restrict__ resi,
    float* __restrict__ outFr, float* __restrict__ outFi,
    bf16* __restrict__ outBr, bf16* __restrict__ outBi,
    int N, int K) {
    constexpr int MR = BM / 32;  // fragment rows per wave
    constexpr int NR = BN / 32;  // fragment cols per wave
    constexpr int SEGS_A = BM / 16;
    constexpr int SEGS_B = BN / 16;
    constexpr int SEGS_PW = (2 * SEGS_A + 2 * SEGS_B) / 4;  // per wave

    __shared__ bf16 sAr[BM][32];
    __shared__ bf16 sAi[BM][32];
    __shared__ bf16 sBr[BN][32];
    __shared__ bf16 sBi[BN][32];

    const int tid = threadIdx.x;
    const int wave = tid >> 6, lane = tid & 63;
    const int lg = lane >> 4, lr = lane & 15;

    const int nwgx = gridDim.x;
    int wg = blockIdx.y * nwgx + blockIdx.x;
    const int cpx = (nwgx * gridDim.y) >> 3;
    wg = (wg & 7) * cpx + (wg >> 3);
    const int row0 = (wg % nwgx) * BM, col0 = (wg / nwgx) * BN;

    const int wm = (wave >> 1) * (BM / 2), wn = (wave & 1) * (BN / 2);
    const int srow = lane >> 2;
    const int sc8 = (lane & 3) * 8;

    f32x4 accr[MR][NR], acci[MR][NR];
#pragma unroll
    for (int a = 0; a < MR; ++a)
#pragma unroll
        for (int b2 = 0; b2 < NR; ++b2) {
            accr[a][b2] = zero4();
            acci[a][b2] = zero4();
        }

    for (int kt = 0; kt < K; kt += 32) {
        __syncthreads();
#pragma unroll
        for (int s = 0; s < SEGS_PW; ++s) {
            const int id = wave * SEGS_PW + s;
            if (id < SEGS_A) {
                const int row = id * 16 + srow;
                gl_lds16(Ar + (size_t)(row0 + row) * K + kt + sc8, &sAr[id * 16][0]);
            } else if (id < 2 * SEGS_A) {
                const int row = (id - SEGS_A) * 16 + srow;
                gl_lds16(Ai + (size_t)(row0 + row) * K + kt + sc8,
                         &sAi[(id - SEGS_A) * 16][0]);
            } else if (id < 2 * SEGS_A + SEGS_B) {
                const int row = (id - 2 * SEGS_A) * 16 + srow;
                gl_lds16(Wr + (size_t)(col0 + row) * K + kt + sc8,
                         &sBr[(id - 2 * SEGS_A) * 16][0]);
            } else {
                const int row = (id - 2 * SEGS_A - SEGS_B) * 16 + srow;
                gl_lds16(Wi + (size_t)(col0 + row) * K + kt + sc8,
                         &sBi[(id - 2 * SEGS_A - SEGS_B) * 16][0]);
            }
        }
        __syncthreads();

        bf16x8 ar[MR], ai[MR], an[MR];
#pragma unroll
        for (int mt = 0; mt < MR; ++mt) {
            ar[mt] = *(const bf16x8*)(&sAr[wm + mt * 16 + lr][lg * 8]);
            ai[mt] = *(const bf16x8*)(&sAi[wm + mt * 16 + lr][lg * 8]);
            an[mt] = bneg8(ai[mt]);
        }
#pragma unroll
        for (int nt = 0; nt < NR; ++nt) {
            const bf16x8 br8 = *(const bf16x8*)(&sBr[wn + nt * 16 + lr][lg * 8]);
            const bf16x8 bi8 = *(const bf16x8*)(&sBi[wn + nt * 16 + lr][lg * 8]);
#pragma unroll
            for (int mt = 0; mt < MR; ++mt) {
                accr[mt][nt] = MFMA16(ar[mt], br8, accr[mt][nt]);
                accr[mt][nt] = MFMA16(an[mt], bi8, accr[mt][nt]);
                acci[mt][nt] = MFMA16(ar[mt], bi8, acci[mt][nt]);
                acci[mt][nt] = MFMA16(ai[mt], br8, acci[mt][nt]);
            }
        }
    }

#pragma unroll
    for (int nt = 0; nt < NR; ++nt) {
        const int col = col0 + wn + nt * 16 + lr;
        const float bre = br[col], bie = bi[col];
#pragma unroll
        for (int mt = 0; mt < MR; ++mt) {
#pragma unroll
            for (int j = 0; j < 4; ++j) {
                const int row = row0 + wm + mt * 16 + lg * 4 + j;
                float vr = accr[mt][nt][j] + bre;
                float vi = acci[mt][nt][j] + bie;
                const size_t o = (size_t)row * N + col;
                if (MODE == 0) {
                    outBr[o] = (bf16)vr;
                    outBi[o] = (bf16)vi;
                } else if (MODE == 1) {
                    const float2 rv = ((const float2*)resr)[(size_t)row * 768 + col];
                    outFr[o] = rv.x + vr;
                    outFi[o] = rv.y + vi;
                } else if (MODE == 2) {
                    vr = 0.5f * vr * (1.0f + erff(vr * 0.70710678118654752f));
                    vi = 0.5f * vi * (1.0f + erff(vi * 0.70710678118654752f));
                    outBr[o] = (bf16)vr;
                    outBi[o] = (bf16)vi;
                } else {
                    const size_t ro = (size_t)row * 768 + col;
                    outFr[(size_t)row * 1536 + 2 * col]     = resr[ro] + vr;
                    outFr[(size_t)row * 1536 + 2 * col + 1] = resi[ro] + vi;
                }
            }
        }
    }
}

// ---------------------------------------------------------------------------
// transpose V slice of qkv into [B*nH][64 d][2048 n] bf16 planes
// ---------------------------------------------------------------------------
__global__ __launch_bounds__(256) void vtrans_kernel(
    const bf16* __restrict__ qkvr, const bf16* __restrict__ qkvi,
    bf16* __restrict__ vtr, bf16* __restrict__ vti) {
    __shared__ bf16 sr[64][65];
    __shared__ bf16 si[64][65];
    const int t = threadIdx.x;
    const int nb = blockIdx.x, h = blockIdx.y, b = blockIdx.z;
    const size_t ld = 2304;
    const bf16* srcr = qkvr + (size_t)(b * 2048 + nb * 64) * ld + 1536 + h * 64;
    const bf16* srci = qkvi + (size_t)(b * 2048 + nb * 64) * ld + 1536 + h * 64;
#pragma unroll
    for (int j = 0; j < 16; ++j) {
        const int idx = t + 256 * j;
        const int n = idx >> 6, d = idx & 63;
        sr[n][d] = srcr[(size_t)n * ld + d];
        si[n][d] = srci[(size_t)n * ld + d];
    }
    __syncthreads();
    bf16* dstr = vtr + (size_t)(b * 12 + h) * 64 * 2048 + nb * 64;
    bf16* dsti = vti + (size_t)(b * 12 + h) * 64 * 2048 + nb * 64;
#pragma unroll
    for (int j = 0; j < 16; ++j) {
        const int idx = t + 256 * j;
        const int d = idx >> 6, n = idx & 63;
        dstr[(size_t)d * 2048 + n] = sr[n][d];
        dsti[(size_t)d * 2048 + n] = si[n][d];
    }
}

// ---------------------------------------------------------------------------
// fused complex flash attention (unchanged from R6: 133 us, passed)
// ---------------------------------------------------------------------------
__global__ __launch_bounds__(256, 3) void cattn_kernel(
    const bf16* __restrict__ qkvr, const bf16* __restrict__ qkvi,
    const bf16* __restrict__ vtr, const bf16* __restrict__ vti,
    bf16* __restrict__ aor, bf16* __restrict__ aoi) {
    __shared__ __align__(16) bf16 sK[2][2][32][64];
    __shared__ __align__(16) bf16 sV[2][64][64];
    __shared__ __align__(16) bf16 sP[4][16][40];

    const int tid = threadIdx.x;
    const int w = tid >> 6, lane = tid & 63;
    const int lg = lane >> 4, lr = lane & 15;
    const int qb = blockIdx.x, h = blockIdx.y, b = blockIdx.z;
    const int ld = 2304;

    const int s_krow = lane >> 3;
    const int s_kch8 = ((lane & 7) ^ s_krow) * 8;
    const int s_vlog = (lane & 7) ^ s_krow;
    const int s_vpl = s_vlog >> 2;
    const int s_vk8 = (s_vlog & 3) * 8;

    const bf16* kbase0 = qkvr + (size_t)b * 2048 * ld + 768 + h * 64;
    const bf16* kbase1 = qkvi + (size_t)b * 2048 * ld + 768 + h * 64;
    const bf16* vbase0 = vtr + (size_t)(b * 12 + h) * 64 * 2048;
    const bf16* vbase1 = vti + (size_t)(b * 12 + h) * 64 * 2048;

    auto stage = [&](int buf, int kt) {
#pragma unroll
        for (int s = 0; s < 2; ++s) {
            const int seg = s * 4 + w;
            const int pl = seg >> 2, rg = seg & 3;
            gl_lds16((pl ? kbase1 : kbase0) +
                         (size_t)(kt * 32 + rg * 8 + s_krow) * ld + s_kch8,
                     &sK[buf][pl][rg * 8][0]);
            gl_lds16((s_vpl ? vbase1 : vbase0) +
                         (size_t)(seg * 8 + s_krow) * 2048 + kt * 32 + s_vk8,
                     &sV[buf][seg * 8][0]);
        }
    };

    stage(0, 0);

    const size_t qoff = (size_t)(b * 2048 + qb * 64 + w * 16 + lr) * ld + h * 64;
    bf16x8 aqr[2], aqi[2];
#pragma unroll
    for (int ks = 0; ks < 2; ++ks) {
        aqr[ks] = *(const bf16x8*)(qkvr + qoff + ks * 32 + lg * 8);
        aqi[ks] = *(const bf16x8*)(qkvi + qoff + ks * 32 + lg * 8);
    }

    f32x4 our[4], oui[4];
#pragma unroll
    for (int d = 0; d < 4; ++d) {
        our[d] = zero4();
        oui[d] = zero4();
    }
    float mrun = -1e30f, lrun = 0.0f;

    for (int kt = 0; kt < 64; ++kt) {
        const int cur = kt & 1;
        if (kt < 63) {
            stage(cur ^ 1, kt + 1);
            __builtin_amdgcn_sched_barrier(0);
            asm volatile("s_waitcnt vmcnt(4)" ::: "memory");
        } else {
            asm volatile("s_waitcnt vmcnt(0)" ::: "memory");
        }
        __builtin_amdgcn_sched_barrier(0);
        __builtin_amdgcn_s_barrier();
        __builtin_amdgcn_sched_barrier(0);

        f32x4 str[2], sti[2];
        str[0] = zero4(); str[1] = zero4();
        sti[0] = zero4(); sti[1] = zero4();
#pragma unroll
        for (int t = 0; t < 2; ++t) {
#pragma unroll
            for (int ks = 0; ks < 2; ++ks) {
                const int ch = ((ks << 2) | lg) ^ (lr & 7);
                const bf16x8 kr8 = *(const bf16x8*)(&sK[cur][0][t * 16 + lr][ch * 8]);
                const bf16x8 ki8 = *(const bf16x8*)(&sK[cur][1][t * 16 + lr][ch * 8]);
                const bf16x8 kn8 = bneg8(kr8);
                str[t] = MFMA16(kr8, aqr[ks], str[t]);
                str[t] = MFMA16(ki8, aqi[ks], str[t]);
                sti[t] = MFMA16(ki8, aqr[ks], sti[t]);
                sti[t] = MFMA16(kn8, aqi[ks], sti[t]);
            }
        }

        float p[8];
        float tmax = -1e30f;
#pragma unroll
        for (int t = 0; t < 2; ++t)
#pragma unroll
            for (int j = 0; j < 4; ++j) {
                const float sr = str[t][j], si = sti[t][j];
                const float m = __builtin_amdgcn_sqrtf(sr * sr + si * si + 1e-8f) * 0.125f;
                p[t * 4 + j] = m;
                tmax = fmaxf(tmax, m);
            }
        tmax = fmaxf(tmax, __shfl_xor(tmax, 16));
        tmax = fmaxf(tmax, __shfl_xor(tmax, 32));

        if (!__all(tmax <= mrun)) {
            const float mnew = fmaxf(mrun, tmax);
            const float corr = __builtin_amdgcn_exp2f((mrun - mnew) * LOG2E);
            float cj[4];
#pragma unroll
            for (int j = 0; j < 4; ++j) cj[j] = __shfl(corr, lg * 4 + j);
#pragma unroll
            for (int d = 0; d < 4; ++d)
#pragma unroll
                for (int j = 0; j < 4; ++j) {
                    our[d][j] *= cj[j];
                    oui[d][j] *= cj[j];
                }
            lrun *= corr;
            mrun = mnew;
        }

        float ls = 0.0f;
#pragma unroll
        for (int i = 0; i < 8; ++i) {
            p[i] = __builtin_amdgcn_exp2f((p[i] - mrun) * LOG2E);
            ls += p[i];
        }
        ls += __shfl_xor(ls, 16);
        ls += __shfl_xor(ls, 32);
        lrun += ls;

#pragma unroll
        for (int t = 0; t < 2; ++t) {
            bf16x4 pk;
#pragma unroll
            for (int j = 0; j < 4; ++j) pk[j] = (bf16)p[t * 4 + j];
            *(bf16x4*)(&sP[w][lr][t * 16 + lg * 4]) = pk;
        }
        const bf16x8 pf = *(const bf16x8*)(&sP[w][lr][lg * 8]);

#pragma unroll
        for (int d = 0; d < 4; ++d) {
            const int slr = lg ^ (lr & 7);
            const int sli = (4 + lg) ^ (lr & 7);
            const bf16x8 vr8 = *(const bf16x8*)(&sV[cur][d * 16 + lr][slr * 8]);
            const bf16x8 vi8 = *(const bf16x8*)(&sV[cur][d * 16 + lr][sli * 8]);
            our[d] = MFMA16(pf, vr8, our[d]);
            oui[d] = MFMA16(pf, vi8, oui[d]);
        }

        __builtin_amdgcn_sched_barrier(0);
        __builtin_amdgcn_s_barrier();
        __builtin_amdgcn_sched_barrier(0);
    }

    float linv[4];
#pragma unroll
    for (int j = 0; j < 4; ++j) {
        const float lj = __shfl(lrun, lg * 4 + j);
        linv[j] = __builtin_amdgcn_rcpf(lj);
    }
#pragma unroll
    for (int d = 0; d < 4; ++d)
#pragma unroll
        for (int j = 0; j < 4; ++j) {
            const int row = b * 2048 + qb * 64 + w * 16 + lg * 4 + j;
            const int col = h * 64 + d * 16 + lr;
            aor[(size_t)row * 768 + col] = (bf16)(our[d][j] * linv[j]);
            aoi[(size_t)row * 768 + col] = (bf16)(oui[d][j] * linv[j]);
        }
}

// ---------------------------------------------------------------------------
// host launch
// ---------------------------------------------------------------------------
extern "C" void kernel_launch(void* const* d_in, const int* in_sizes, int n_in,
                              void* d_out, int out_size, void* d_ws, size_t ws_size,
                              hipStream_t stream) {
    const float* x      = (const float*)d_in[0];
    const float* n1g    = (const float*)d_in[1];
    const float* n1b    = (const float*)d_in[2];
    const float* qkvwr  = (const float*)d_in[3];
    const float* qkvwi  = (const float*)d_in[4];
    const float* qkvbr  = (const float*)d_in[5];
    const float* qkvbi  = (const float*)d_in[6];
    const float* projwr = (const float*)d_in[7];
    const float* projwi = (const float*)d_in[8];
    const float* projbr = (const float*)d_in[9];
    const float* projbi = (const float*)d_in[10];
    const float* n2g    = (const float*)d_in[11];
    const float* n2b    = (const float*)d_in[12];
    const float* fc1wr  = (const float*)d_in[13];
    const float* fc1wi  = (const float*)d_in[14];
    const float* fc1br  = (const float*)d_in[15];
    const float* fc1bi  = (const float*)d_in[16];
    const float* fc2wr  = (const float*)d_in[17];
    const float* fc2wi  = (const float*)d_in[18];
    const float* fc2br  = (const float*)d_in[19];
    const float* fc2bi  = (const float*)d_in[20];

    const int M = 4096, E = 768, E3 = 2304, HH = 1536;

    char* base = (char*)d_ws;
    size_t off = 0;
    auto alloc = [&](size_t bytes) -> void* {
        void* p = base + off;
        off += (bytes + 255) & ~(size_t)255;
        return p;
    };
    float* xr2 = (float*)alloc((size_t)M * E * 4);
    float* xi2 = (float*)alloc((size_t)M * E * 4);
    bf16* nr   = (bf16*)alloc((size_t)M * E * 2);
    bf16* ni   = (bf16*)alloc((size_t)M * E * 2);
    bf16* wqr  = (bf16*)alloc((size_t)E3 * E * 2);
    bf16* wqi  = (bf16*)alloc((size_t)E3 * E * 2);
    bf16* wpr  = (bf16*)alloc((size_t)E * E * 2);
    bf16* wpi  = (bf16*)alloc((size_t)E * E * 2);
    bf16* w1r  = (bf16*)alloc((size_t)HH * E * 2);
    bf16* w1i  = (bf16*)alloc((size_t)HH * E * 2);
    bf16* w2r  = (bf16*)alloc((size_t)E * HH * 2);
    bf16* w2i  = (bf16*)alloc((size_t)E * HH * 2);
    bf16* qkr  = (bf16*)alloc((size_t)M * E3 * 2);
    bf16* qki  = (bf16*)alloc((size_t)M * E3 * 2);
    bf16* vtr  = (bf16*)alloc((size_t)24 * 64 * 2048 * 2);
    bf16* vti  = (bf16*)alloc((size_t)24 * 64 * 2048 * 2);
    bf16* aor  = (bf16*)alloc((size_t)M * E * 2);
    bf16* aoi  = (bf16*)alloc((size_t)M * E * 2);
    bf16* hr   = (bf16*)alloc((size_t)M * HH * 2);
    bf16* hi   = (bf16*)alloc((size_t)M * HH * 2);

    if (off > ws_size) {
        fill_kernel<<<1024, 256, 0, stream>>>((float*)d_out, 1.0e9f, out_size);
        return;
    }

    // fused weight conversion
    Cvt8 c;
    c.s[0] = qkvwr; c.d[0] = wqr;
    c.s[1] = qkvwi; c.d[1] = wqi;
    c.s[2] = projwr; c.d[2] = wpr;
    c.s[3] = projwi; c.d[3] = wpi;
    c.s[4] = fc1wr; c.d[4] = w1r;
    c.s[5] = fc1wi; c.d[5] = w1i;
    c.s[6] = fc2wr; c.d[6] = w2r;
    c.s[7] = fc2wi; c.d[7] = w2i;
    const int nseg[8] = {E3 * E, E3 * E, E * E, E * E, HH * E, HH * E, E * HH, E * HH};
    int cum = 0;
    for (int k = 0; k < 8; ++k) {
        c.boff[k] = cum;
        cum += nseg[k] / 1024;
    }
    c.boff[8] = cum;
    cvt8_kernel<<<cum, 256, 0, stream>>>(c);

    // LN1 (reads interleaved x directly)
    cln_kernel<true><<<M, 256, 0, stream>>>(x, nullptr, n1g, n1b, nr, ni);
    // QKV: 128x128 tiles, grid 576 (2.25/CU)
    cgemm_kernel<128, 128, 0, 2><<<dim3(32, 18), 256, 0, stream>>>(
        nr, ni, wqr, wqi, qkvbr, qkvbi, nullptr, nullptr, nullptr, nullptr,
        qkr, qki, E3, E);
    // V transpose
    vtrans_kernel<<<dim3(32, 12, 2), 256, 0, stream>>>(qkr, qki, vtr, vti);
    // attention (64 q-rows per block; 768 blocks = 3/CU exact)
    cattn_kernel<<<dim3(32, 12, 2), 256, 0, stream>>>(qkr, qki, vtr, vti, aor, aoi);
    // proj + interleaved-x residual: 64x64 tiles, grid 768 = 3/CU exact
    cgemm_kernel<64, 64, 1, 3><<<dim3(64, 12), 256, 0, stream>>>(
        aor, aoi, wpr, wpi, projbr, projbi, x, nullptr, xr2, xi2, nullptr, nullptr,
        E, E);
    // LN2
    cln_kernel<false><<<M, 256, 0, stream>>>(xr2, xi2, n2g, n2b, nr, ni);
    // FC1 + gelu: 64x128 tiles, grid 768 = 3/CU exact
    cgemm_kernel<64, 128, 2, 3><<<dim3(64, 12), 256, 0, stream>>>(
        nr, ni, w1r, w1i, fc1br, fc1bi, nullptr, nullptr, nullptr, nullptr,
        hr, hi, HH, E);
    // FC2 + residual -> interleaved d_out: 64x64 tiles, grid 768 = 3/CU exact
    cgemm_kernel<64, 64, 3, 3><<<dim3(64, 12), 256, 0, stream>>>(
        hr, hi, w2r, w2i, fc2br, fc2bi, xr2, xi2, (float*)d_out, nullptr,
        nullptr, nullptr, E, HH);
}

// Round 8
// 385.519 us; speedup vs baseline: 1.1670x; 1.1670x over previous
//
#include <hip/hip_runtime.h>
#include <cmath>

typedef __bf16 bf16;
typedef __bf16 bf16x8 __attribute__((ext_vector_type(8)));
typedef __bf16 bf16x4 __attribute__((ext_vector_type(4)));
typedef float  f32x4  __attribute__((ext_vector_type(4)));
typedef unsigned int u32x4 __attribute__((ext_vector_type(4)));

#define MFMA16(a, b, c) __builtin_amdgcn_mfma_f32_16x16x32_bf16((a), (b), (c), 0, 0, 0)
#define LOG2E 1.44269504088896f

static __device__ __forceinline__ void gl_lds16(const void* g, void* l) {
    __builtin_amdgcn_global_load_lds((const __attribute__((address_space(1))) void*)g,
                                     (__attribute__((address_space(3))) void*)l, 16, 0, 0);
}

static __device__ __forceinline__ bf16x8 bneg8(bf16x8 x) {
    u32x4 u = __builtin_bit_cast(u32x4, x);
    u = u ^ 0x80008000u;
    return __builtin_bit_cast(bf16x8, u);
}

static __device__ __forceinline__ f32x4 zero4() {
    return f32x4{0.0f, 0.0f, 0.0f, 0.0f};
}

// ---------------------------------------------------------------------------
// small utility kernels
// ---------------------------------------------------------------------------
__global__ void fill_kernel(float* p, float v, int n) {
    for (int i = blockIdx.x * blockDim.x + threadIdx.x; i < n; i += gridDim.x * blockDim.x)
        p[i] = v;
}

// fused 8-way f32 -> bf16 weight conversion (all sizes % 1024 == 0)
struct Cvt8 {
    const float* s[8];
    bf16* d[8];
    int boff[9];
};
__global__ __launch_bounds__(256) void cvt8_kernel(Cvt8 c) {
    int blk = blockIdx.x;
    int seg = 0;
#pragma unroll
    for (int k = 0; k < 7; ++k)
        if (blk >= c.boff[k + 1]) seg = k + 1;
    const int local = blk - c.boff[seg];
    const int i = local * 1024 + threadIdx.x * 4;
    const float4 v = *(const float4*)(c.s[seg] + i);
    bf16x4 o;
    o[0] = (bf16)v.x; o[1] = (bf16)v.y; o[2] = (bf16)v.z; o[3] = (bf16)v.w;
    *(bf16x4*)(c.d[seg] + i) = o;
}

// ---------------------------------------------------------------------------
// complex magnitude layernorm. ILV=true: xa is interleaved float2 [row][768][2]
// ---------------------------------------------------------------------------
template <bool ILV>
__global__ __launch_bounds__(256) void cln_kernel(
    const float* __restrict__ xa, const float* __restrict__ xb,
    const float* __restrict__ gamma, const float* __restrict__ beta,
    bf16* __restrict__ nr, bf16* __restrict__ ni) {
    __shared__ float red[4];
    const int t = threadIdx.x;
    const size_t base = (size_t)blockIdx.x * 768;

    float r[3], im[3], mg[3];
#pragma unroll
    for (int j = 0; j < 3; ++j) {
        const int f = t + j * 256;
        if (ILV) {
            const float2 v = ((const float2*)xa)[base + f];
            r[j] = v.x;
            im[j] = v.y;
        } else {
            r[j] = xa[base + f];
            im[j] = xb[base + f];
        }
        mg[j] = __builtin_amdgcn_sqrtf(r[j] * r[j] + im[j] * im[j] + 1e-6f);
    }
    float s = mg[0] + mg[1] + mg[2];
#pragma unroll
    for (int m = 32; m >= 1; m >>= 1) s += __shfl_xor(s, m);
    if ((t & 63) == 0) red[t >> 6] = s;
    __syncthreads();
    const float mean = (red[0] + red[1] + red[2] + red[3]) * (1.0f / 768.0f);
    __syncthreads();

    float v2 = 0.0f;
#pragma unroll
    for (int j = 0; j < 3; ++j) {
        const float d = mg[j] - mean;
        v2 += d * d;
    }
#pragma unroll
    for (int m = 32; m >= 1; m >>= 1) v2 += __shfl_xor(v2, m);
    if ((t & 63) == 0) red[t >> 6] = v2;
    __syncthreads();
    const float var = (red[0] + red[1] + red[2] + red[3]) * (1.0f / 768.0f);
    const float rstd = rsqrtf(var + 1e-6f);

#pragma unroll
    for (int j = 0; j < 3; ++j) {
        const int f = t + j * 256;
        const float sc = (mg[j] - mean) * rstd / (mg[j] + 1e-6f);
        nr[base + f] = (bf16)(gamma[2 * f] * (r[j] * sc) + beta[2 * f]);
        ni[base + f] = (bf16)(gamma[2 * f + 1] * (im[j] * sc) + beta[2 * f + 1]);
    }
}

// ---------------------------------------------------------------------------
// complex GEMM (NT) v2: double-buffered fused-plane LDS (row = [real|imag],
// 128B, XOR-swizzled via pre-swizzled global source), counted vmcnt + raw
// s_barrier (loads stay in flight across barriers), XCD-aware block swizzle.
// ---------------------------------------------------------------------------
template <int BM, int BN, int MODE, int OCC>
__global__ __launch_bounds__(256, OCC) void cgemm_kernel(
    const bf16* __restrict__ Ar, const bf16* __restrict__ Ai,
    const bf16* __restrict__ Wr, const bf16* __restrict__ Wi,
    const float* __restrict__ br, const float* __restrict__ bi,
    const float* __restrict__ resr, const float* __restrict__ resi,
    float* __restrict__ outFr, float* __restrict__ outFi,
    bf16* __restrict__ outBr, bf16* __restrict__ outBi,
    int N, int K) {
    constexpr int MR = BM / 32;          // fragment rows per wave
    constexpr int NR = BN / 32;          // fragment cols per wave
    constexpr int ASEG = BM / 8;         // 8-row A segments
    constexpr int NSEG = (BM + BN) / 8;  // total segments per K-step
    constexpr int SPW = NSEG / 4;        // segments per wave

    __shared__ __align__(16) bf16 sA[2][BM][64];  // row = [real 32 | imag 32]
    __shared__ __align__(16) bf16 sB[2][BN][64];

    const int tid = threadIdx.x;
    const int wave = tid >> 6, lane = tid & 63;
    const int lg = lane >> 4, lr = lane & 15;

    const int nwgx = gridDim.x;
    int wg = blockIdx.y * nwgx + blockIdx.x;
    const int cpx = (nwgx * gridDim.y) >> 3;
    wg = (wg & 7) * cpx + (wg >> 3);
    const int row0 = (wg % nwgx) * BM, col0 = (wg / nwgx) * BN;

    const int wm = (wave >> 1) * (BM / 2), wn = (wave & 1) * (BN / 2);

    // staging lane constants: 8 rows x 8 slots per segment; slot s holds
    // logical chunk s ^ (row&7); chunk<4 = real plane, else imag.
    const int srow = lane >> 3;             // row within segment
    const int schunk = (lane & 7) ^ srow;   // logical chunk for this slot
    const int spl = schunk >> 2;            // plane select
    const int sc8 = (schunk & 3) * 8;       // element offset within plane row

    auto issue = [&](int buf, int kt) {
#pragma unroll
        for (int s = 0; s < SPW; ++s) {
            const int id = wave * SPW + s;
            if (id < ASEG) {
                const int row = id * 8 + srow;
                gl_lds16((spl ? Ai : Ar) + (size_t)(row0 + row) * K + kt + sc8,
                         &sA[buf][id * 8][0]);
            } else {
                const int row = (id - ASEG) * 8 + srow;
                gl_lds16((spl ? Wi : Wr) + (size_t)(col0 + row) * K + kt + sc8,
                         &sB[buf][(id - ASEG) * 8][0]);
            }
        }
    };

    f32x4 accr[MR][NR], acci[MR][NR];
#pragma unroll
    for (int a = 0; a < MR; ++a)
#pragma unroll
        for (int b2 = 0; b2 < NR; ++b2) {
            accr[a][b2] = zero4();
            acci[a][b2] = zero4();
        }

    issue(0, 0);

    const int KT = K / 32;
    for (int kt = 0; kt < KT; ++kt) {
        const int buf = kt & 1;
        if (kt + 1 < KT) {
            issue(buf ^ 1, (kt + 1) * 32);  // prefetch stays in flight
            __builtin_amdgcn_sched_barrier(0);
            if constexpr (SPW == 8)
                asm volatile("s_waitcnt vmcnt(8)" ::: "memory");
            else if constexpr (SPW == 6)
                asm volatile("s_waitcnt vmcnt(6)" ::: "memory");
            else
                asm volatile("s_waitcnt vmcnt(0)" ::: "memory");
        } else {
            asm volatile("s_waitcnt vmcnt(0)" ::: "memory");
        }
        __builtin_amdgcn_sched_barrier(0);
        __builtin_amdgcn_s_barrier();  // tile kt resident for all waves
        __builtin_amdgcn_sched_barrier(0);

        bf16x8 ar[MR], ai[MR], an[MR];
#pragma unroll
        for (int mt = 0; mt < MR; ++mt) {
            const int rr = wm + mt * 16 + lr;
            const int slr = lg ^ (rr & 7);
            const int sli = (4 + lg) ^ (rr & 7);
            ar[mt] = *(const bf16x8*)(&sA[buf][rr][slr * 8]);
            ai[mt] = *(const bf16x8*)(&sA[buf][rr][sli * 8]);
            an[mt] = bneg8(ai[mt]);
        }
#pragma unroll
        for (int nt = 0; nt < NR; ++nt) {
            const int rr = wn + nt * 16 + lr;
            const int slr = lg ^ (rr & 7);
            const int sli = (4 + lg) ^ (rr & 7);
            const bf16x8 br8 = *(const bf16x8*)(&sB[buf][rr][slr * 8]);
            const bf16x8 bi8 = *(const bf16x8*)(&sB[buf][rr][sli * 8]);
#pragma unroll
            for (int mt = 0; mt < MR; ++mt) {
                accr[mt][nt] = MFMA16(ar[mt], br8, accr[mt][nt]);
                accr[mt][nt] = MFMA16(an[mt], bi8, accr[mt][nt]);
                acci[mt][nt] = MFMA16(ar[mt], bi8, acci[mt][nt]);
                acci[mt][nt] = MFMA16(ai[mt], br8, acci[mt][nt]);
            }
        }

        if (kt + 1 < KT) {
            __builtin_amdgcn_sched_barrier(0);
            __builtin_amdgcn_s_barrier();  // all reads of buf done before reuse
            __builtin_amdgcn_sched_barrier(0);
        }
    }

#pragma unroll
    for (int nt = 0; nt < NR; ++nt) {
        const int col = col0 + wn + nt * 16 + lr;
        const float bre = br[col], bie = bi[col];
#pragma unroll
        for (int mt = 0; mt < MR; ++mt) {
#pragma unroll
            for (int j = 0; j < 4; ++j) {
                const int row = row0 + wm + mt * 16 + lg * 4 + j;
                float vr = accr[mt][nt][j] + bre;
                float vi = acci[mt][nt][j] + bie;
                const size_t o = (size_t)row * N + col;
                if (MODE == 0) {
                    outBr[o] = (bf16)vr;
                    outBi[o] = (bf16)vi;
                } else if (MODE == 1) {
                    const float2 rv = ((const float2*)resr)[(size_t)row * 768 + col];
                    outFr[o] = rv.x + vr;
                    outFi[o] = rv.y + vi;
                } else if (MODE == 2) {
                    vr = 0.5f * vr * (1.0f + erff(vr * 0.70710678118654752f));
                    vi = 0.5f * vi * (1.0f + erff(vi * 0.70710678118654752f));
                    outBr[o] = (bf16)vr;
                    outBi[o] = (bf16)vi;
                } else {
                    const size_t ro = (size_t)row * 768 + col;
                    outFr[(size_t)row * 1536 + 2 * col]     = resr[ro] + vr;
                    outFr[(size_t)row * 1536 + 2 * col + 1] = resi[ro] + vi;
                }
            }
        }
    }
}

// ---------------------------------------------------------------------------
// transpose V slice of qkv into [B*nH][64 d][2048 n] bf16 planes
// ---------------------------------------------------------------------------
__global__ __launch_bounds__(256) void vtrans_kernel(
    const bf16* __restrict__ qkvr, const bf16* __restrict__ qkvi,
    bf16* __restrict__ vtr, bf16* __restrict__ vti) {
    __shared__ bf16 sr[64][65];
    __shared__ bf16 si[64][65];
    const int t = threadIdx.x;
    const int nb = blockIdx.x, h = blockIdx.y, b = blockIdx.z;
    const size_t ld = 2304;
    const bf16* srcr = qkvr + (size_t)(b * 2048 + nb * 64) * ld + 1536 + h * 64;
    const bf16* srci = qkvi + (size_t)(b * 2048 + nb * 64) * ld + 1536 + h * 64;
#pragma unroll
    for (int j = 0; j < 16; ++j) {
        const int idx = t + 256 * j;
        const int n = idx >> 6, d = idx & 63;
        sr[n][d] = srcr[(size_t)n * ld + d];
        si[n][d] = srci[(size_t)n * ld + d];
    }
    __syncthreads();
    bf16* dstr = vtr + (size_t)(b * 12 + h) * 64 * 2048 + nb * 64;
    bf16* dsti = vti + (size_t)(b * 12 + h) * 64 * 2048 + nb * 64;
#pragma unroll
    for (int j = 0; j < 16; ++j) {
        const int idx = t + 256 * j;
        const int d = idx >> 6, n = idx & 63;
        dstr[(size_t)d * 2048 + n] = sr[n][d];
        dsti[(size_t)d * 2048 + n] = si[n][d];
    }
}

// ---------------------------------------------------------------------------
// fused complex flash attention (unchanged from R6: 133 us, passed)
// ---------------------------------------------------------------------------
__global__ __launch_bounds__(256, 3) void cattn_kernel(
    const bf16* __restrict__ qkvr, const bf16* __restrict__ qkvi,
    const bf16* __restrict__ vtr, const bf16* __restrict__ vti,
    bf16* __restrict__ aor, bf16* __restrict__ aoi) {
    __shared__ __align__(16) bf16 sK[2][2][32][64];
    __shared__ __align__(16) bf16 sV[2][64][64];
    __shared__ __align__(16) bf16 sP[4][16][40];

    const int tid = threadIdx.x;
    const int w = tid >> 6, lane = tid & 63;
    const int lg = lane >> 4, lr = lane & 15;
    const int qb = blockIdx.x, h = blockIdx.y, b = blockIdx.z;
    const int ld = 2304;

    const int s_krow = lane >> 3;
    const int s_kch8 = ((lane & 7) ^ s_krow) * 8;
    const int s_vlog = (lane & 7) ^ s_krow;
    const int s_vpl = s_vlog >> 2;
    const int s_vk8 = (s_vlog & 3) * 8;

    const bf16* kbase0 = qkvr + (size_t)b * 2048 * ld + 768 + h * 64;
    const bf16* kbase1 = qkvi + (size_t)b * 2048 * ld + 768 + h * 64;
    const bf16* vbase0 = vtr + (size_t)(b * 12 + h) * 64 * 2048;
    const bf16* vbase1 = vti + (size_t)(b * 12 + h) * 64 * 2048;

    auto stage = [&](int buf, int kt) {
#pragma unroll
        for (int s = 0; s < 2; ++s) {
            const int seg = s * 4 + w;
            const int pl = seg >> 2, rg = seg & 3;
            gl_lds16((pl ? kbase1 : kbase0) +
                         (size_t)(kt * 32 + rg * 8 + s_krow) * ld + s_kch8,
                     &sK[buf][pl][rg * 8][0]);
            gl_lds16((s_vpl ? vbase1 : vbase0) +
                         (size_t)(seg * 8 + s_krow) * 2048 + kt * 32 + s_vk8,
                     &sV[buf][seg * 8][0]);
        }
    };

    stage(0, 0);

    const size_t qoff = (size_t)(b * 2048 + qb * 64 + w * 16 + lr) * ld + h * 64;
    bf16x8 aqr[2], aqi[2];
#pragma unroll
    for (int ks = 0; ks < 2; ++ks) {
        aqr[ks] = *(const bf16x8*)(qkvr + qoff + ks * 32 + lg * 8);
        aqi[ks] = *(const bf16x8*)(qkvi + qoff + ks * 32 + lg * 8);
    }

    f32x4 our[4], oui[4];
#pragma unroll
    for (int d = 0; d < 4; ++d) {
        our[d] = zero4();
        oui[d] = zero4();
    }
    float mrun = -1e30f, lrun = 0.0f;

    for (int kt = 0; kt < 64; ++kt) {
        const int cur = kt & 1;
        if (kt < 63) {
            stage(cur ^ 1, kt + 1);
            __builtin_amdgcn_sched_barrier(0);
            asm volatile("s_waitcnt vmcnt(4)" ::: "memory");
        } else {
            asm volatile("s_waitcnt vmcnt(0)" ::: "memory");
        }
        __builtin_amdgcn_sched_barrier(0);
        __builtin_amdgcn_s_barrier();
        __builtin_amdgcn_sched_barrier(0);

        f32x4 str[2], sti[2];
        str[0] = zero4(); str[1] = zero4();
        sti[0] = zero4(); sti[1] = zero4();
#pragma unroll
        for (int t = 0; t < 2; ++t) {
#pragma unroll
            for (int ks = 0; ks < 2; ++ks) {
                const int ch = ((ks << 2) | lg) ^ (lr & 7);
                const bf16x8 kr8 = *(const bf16x8*)(&sK[cur][0][t * 16 + lr][ch * 8]);
                const bf16x8 ki8 = *(const bf16x8*)(&sK[cur][1][t * 16 + lr][ch * 8]);
                const bf16x8 kn8 = bneg8(kr8);
                str[t] = MFMA16(kr8, aqr[ks], str[t]);
                str[t] = MFMA16(ki8, aqi[ks], str[t]);
                sti[t] = MFMA16(ki8, aqr[ks], sti[t]);
                sti[t] = MFMA16(kn8, aqi[ks], sti[t]);
            }
        }

        float p[8];
        float tmax = -1e30f;
#pragma unroll
        for (int t = 0; t < 2; ++t)
#pragma unroll
            for (int j = 0; j < 4; ++j) {
                const float sr = str[t][j], si = sti[t][j];
                const float m = __builtin_amdgcn_sqrtf(sr * sr + si * si + 1e-8f) * 0.125f;
                p[t * 4 + j] = m;
                tmax = fmaxf(tmax, m);
            }
        tmax = fmaxf(tmax, __shfl_xor(tmax, 16));
        tmax = fmaxf(tmax, __shfl_xor(tmax, 32));

        if (!__all(tmax <= mrun)) {
            const float mnew = fmaxf(mrun, tmax);
            const float corr = __builtin_amdgcn_exp2f((mrun - mnew) * LOG2E);
            float cj[4];
#pragma unroll
            for (int j = 0; j < 4; ++j) cj[j] = __shfl(corr, lg * 4 + j);
#pragma unroll
            for (int d = 0; d < 4; ++d)
#pragma unroll
                for (int j = 0; j < 4; ++j) {
                    our[d][j] *= cj[j];
                    oui[d][j] *= cj[j];
                }
            lrun *= corr;
            mrun = mnew;
        }

        float ls = 0.0f;
#pragma unroll
        for (int i = 0; i < 8; ++i) {
            p[i] = __builtin_amdgcn_exp2f((p[i] - mrun) * LOG2E);
            ls += p[i];
        }
        ls += __shfl_xor(ls, 16);
        ls += __shfl_xor(ls, 32);
        lrun += ls;

#pragma unroll
        for (int t = 0; t < 2; ++t) {
            bf16x4 pk;
#pragma unroll
            for (int j = 0; j < 4; ++j) pk[j] = (bf16)p[t * 4 + j];
            *(bf16x4*)(&sP[w][lr][t * 16 + lg * 4]) = pk;
        }
        const bf16x8 pf = *(const bf16x8*)(&sP[w][lr][lg * 8]);

#pragma unroll
        for (int d = 0; d < 4; ++d) {
            const int slr = lg ^ (lr & 7);
            const int sli = (4 + lg) ^ (lr & 7);
            const bf16x8 vr8 = *(const bf16x8*)(&sV[cur][d * 16 + lr][slr * 8]);
            const bf16x8 vi8 = *(const bf16x8*)(&sV[cur][d * 16 + lr][sli * 8]);
            our[d] = MFMA16(pf, vr8, our[d]);
            oui[d] = MFMA16(pf, vi8, oui[d]);
        }

        __builtin_amdgcn_sched_barrier(0);
        __builtin_amdgcn_s_barrier();
        __builtin_amdgcn_sched_barrier(0);
    }

    float linv[4];
#pragma unroll
    for (int j = 0; j < 4; ++j) {
        const float lj = __shfl(lrun, lg * 4 + j);
        linv[j] = __builtin_amdgcn_rcpf(lj);
    }
#pragma unroll
    for (int d = 0; d < 4; ++d)
#pragma unroll
        for (int j = 0; j < 4; ++j) {
            const int row = b * 2048 + qb * 64 + w * 16 + lg * 4 + j;
            const int col = h * 64 + d * 16 + lr;
            aor[(size_t)row * 768 + col] = (bf16)(our[d][j] * linv[j]);
            aoi[(size_t)row * 768 + col] = (bf16)(oui[d][j] * linv[j]);
        }
}

// ---------------------------------------------------------------------------
// host launch
// ---------------------------------------------------------------------------
extern "C" void kernel_launch(void* const* d_in, const int* in_sizes, int n_in,
                              void* d_out, int out_size, void* d_ws, size_t ws_size,
                              hipStream_t stream) {
    const float* x      = (const float*)d_in[0];
    const float* n1g    = (const float*)d_in[1];
    const float* n1b    = (const float*)d_in[2];
    const float* qkvwr  = (const float*)d_in[3];
    const float* qkvwi  = (const float*)d_in[4];
    const float* qkvbr  = (const float*)d_in[5];
    const float* qkvbi  = (const float*)d_in[6];
    const float* projwr = (const float*)d_in[7];
    const float* projwi = (const float*)d_in[8];
    const float* projbr = (const float*)d_in[9];
    const float* projbi = (const float*)d_in[10];
    const float* n2g    = (const float*)d_in[11];
    const float* n2b    = (const float*)d_in[12];
    const float* fc1wr  = (const float*)d_in[13];
    const float* fc1wi  = (const float*)d_in[14];
    const float* fc1br  = (const float*)d_in[15];
    const float* fc1bi  = (const float*)d_in[16];
    const float* fc2wr  = (const float*)d_in[17];
    const float* fc2wi  = (const float*)d_in[18];
    const float* fc2br  = (const float*)d_in[19];
    const float* fc2bi  = (const float*)d_in[20];

    const int M = 4096, E = 768, E3 = 2304, HH = 1536;

    char* base = (char*)d_ws;
    size_t off = 0;
    auto alloc = [&](size_t bytes) -> void* {
        void* p = base + off;
        off += (bytes + 255) & ~(size_t)255;
        return p;
    };
    float* xr2 = (float*)alloc((size_t)M * E * 4);
    float* xi2 = (float*)alloc((size_t)M * E * 4);
    bf16* nr   = (bf16*)alloc((size_t)M * E * 2);
    bf16* ni   = (bf16*)alloc((size_t)M * E * 2);
    bf16* wqr  = (bf16*)alloc((size_t)E3 * E * 2);
    bf16* wqi  = (bf16*)alloc((size_t)E3 * E * 2);
    bf16* wpr  = (bf16*)alloc((size_t)E * E * 2);
    bf16* wpi  = (bf16*)alloc((size_t)E * E * 2);
    bf16* w1r  = (bf16*)alloc((size_t)HH * E * 2);
    bf16* w1i  = (bf16*)alloc((size_t)HH * E * 2);
    bf16* w2r  = (bf16*)alloc((size_t)E * HH * 2);
    bf16* w2i  = (bf16*)alloc((size_t)E * HH * 2);
    bf16* qkr  = (bf16*)alloc((size_t)M * E3 * 2);
    bf16* qki  = (bf16*)alloc((size_t)M * E3 * 2);
    bf16* vtr  = (bf16*)alloc((size_t)24 * 64 * 2048 * 2);
    bf16* vti  = (bf16*)alloc((size_t)24 * 64 * 2048 * 2);
    bf16* aor  = (bf16*)alloc((size_t)M * E * 2);
    bf16* aoi  = (bf16*)alloc((size_t)M * E * 2);
    bf16* hr   = (bf16*)alloc((size_t)M * HH * 2);
    bf16* hi   = (bf16*)alloc((size_t)M * HH * 2);

    if (off > ws_size) {
        fill_kernel<<<1024, 256, 0, stream>>>((float*)d_out, 1.0e9f, out_size);
        return;
    }

    // fused weight conversion
    Cvt8 c;
    c.s[0] = qkvwr; c.d[0] = wqr;
    c.s[1] = qkvwi; c.d[1] = wqi;
    c.s[2] = projwr; c.d[2] = wpr;
    c.s[3] = projwi; c.d[3] = wpi;
    c.s[4] = fc1wr; c.d[4] = w1r;
    c.s[5] = fc1wi; c.d[5] = w1i;
    c.s[6] = fc2wr; c.d[6] = w2r;
    c.s[7] = fc2wi; c.d[7] = w2i;
    const int nseg[8] = {E3 * E, E3 * E, E * E, E * E, HH * E, HH * E, E * HH, E * HH};
    int cum = 0;
    for (int k = 0; k < 8; ++k) {
        c.boff[k] = cum;
        cum += nseg[k] / 1024;
    }
    c.boff[8] = cum;
    cvt8_kernel<<<cum, 256, 0, stream>>>(c);

    // LN1 (reads interleaved x directly)
    cln_kernel<true><<<M, 256, 0, stream>>>(x, nullptr, n1g, n1b, nr, ni);
    // QKV: 128x128, dbuf+counted vmcnt, grid 576
    cgemm_kernel<128, 128, 0, 2><<<dim3(32, 18), 256, 0, stream>>>(
        nr, ni, wqr, wqi, qkvbr, qkvbi, nullptr, nullptr, nullptr, nullptr,
        qkr, qki, E3, E);
    // V transpose
    vtrans_kernel<<<dim3(32, 12, 2), 256, 0, stream>>>(qkr, qki, vtr, vti);
    // attention (64 q-rows per block; 768 blocks = 3/CU exact)
    cattn_kernel<<<dim3(32, 12, 2), 256, 0, stream>>>(qkr, qki, vtr, vti, aor, aoi);
    // proj + interleaved-x residual: 128x64, grid 384, 3 blocks/CU capable
    cgemm_kernel<128, 64, 1, 3><<<dim3(32, 12), 256, 0, stream>>>(
        aor, aoi, wpr, wpi, projbr, projbi, x, nullptr, xr2, xi2, nullptr, nullptr,
        E, E);
    // LN2
    cln_kernel<false><<<M, 256, 0, stream>>>(xr2, xi2, n2g, n2b, nr, ni);
    // FC1 + gelu: 128x128, grid 384
    cgemm_kernel<128, 128, 2, 2><<<dim3(32, 12), 256, 0, stream>>>(
        nr, ni, w1r, w1i, fc1br, fc1bi, nullptr, nullptr, nullptr, nullptr,
        hr, hi, HH, E);
    // FC2 + residual -> interleaved d_out: 128x64, grid 384
    cgemm_kernel<128, 64, 3, 3><<<dim3(32, 12), 256, 0, stream>>>(
        hr, hi, w2r, w2i, fc2br, fc2bi, xr2, xi2, (float*)d_out, nullptr,
        nullptr, nullptr, E, HH);
}

// Round 9
// 371.068 us; speedup vs baseline: 1.2125x; 1.0389x over previous
//
#include <hip/hip_runtime.h>
#include <cmath>

typedef __bf16 bf16;
typedef __bf16 bf16x8 __attribute__((ext_vector_type(8)));
typedef __bf16 bf16x4 __attribute__((ext_vector_type(4)));
typedef float  f32x4  __attribute__((ext_vector_type(4)));
typedef unsigned int u32x4 __attribute__((ext_vector_type(4)));

#define MFMA16(a, b, c) __builtin_amdgcn_mfma_f32_16x16x32_bf16((a), (b), (c), 0, 0, 0)
#define LOG2E 1.44269504088896f

static __device__ __forceinline__ void gl_lds16(const void* g, void* l) {
    __builtin_amdgcn_global_load_lds((const __attribute__((address_space(1))) void*)g,
                                     (__attribute__((address_space(3))) void*)l, 16, 0, 0);
}

static __device__ __forceinline__ bf16x8 bneg8(bf16x8 x) {
    u32x4 u = __builtin_bit_cast(u32x4, x);
    u = u ^ 0x80008000u;
    return __builtin_bit_cast(bf16x8, u);
}

static __device__ __forceinline__ f32x4 zero4() {
    return f32x4{0.0f, 0.0f, 0.0f, 0.0f};
}

// ---------------------------------------------------------------------------
// small utility kernels
// ---------------------------------------------------------------------------
__global__ void fill_kernel(float* p, float v, int n) {
    for (int i = blockIdx.x * blockDim.x + threadIdx.x; i < n; i += gridDim.x * blockDim.x)
        p[i] = v;
}

// fused 8-way f32 -> bf16 weight conversion (all sizes % 1024 == 0)
struct Cvt8 {
    const float* s[8];
    bf16* d[8];
    int boff[9];
};
__global__ __launch_bounds__(256) void cvt8_kernel(Cvt8 c) {
    int blk = blockIdx.x;
    int seg = 0;
#pragma unroll
    for (int k = 0; k < 7; ++k)
        if (blk >= c.boff[k + 1]) seg = k + 1;
    const int local = blk - c.boff[seg];
    const int i = local * 1024 + threadIdx.x * 4;
    const float4 v = *(const float4*)(c.s[seg] + i);
    bf16x4 o;
    o[0] = (bf16)v.x; o[1] = (bf16)v.y; o[2] = (bf16)v.z; o[3] = (bf16)v.w;
    *(bf16x4*)(c.d[seg] + i) = o;
}

// ---------------------------------------------------------------------------
// complex magnitude layernorm. ILV=true: xa is interleaved float2 [row][768][2]
// ---------------------------------------------------------------------------
template <bool ILV>
__global__ __launch_bounds__(256) void cln_kernel(
    const float* __restrict__ xa, const float* __restrict__ xb,
    const float* __restrict__ gamma, const float* __restrict__ beta,
    bf16* __restrict__ nr, bf16* __restrict__ ni) {
    __shared__ float red[4];
    const int t = threadIdx.x;
    const size_t base = (size_t)blockIdx.x * 768;

    float r[3], im[3], mg[3];
#pragma unroll
    for (int j = 0; j < 3; ++j) {
        const int f = t + j * 256;
        if (ILV) {
            const float2 v = ((const float2*)xa)[base + f];
            r[j] = v.x;
            im[j] = v.y;
        } else {
            r[j] = xa[base + f];
            im[j] = xb[base + f];
        }
        mg[j] = __builtin_amdgcn_sqrtf(r[j] * r[j] + im[j] * im[j] + 1e-6f);
    }
    float s = mg[0] + mg[1] + mg[2];
#pragma unroll
    for (int m = 32; m >= 1; m >>= 1) s += __shfl_xor(s, m);
    if ((t & 63) == 0) red[t >> 6] = s;
    __syncthreads();
    const float mean = (red[0] + red[1] + red[2] + red[3]) * (1.0f / 768.0f);
    __syncthreads();

    float v2 = 0.0f;
#pragma unroll
    for (int j = 0; j < 3; ++j) {
        const float d = mg[j] - mean;
        v2 += d * d;
    }
#pragma unroll
    for (int m = 32; m >= 1; m >>= 1) v2 += __shfl_xor(v2, m);
    if ((t & 63) == 0) red[t >> 6] = v2;
    __syncthreads();
    const float var = (red[0] + red[1] + red[2] + red[3]) * (1.0f / 768.0f);
    const float rstd = rsqrtf(var + 1e-6f);

#pragma unroll
    for (int j = 0; j < 3; ++j) {
        const int f = t + j * 256;
        const float sc = (mg[j] - mean) * rstd / (mg[j] + 1e-6f);
        nr[base + f] = (bf16)(gamma[2 * f] * (r[j] * sc) + beta[2 * f]);
        ni[base + f] = (bf16)(gamma[2 * f + 1] * (im[j] * sc) + beta[2 * f + 1]);
    }
}

// ---------------------------------------------------------------------------
// complex GEMM (NT) v2: double-buffered fused-plane LDS (row = [real|imag],
// 128B, XOR-swizzled via pre-swizzled global source), counted vmcnt + raw
// s_barrier, XCD-aware block swizzle, setprio around compute phase.
// ---------------------------------------------------------------------------
template <int BM, int BN, int MODE, int OCC>
__global__ __launch_bounds__(256, OCC) void cgemm_kernel(
    const bf16* __restrict__ Ar, const bf16* __restrict__ Ai,
    const bf16* __restrict__ Wr, const bf16* __restrict__ Wi,
    const float* __restrict__ br, const float* __restrict__ bi,
    const float* __restrict__ resr, const float* __restrict__ resi,
    float* __restrict__ outFr, float* __restrict__ outFi,
    bf16* __restrict__ outBr, bf16* __restrict__ outBi,
    int N, int K) {
    constexpr int MR = BM / 32;
    constexpr int NR = BN / 32;
    constexpr int ASEG = BM / 8;
    constexpr int NSEG = (BM + BN) / 8;
    constexpr int SPW = NSEG / 4;

    __shared__ __align__(16) bf16 sA[2][BM][64];  // row = [real 32 | imag 32]
    __shared__ __align__(16) bf16 sB[2][BN][64];

    const int tid = threadIdx.x;
    const int wave = tid >> 6, lane = tid & 63;
    const int lg = lane >> 4, lr = lane & 15;

    const int nwgx = gridDim.x;
    int wg = blockIdx.y * nwgx + blockIdx.x;
    const int cpx = (nwgx * gridDim.y) >> 3;
    wg = (wg & 7) * cpx + (wg >> 3);
    const int row0 = (wg % nwgx) * BM, col0 = (wg / nwgx) * BN;

    const int wm = (wave >> 1) * (BM / 2), wn = (wave & 1) * (BN / 2);

    const int srow = lane >> 3;
    const int schunk = (lane & 7) ^ srow;
    const int spl = schunk >> 2;
    const int sc8 = (schunk & 3) * 8;

    auto issue = [&](int buf, int kt) {
#pragma unroll
        for (int s = 0; s < SPW; ++s) {
            const int id = wave * SPW + s;
            if (id < ASEG) {
                const int row = id * 8 + srow;
                gl_lds16((spl ? Ai : Ar) + (size_t)(row0 + row) * K + kt + sc8,
                         &sA[buf][id * 8][0]);
            } else {
                const int row = (id - ASEG) * 8 + srow;
                gl_lds16((spl ? Wi : Wr) + (size_t)(col0 + row) * K + kt + sc8,
                         &sB[buf][(id - ASEG) * 8][0]);
            }
        }
    };

    f32x4 accr[MR][NR], acci[MR][NR];
#pragma unroll
    for (int a = 0; a < MR; ++a)
#pragma unroll
        for (int b2 = 0; b2 < NR; ++b2) {
            accr[a][b2] = zero4();
            acci[a][b2] = zero4();
        }

    issue(0, 0);

    const int KT = K / 32;
    for (int kt = 0; kt < KT; ++kt) {
        const int buf = kt & 1;
        if (kt + 1 < KT) {
            issue(buf ^ 1, (kt + 1) * 32);
            __builtin_amdgcn_sched_barrier(0);
            if constexpr (SPW == 8)
                asm volatile("s_waitcnt vmcnt(8)" ::: "memory");
            else if constexpr (SPW == 6)
                asm volatile("s_waitcnt vmcnt(6)" ::: "memory");
            else
                asm volatile("s_waitcnt vmcnt(0)" ::: "memory");
        } else {
            asm volatile("s_waitcnt vmcnt(0)" ::: "memory");
        }
        __builtin_amdgcn_sched_barrier(0);
        __builtin_amdgcn_s_barrier();
        __builtin_amdgcn_sched_barrier(0);

        __builtin_amdgcn_s_setprio(1);
        bf16x8 ar[MR], ai[MR], an[MR];
#pragma unroll
        for (int mt = 0; mt < MR; ++mt) {
            const int rr = wm + mt * 16 + lr;
            const int slr = lg ^ (rr & 7);
            const int sli = (4 + lg) ^ (rr & 7);
            ar[mt] = *(const bf16x8*)(&sA[buf][rr][slr * 8]);
            ai[mt] = *(const bf16x8*)(&sA[buf][rr][sli * 8]);
            an[mt] = bneg8(ai[mt]);
        }
#pragma unroll
        for (int nt = 0; nt < NR; ++nt) {
            const int rr = wn + nt * 16 + lr;
            const int slr = lg ^ (rr & 7);
            const int sli = (4 + lg) ^ (rr & 7);
            const bf16x8 br8 = *(const bf16x8*)(&sB[buf][rr][slr * 8]);
            const bf16x8 bi8 = *(const bf16x8*)(&sB[buf][rr][sli * 8]);
#pragma unroll
            for (int mt = 0; mt < MR; ++mt) {
                accr[mt][nt] = MFMA16(ar[mt], br8, accr[mt][nt]);
                accr[mt][nt] = MFMA16(an[mt], bi8, accr[mt][nt]);
                acci[mt][nt] = MFMA16(ar[mt], bi8, acci[mt][nt]);
                acci[mt][nt] = MFMA16(ai[mt], br8, acci[mt][nt]);
            }
        }
        __builtin_amdgcn_s_setprio(0);

        if (kt + 1 < KT) {
            __builtin_amdgcn_sched_barrier(0);
            __builtin_amdgcn_s_barrier();
            __builtin_amdgcn_sched_barrier(0);
        }
    }

#pragma unroll
    for (int nt = 0; nt < NR; ++nt) {
        const int col = col0 + wn + nt * 16 + lr;
        const float bre = br[col], bie = bi[col];
#pragma unroll
        for (int mt = 0; mt < MR; ++mt) {
#pragma unroll
            for (int j = 0; j < 4; ++j) {
                const int row = row0 + wm + mt * 16 + lg * 4 + j;
                float vr = accr[mt][nt][j] + bre;
                float vi = acci[mt][nt][j] + bie;
                const size_t o = (size_t)row * N + col;
                if (MODE == 0) {
                    outBr[o] = (bf16)vr;
                    outBi[o] = (bf16)vi;
                } else if (MODE == 1) {
                    const float2 rv = ((const float2*)resr)[(size_t)row * 768 + col];
                    outFr[o] = rv.x + vr;
                    outFi[o] = rv.y + vi;
                } else if (MODE == 2) {
                    vr = 0.5f * vr * (1.0f + erff(vr * 0.70710678118654752f));
                    vi = 0.5f * vi * (1.0f + erff(vi * 0.70710678118654752f));
                    outBr[o] = (bf16)vr;
                    outBi[o] = (bf16)vi;
                } else {
                    const size_t ro = (size_t)row * 768 + col;
                    outFr[(size_t)row * 1536 + 2 * col]     = resr[ro] + vr;
                    outFr[(size_t)row * 1536 + 2 * col + 1] = resi[ro] + vi;
                }
            }
        }
    }
}

// ---------------------------------------------------------------------------
// transpose V slice of qkv into [B*nH][64 d][2048 n] bf16 planes
// ---------------------------------------------------------------------------
__global__ __launch_bounds__(256) void vtrans_kernel(
    const bf16* __restrict__ qkvr, const bf16* __restrict__ qkvi,
    bf16* __restrict__ vtr, bf16* __restrict__ vti) {
    __shared__ bf16 sr[64][65];
    __shared__ bf16 si[64][65];
    const int t = threadIdx.x;
    const int nb = blockIdx.x, h = blockIdx.y, b = blockIdx.z;
    const size_t ld = 2304;
    const bf16* srcr = qkvr + (size_t)(b * 2048 + nb * 64) * ld + 1536 + h * 64;
    const bf16* srci = qkvi + (size_t)(b * 2048 + nb * 64) * ld + 1536 + h * 64;
#pragma unroll
    for (int j = 0; j < 16; ++j) {
        const int idx = t + 256 * j;
        const int n = idx >> 6, d = idx & 63;
        sr[n][d] = srcr[(size_t)n * ld + d];
        si[n][d] = srci[(size_t)n * ld + d];
    }
    __syncthreads();
    bf16* dstr = vtr + (size_t)(b * 12 + h) * 64 * 2048 + nb * 64;
    bf16* dsti = vti + (size_t)(b * 12 + h) * 64 * 2048 + nb * 64;
#pragma unroll
    for (int j = 0; j < 16; ++j) {
        const int idx = t + 256 * j;
        const int d = idx >> 6, n = idx & 63;
        dstr[(size_t)d * 2048 + n] = sr[n][d];
        dsti[(size_t)d * 2048 + n] = si[n][d];
    }
}

// ---------------------------------------------------------------------------
// fused complex flash attention v7: R6 structure + shortened softmax chain
// (max on |S|^2, fused exp2 arg, defer-max THR=8), setprio on MFMA clusters,
// pointer-bump staging.
// ---------------------------------------------------------------------------
__global__ __launch_bounds__(256, 3) void cattn_kernel(
    const bf16* __restrict__ qkvr, const bf16* __restrict__ qkvi,
    const bf16* __restrict__ vtr, const bf16* __restrict__ vti,
    bf16* __restrict__ aor, bf16* __restrict__ aoi) {
    __shared__ __align__(16) bf16 sK[2][2][32][64];
    __shared__ __align__(16) bf16 sV[2][64][64];
    __shared__ __align__(16) bf16 sP[4][16][40];

    const int tid = threadIdx.x;
    const int w = tid >> 6, lane = tid & 63;
    const int lg = lane >> 4, lr = lane & 15;
    const int qb = blockIdx.x, h = blockIdx.y, b = blockIdx.z;
    const int ld = 2304;

    const int s_krow = lane >> 3;
    const int s_kch8 = ((lane & 7) ^ s_krow) * 8;
    const int s_vlog = (lane & 7) ^ s_krow;
    const int s_vpl = s_vlog >> 2;
    const int s_vk8 = (s_vlog & 3) * 8;

    const bf16* kbase0 = qkvr + (size_t)b * 2048 * ld + 768 + h * 64;
    const bf16* kbase1 = qkvi + (size_t)b * 2048 * ld + 768 + h * 64;
    const bf16* vbase = (s_vpl ? vti : vtr) + (size_t)(b * 12 + h) * 64 * 2048;

    // running staging pointers (advance by one 32-key tile per stage call)
    const bf16* kp0 = kbase0 + (size_t)(w * 8 + s_krow) * ld + s_kch8;
    const bf16* kp1 = kbase1 + (size_t)(w * 8 + s_krow) * ld + s_kch8;
    const bf16* vp0 = vbase + (size_t)(w * 8 + s_krow) * 2048 + s_vk8;
    const bf16* vp1 = vbase + (size_t)((4 + w) * 8 + s_krow) * 2048 + s_vk8;

    auto stage = [&](int buf) {
        gl_lds16(kp0, &sK[buf][0][w * 8][0]);
        gl_lds16(kp1, &sK[buf][1][w * 8][0]);
        gl_lds16(vp0, &sV[buf][w * 8][0]);
        gl_lds16(vp1, &sV[buf][(4 + w) * 8][0]);
        kp0 += 32 * ld;
        kp1 += 32 * ld;
        vp0 += 32;
        vp1 += 32;
    };

    stage(0);

    const size_t qoff = (size_t)(b * 2048 + qb * 64 + w * 16 + lr) * ld + h * 64;
    bf16x8 aqr[2], aqi[2];
#pragma unroll
    for (int ks = 0; ks < 2; ++ks) {
        aqr[ks] = *(const bf16x8*)(qkvr + qoff + ks * 32 + lg * 8);
        aqi[ks] = *(const bf16x8*)(qkvi + qoff + ks * 32 + lg * 8);
    }

    f32x4 our[4], oui[4];
#pragma unroll
    for (int d = 0; d < 4; ++d) {
        our[d] = zero4();
        oui[d] = zero4();
    }
    const float C1 = 0.125f * LOG2E;
    float mrun = -1e30f, lrun = 0.0f;
    float thr2 = -1.0f;   // skip-rescale bound on |S|^2 (forces rescale on tile 0)
    float mC2 = 0.0f;     // -mrun*LOG2E, set on first rescale

    for (int kt = 0; kt < 64; ++kt) {
        const int cur = kt & 1;
        if (kt < 63) {
            stage(cur ^ 1);
            __builtin_amdgcn_sched_barrier(0);
            asm volatile("s_waitcnt vmcnt(4)" ::: "memory");
        } else {
            asm volatile("s_waitcnt vmcnt(0)" ::: "memory");
        }
        __builtin_amdgcn_sched_barrier(0);
        __builtin_amdgcn_s_barrier();
        __builtin_amdgcn_sched_barrier(0);

        // ---- QK^T ----
        f32x4 str[2], sti[2];
        str[0] = zero4(); str[1] = zero4();
        sti[0] = zero4(); sti[1] = zero4();
        __builtin_amdgcn_s_setprio(1);
#pragma unroll
        for (int t = 0; t < 2; ++t) {
#pragma unroll
            for (int ks = 0; ks < 2; ++ks) {
                const int ch = ((ks << 2) | lg) ^ (lr & 7);
                const bf16x8 kr8 = *(const bf16x8*)(&sK[cur][0][t * 16 + lr][ch * 8]);
                const bf16x8 ki8 = *(const bf16x8*)(&sK[cur][1][t * 16 + lr][ch * 8]);
                const bf16x8 kn8 = bneg8(kr8);
                str[t] = MFMA16(kr8, aqr[ks], str[t]);
                str[t] = MFMA16(ki8, aqi[ks], str[t]);
                sti[t] = MFMA16(ki8, aqr[ks], sti[t]);
                sti[t] = MFMA16(kn8, aqi[ks], sti[t]);
            }
        }
        __builtin_amdgcn_s_setprio(0);

        // ---- squared magnitudes; max chain independent of sqrt ----
        float v[8];
        float vmax = 0.0f;
#pragma unroll
        for (int t = 0; t < 2; ++t)
#pragma unroll
            for (int j = 0; j < 4; ++j) {
                const float sr = str[t][j], si = sti[t][j];
                const float vv = fmaf(sr, sr, fmaf(si, si, 1e-8f));
                v[t * 4 + j] = vv;
                vmax = fmaxf(vmax, vv);
            }
        vmax = fmaxf(vmax, __shfl_xor(vmax, 16));
        vmax = fmaxf(vmax, __shfl_xor(vmax, 32));

        // defer-max: rescale only if sqrt(vmax)/8 > mrun + 8
        if (!__all(vmax <= thr2)) {
            const float tm = __builtin_amdgcn_sqrtf(vmax) * 0.125f;
            const float mnew = fmaxf(mrun, tm);
            const float corr = __builtin_amdgcn_exp2f((mrun - mnew) * LOG2E);
            float cj[4];
#pragma unroll
            for (int j = 0; j < 4; ++j) cj[j] = __shfl(corr, lg * 4 + j);
#pragma unroll
            for (int d = 0; d < 4; ++d)
#pragma unroll
                for (int j = 0; j < 4; ++j) {
                    our[d][j] *= cj[j];
                    oui[d][j] *= cj[j];
                }
            lrun *= corr;
            mrun = mnew;
            const float m8 = mrun + 8.0f;
            thr2 = 64.0f * m8 * m8;
            mC2 = -mrun * LOG2E;
        }

        // ---- p = exp2(sqrt(v)*C1 + mC2); sqrt/exp2 pipeline across 8 ----
        float p[8];
        float ls = 0.0f;
#pragma unroll
        for (int i = 0; i < 8; ++i) {
            p[i] = __builtin_amdgcn_exp2f(
                fmaf(__builtin_amdgcn_sqrtf(v[i]), C1, mC2));
            ls += p[i];
        }
        ls += __shfl_xor(ls, 16);
        ls += __shfl_xor(ls, 32);
        lrun += ls;

        // ---- P -> LDS -> PV A-fragment ----
#pragma unroll
        for (int t = 0; t < 2; ++t) {
            bf16x4 pk;
#pragma unroll
            for (int j = 0; j < 4; ++j) pk[j] = (bf16)p[t * 4 + j];
            *(bf16x4*)(&sP[w][lr][t * 16 + lg * 4]) = pk;
        }
        const bf16x8 pf = *(const bf16x8*)(&sP[w][lr][lg * 8]);

        __builtin_amdgcn_s_setprio(1);
#pragma unroll
        for (int d = 0; d < 4; ++d) {
            const int slr = lg ^ (lr & 7);
            const int sli = (4 + lg) ^ (lr & 7);
            const bf16x8 vr8 = *(const bf16x8*)(&sV[cur][d * 16 + lr][slr * 8]);
            const bf16x8 vi8 = *(const bf16x8*)(&sV[cur][d * 16 + lr][sli * 8]);
            our[d] = MFMA16(pf, vr8, our[d]);
            oui[d] = MFMA16(pf, vi8, oui[d]);
        }
        __builtin_amdgcn_s_setprio(0);

        __builtin_amdgcn_sched_barrier(0);
        __builtin_amdgcn_s_barrier();
        __builtin_amdgcn_sched_barrier(0);
    }

    float linv[4];
#pragma unroll
    for (int j = 0; j < 4; ++j) {
        const float lj = __shfl(lrun, lg * 4 + j);
        linv[j] = __builtin_amdgcn_rcpf(lj);
    }
#pragma unroll
    for (int d = 0; d < 4; ++d)
#pragma unroll
        for (int j = 0; j < 4; ++j) {
            const int row = b * 2048 + qb * 64 + w * 16 + lg * 4 + j;
            const int col = h * 64 + d * 16 + lr;
            aor[(size_t)row * 768 + col] = (bf16)(our[d][j] * linv[j]);
            aoi[(size_t)row * 768 + col] = (bf16)(oui[d][j] * linv[j]);
        }
}

// ---------------------------------------------------------------------------
// host launch
// ---------------------------------------------------------------------------
extern "C" void kernel_launch(void* const* d_in, const int* in_sizes, int n_in,
                              void* d_out, int out_size, void* d_ws, size_t ws_size,
                              hipStream_t stream) {
    const float* x      = (const float*)d_in[0];
    const float* n1g    = (const float*)d_in[1];
    const float* n1b    = (const float*)d_in[2];
    const float* qkvwr  = (const float*)d_in[3];
    const float* qkvwi  = (const float*)d_in[4];
    const float* qkvbr  = (const float*)d_in[5];
    const float* qkvbi  = (const float*)d_in[6];
    const float* projwr = (const float*)d_in[7];
    const float* projwi = (const float*)d_in[8];
    const float* projbr = (const float*)d_in[9];
    const float* projbi = (const float*)d_in[10];
    const float* n2g    = (const float*)d_in[11];
    const float* n2b    = (const float*)d_in[12];
    const float* fc1wr  = (const float*)d_in[13];
    const float* fc1wi  = (const float*)d_in[14];
    const float* fc1br  = (const float*)d_in[15];
    const float* fc1bi  = (const float*)d_in[16];
    const float* fc2wr  = (const float*)d_in[17];
    const float* fc2wi  = (const float*)d_in[18];
    const float* fc2br  = (const float*)d_in[19];
    const float* fc2bi  = (const float*)d_in[20];

    const int M = 4096, E = 768, E3 = 2304, HH = 1536;

    char* base = (char*)d_ws;
    size_t off = 0;
    auto alloc = [&](size_t bytes) -> void* {
        void* p = base + off;
        off += (bytes + 255) & ~(size_t)255;
        return p;
    };
    float* xr2 = (float*)alloc((size_t)M * E * 4);
    float* xi2 = (float*)alloc((size_t)M * E * 4);
    bf16* nr   = (bf16*)alloc((size_t)M * E * 2);
    bf16* ni   = (bf16*)alloc((size_t)M * E * 2);
    bf16* wqr  = (bf16*)alloc((size_t)E3 * E * 2);
    bf16* wqi  = (bf16*)alloc((size_t)E3 * E * 2);
    bf16* wpr  = (bf16*)alloc((size_t)E * E * 2);
    bf16* wpi  = (bf16*)alloc((size_t)E * E * 2);
    bf16* w1r  = (bf16*)alloc((size_t)HH * E * 2);
    bf16* w1i  = (bf16*)alloc((size_t)HH * E * 2);
    bf16* w2r  = (bf16*)alloc((size_t)E * HH * 2);
    bf16* w2i  = (bf16*)alloc((size_t)E * HH * 2);
    bf16* qkr  = (bf16*)alloc((size_t)M * E3 * 2);
    bf16* qki  = (bf16*)alloc((size_t)M * E3 * 2);
    bf16* vtr  = (bf16*)alloc((size_t)24 * 64 * 2048 * 2);
    bf16* vti  = (bf16*)alloc((size_t)24 * 64 * 2048 * 2);
    bf16* aor  = (bf16*)alloc((size_t)M * E * 2);
    bf16* aoi  = (bf16*)alloc((size_t)M * E * 2);
    bf16* hr   = (bf16*)alloc((size_t)M * HH * 2);
    bf16* hi   = (bf16*)alloc((size_t)M * HH * 2);

    if (off > ws_size) {
        fill_kernel<<<1024, 256, 0, stream>>>((float*)d_out, 1.0e9f, out_size);
        return;
    }

    // fused weight conversion
    Cvt8 c;
    c.s[0] = qkvwr; c.d[0] = wqr;
    c.s[1] = qkvwi; c.d[1] = wqi;
    c.s[2] = projwr; c.d[2] = wpr;
    c.s[3] = projwi; c.d[3] = wpi;
    c.s[4] = fc1wr; c.d[4] = w1r;
    c.s[5] = fc1wi; c.d[5] = w1i;
    c.s[6] = fc2wr; c.d[6] = w2r;
    c.s[7] = fc2wi; c.d[7] = w2i;
    const int nseg[8] = {E3 * E, E3 * E, E * E, E * E, HH * E, HH * E, E * HH, E * HH};
    int cum = 0;
    for (int k = 0; k < 8; ++k) {
        c.boff[k] = cum;
        cum += nseg[k] / 1024;
    }
    c.boff[8] = cum;
    cvt8_kernel<<<cum, 256, 0, stream>>>(c);

    // LN1 (reads interleaved x directly)
    cln_kernel<true><<<M, 256, 0, stream>>>(x, nullptr, n1g, n1b, nr, ni);
    // QKV: 128x128, dbuf+counted vmcnt, grid 576
    cgemm_kernel<128, 128, 0, 2><<<dim3(32, 18), 256, 0, stream>>>(
        nr, ni, wqr, wqi, qkvbr, qkvbi, nullptr, nullptr, nullptr, nullptr,
        qkr, qki, E3, E);
    // V transpose
    vtrans_kernel<<<dim3(32, 12, 2), 256, 0, stream>>>(qkr, qki, vtr, vti);
    // attention (64 q-rows per block; 768 blocks = 3/CU exact)
    cattn_kernel<<<dim3(32, 12, 2), 256, 0, stream>>>(qkr, qki, vtr, vti, aor, aoi);
    // proj + interleaved-x residual: 128x64, grid 384
    cgemm_kernel<128, 64, 1, 3><<<dim3(32, 12), 256, 0, stream>>>(
        aor, aoi, wpr, wpi, projbr, projbi, x, nullptr, xr2, xi2, nullptr, nullptr,
        E, E);
    // LN2
    cln_kernel<false><<<M, 256, 0, stream>>>(xr2, xi2, n2g, n2b, nr, ni);
    // FC1 + gelu: 128x128, grid 384
    cgemm_kernel<128, 128, 2, 2><<<dim3(32, 12), 256, 0, stream>>>(
        nr, ni, w1r, w1i, fc1br, fc1bi, nullptr, nullptr, nullptr, nullptr,
        hr, hi, HH, E);
    // FC2 + residual -> interleaved d_out: 128x64, grid 384
    cgemm_kernel<128, 64, 3, 3><<<dim3(32, 12), 256, 0, stream>>>(
        hr, hi, w2r, w2i, fc2br, fc2bi, xr2, xi2, (float*)d_out, nullptr,
        nullptr, nullptr, E, HH);
}

// Round 10
// 355.059 us; speedup vs baseline: 1.2672x; 1.0451x over previous
//
#include <hip/hip_runtime.h>
#include <cmath>

typedef __bf16 bf16;
typedef __bf16 bf16x8 __attribute__((ext_vector_type(8)));
typedef __bf16 bf16x4 __attribute__((ext_vector_type(4)));
typedef float  f32x4  __attribute__((ext_vector_type(4)));
typedef unsigned int u32x4 __attribute__((ext_vector_type(4)));

#define MFMA16(a, b, c) __builtin_amdgcn_mfma_f32_16x16x32_bf16((a), (b), (c), 0, 0, 0)
#define LOG2E 1.44269504088896f

static __device__ __forceinline__ void gl_lds16(const void* g, void* l) {
    __builtin_amdgcn_global_load_lds((const __attribute__((address_space(1))) void*)g,
                                     (__attribute__((address_space(3))) void*)l, 16, 0, 0);
}

static __device__ __forceinline__ bf16x8 bneg8(bf16x8 x) {
    u32x4 u = __builtin_bit_cast(u32x4, x);
    u = u ^ 0x80008000u;
    return __builtin_bit_cast(bf16x8, u);
}

static __device__ __forceinline__ f32x4 zero4() {
    return f32x4{0.0f, 0.0f, 0.0f, 0.0f};
}

// ---------------------------------------------------------------------------
// small utility kernels
// ---------------------------------------------------------------------------
__global__ void fill_kernel(float* p, float v, int n) {
    for (int i = blockIdx.x * blockDim.x + threadIdx.x; i < n; i += gridDim.x * blockDim.x)
        p[i] = v;
}

// fused 8-way f32 -> bf16 weight conversion (all sizes % 1024 == 0)
struct Cvt8 {
    const float* s[8];
    bf16* d[8];
    int boff[9];
};
__global__ __launch_bounds__(256) void cvt8_kernel(Cvt8 c) {
    int blk = blockIdx.x;
    int seg = 0;
#pragma unroll
    for (int k = 0; k < 7; ++k)
        if (blk >= c.boff[k + 1]) seg = k + 1;
    const int local = blk - c.boff[seg];
    const int i = local * 1024 + threadIdx.x * 4;
    const float4 v = *(const float4*)(c.s[seg] + i);
    bf16x4 o;
    o[0] = (bf16)v.x; o[1] = (bf16)v.y; o[2] = (bf16)v.z; o[3] = (bf16)v.w;
    *(bf16x4*)(c.d[seg] + i) = o;
}

// ---------------------------------------------------------------------------
// complex magnitude layernorm. ILV=true: xa is interleaved float2 [row][768][2]
// ---------------------------------------------------------------------------
template <bool ILV>
__global__ __launch_bounds__(256) void cln_kernel(
    const float* __restrict__ xa, const float* __restrict__ xb,
    const float* __restrict__ gamma, const float* __restrict__ beta,
    bf16* __restrict__ nr, bf16* __restrict__ ni) {
    __shared__ float red[4];
    const int t = threadIdx.x;
    const size_t base = (size_t)blockIdx.x * 768;

    float r[3], im[3], mg[3];
#pragma unroll
    for (int j = 0; j < 3; ++j) {
        const int f = t + j * 256;
        if (ILV) {
            const float2 v = ((const float2*)xa)[base + f];
            r[j] = v.x;
            im[j] = v.y;
        } else {
            r[j] = xa[base + f];
            im[j] = xb[base + f];
        }
        mg[j] = __builtin_amdgcn_sqrtf(r[j] * r[j] + im[j] * im[j] + 1e-6f);
    }
    float s = mg[0] + mg[1] + mg[2];
#pragma unroll
    for (int m = 32; m >= 1; m >>= 1) s += __shfl_xor(s, m);
    if ((t & 63) == 0) red[t >> 6] = s;
    __syncthreads();
    const float mean = (red[0] + red[1] + red[2] + red[3]) * (1.0f / 768.0f);
    __syncthreads();

    float v2 = 0.0f;
#pragma unroll
    for (int j = 0; j < 3; ++j) {
        const float d = mg[j] - mean;
        v2 += d * d;
    }
#pragma unroll
    for (int m = 32; m >= 1; m >>= 1) v2 += __shfl_xor(v2, m);
    if ((t & 63) == 0) red[t >> 6] = v2;
    __syncthreads();
    const float var = (red[0] + red[1] + red[2] + red[3]) * (1.0f / 768.0f);
    const float rstd = rsqrtf(var + 1e-6f);

#pragma unroll
    for (int j = 0; j < 3; ++j) {
        const int f = t + j * 256;
        const float sc = (mg[j] - mean) * rstd / (mg[j] + 1e-6f);
        nr[base + f] = (bf16)(gamma[2 * f] * (r[j] * sc) + beta[2 * f]);
        ni[base + f] = (bf16)(gamma[2 * f + 1] * (im[j] * sc) + beta[2 * f + 1]);
    }
}

// ---------------------------------------------------------------------------
// complex GEMM (NT): double-buffered fused-plane LDS (row = [real|imag], 128B,
// XOR-swizzled via pre-swizzled global source), counted vmcnt + raw s_barrier,
// XCD-aware block swizzle. (R8 structure; no setprio — m190.)
// ---------------------------------------------------------------------------
template <int BM, int BN, int MODE, int OCC>
__global__ __launch_bounds__(256, OCC) void cgemm_kernel(
    const bf16* __restrict__ Ar, const bf16* __restrict__ Ai,
    const bf16* __restrict__ Wr, const bf16* __restrict__ Wi,
    const float* __restrict__ br, const float* __restrict__ bi,
    const float* __restrict__ resr, const float* __restrict__ resi,
    float* __restrict__ outFr, float* __restrict__ outFi,
    bf16* __restrict__ outBr, bf16* __restrict__ outBi,
    int N, int K) {
    constexpr int MR = BM / 32;
    constexpr int NR = BN / 32;
    constexpr int ASEG = BM / 8;
    constexpr int NSEG = (BM + BN) / 8;
    constexpr int SPW = NSEG / 4;

    __shared__ __align__(16) bf16 sA[2][BM][64];  // row = [real 32 | imag 32]
    __shared__ __align__(16) bf16 sB[2][BN][64];

    const int tid = threadIdx.x;
    const int wave = tid >> 6, lane = tid & 63;
    const int lg = lane >> 4, lr = lane & 15;

    const int nwgx = gridDim.x;
    int wg = blockIdx.y * nwgx + blockIdx.x;
    const int cpx = (nwgx * gridDim.y) >> 3;
    wg = (wg & 7) * cpx + (wg >> 3);
    const int row0 = (wg % nwgx) * BM, col0 = (wg / nwgx) * BN;

    const int wm = (wave >> 1) * (BM / 2), wn = (wave & 1) * (BN / 2);

    const int srow = lane >> 3;
    const int schunk = (lane & 7) ^ srow;
    const int spl = schunk >> 2;
    const int sc8 = (schunk & 3) * 8;

    auto issue = [&](int buf, int kt) {
#pragma unroll
        for (int s = 0; s < SPW; ++s) {
            const int id = wave * SPW + s;
            if (id < ASEG) {
                const int row = id * 8 + srow;
                gl_lds16((spl ? Ai : Ar) + (size_t)(row0 + row) * K + kt + sc8,
                         &sA[buf][id * 8][0]);
            } else {
                const int row = (id - ASEG) * 8 + srow;
                gl_lds16((spl ? Wi : Wr) + (size_t)(col0 + row) * K + kt + sc8,
                         &sB[buf][(id - ASEG) * 8][0]);
            }
        }
    };

    f32x4 accr[MR][NR], acci[MR][NR];
#pragma unroll
    for (int a = 0; a < MR; ++a)
#pragma unroll
        for (int b2 = 0; b2 < NR; ++b2) {
            accr[a][b2] = zero4();
            acci[a][b2] = zero4();
        }

    issue(0, 0);

    const int KT = K / 32;
    for (int kt = 0; kt < KT; ++kt) {
        const int buf = kt & 1;
        if (kt + 1 < KT) {
            issue(buf ^ 1, (kt + 1) * 32);
            __builtin_amdgcn_sched_barrier(0);
            if constexpr (SPW == 8)
                asm volatile("s_waitcnt vmcnt(8)" ::: "memory");
            else if constexpr (SPW == 6)
                asm volatile("s_waitcnt vmcnt(6)" ::: "memory");
            else
                asm volatile("s_waitcnt vmcnt(0)" ::: "memory");
        } else {
            asm volatile("s_waitcnt vmcnt(0)" ::: "memory");
        }
        __builtin_amdgcn_sched_barrier(0);
        __builtin_amdgcn_s_barrier();
        __builtin_amdgcn_sched_barrier(0);

        bf16x8 ar[MR], ai[MR], an[MR];
#pragma unroll
        for (int mt = 0; mt < MR; ++mt) {
            const int rr = wm + mt * 16 + lr;
            const int slr = lg ^ (rr & 7);
            const int sli = (4 + lg) ^ (rr & 7);
            ar[mt] = *(const bf16x8*)(&sA[buf][rr][slr * 8]);
            ai[mt] = *(const bf16x8*)(&sA[buf][rr][sli * 8]);
            an[mt] = bneg8(ai[mt]);
        }
#pragma unroll
        for (int nt = 0; nt < NR; ++nt) {
            const int rr = wn + nt * 16 + lr;
            const int slr = lg ^ (rr & 7);
            const int sli = (4 + lg) ^ (rr & 7);
            const bf16x8 br8 = *(const bf16x8*)(&sB[buf][rr][slr * 8]);
            const bf16x8 bi8 = *(const bf16x8*)(&sB[buf][rr][sli * 8]);
#pragma unroll
            for (int mt = 0; mt < MR; ++mt) {
                accr[mt][nt] = MFMA16(ar[mt], br8, accr[mt][nt]);
                accr[mt][nt] = MFMA16(an[mt], bi8, accr[mt][nt]);
                acci[mt][nt] = MFMA16(ar[mt], bi8, acci[mt][nt]);
                acci[mt][nt] = MFMA16(ai[mt], br8, acci[mt][nt]);
            }
        }

        if (kt + 1 < KT) {
            __builtin_amdgcn_sched_barrier(0);
            __builtin_amdgcn_s_barrier();
            __builtin_amdgcn_sched_barrier(0);
        }
    }

#pragma unroll
    for (int nt = 0; nt < NR; ++nt) {
        const int col = col0 + wn + nt * 16 + lr;
        const float bre = br[col], bie = bi[col];
#pragma unroll
        for (int mt = 0; mt < MR; ++mt) {
#pragma unroll
            for (int j = 0; j < 4; ++j) {
                const int row = row0 + wm + mt * 16 + lg * 4 + j;
                float vr = accr[mt][nt][j] + bre;
                float vi = acci[mt][nt][j] + bie;
                const size_t o = (size_t)row * N + col;
                if (MODE == 0) {
                    outBr[o] = (bf16)vr;
                    outBi[o] = (bf16)vi;
                } else if (MODE == 1) {
                    const float2 rv = ((const float2*)resr)[(size_t)row * 768 + col];
                    outFr[o] = rv.x + vr;
                    outFi[o] = rv.y + vi;
                } else if (MODE == 2) {
                    // fast tanh-GELU: x * e / (e+1), e = exp2(x*(1+0.044715x^2)*2.3022082)
                    const float t2r = fmaf(vr * vr, 0.044715f, 1.0f);
                    const float er = __builtin_amdgcn_exp2f(vr * t2r * 2.3022082f);
                    vr = vr - vr * __builtin_amdgcn_rcpf(er + 1.0f);
                    const float t2i = fmaf(vi * vi, 0.044715f, 1.0f);
                    const float ei = __builtin_amdgcn_exp2f(vi * t2i * 2.3022082f);
                    vi = vi - vi * __builtin_amdgcn_rcpf(ei + 1.0f);
                    outBr[o] = (bf16)vr;
                    outBi[o] = (bf16)vi;
                } else {
                    const size_t ro = (size_t)row * 768 + col;
                    outFr[(size_t)row * 1536 + 2 * col]     = resr[ro] + vr;
                    outFr[(size_t)row * 1536 + 2 * col + 1] = resi[ro] + vi;
                }
            }
        }
    }
}

// ---------------------------------------------------------------------------
// transpose V slice of qkv into [B*nH][64 d][2048 n] bf16 planes
// ---------------------------------------------------------------------------
__global__ __launch_bounds__(256) void vtrans_kernel(
    const bf16* __restrict__ qkvr, const bf16* __restrict__ qkvi,
    bf16* __restrict__ vtr, bf16* __restrict__ vti) {
    __shared__ bf16 sr[64][65];
    __shared__ bf16 si[64][65];
    const int t = threadIdx.x;
    const int nb = blockIdx.x, h = blockIdx.y, b = blockIdx.z;
    const size_t ld = 2304;
    const bf16* srcr = qkvr + (size_t)(b * 2048 + nb * 64) * ld + 1536 + h * 64;
    const bf16* srci = qkvi + (size_t)(b * 2048 + nb * 64) * ld + 1536 + h * 64;
#pragma unroll
    for (int j = 0; j < 16; ++j) {
        const int idx = t + 256 * j;
        const int n = idx >> 6, d = idx & 63;
        sr[n][d] = srcr[(size_t)n * ld + d];
        si[n][d] = srci[(size_t)n * ld + d];
    }
    __syncthreads();
    bf16* dstr = vtr + (size_t)(b * 12 + h) * 64 * 2048 + nb * 64;
    bf16* dsti = vti + (size_t)(b * 12 + h) * 64 * 2048 + nb * 64;
#pragma unroll
    for (int j = 0; j < 16; ++j) {
        const int idx = t + 256 * j;
        const int d = idx >> 6, n = idx & 63;
        dstr[(size_t)d * 2048 + n] = sr[n][d];
        dsti[(size_t)d * 2048 + n] = si[n][d];
    }
}

// ---------------------------------------------------------------------------
// fused complex flash attention v8: R9 softmax chain + T15 deferred-PV
// pipeline (PV of tile k-1 overlaps softmax of tile k); V in 3-slot LDS ring.
// ---------------------------------------------------------------------------
__global__ __launch_bounds__(256, 3) void cattn_kernel(
    const bf16* __restrict__ qkvr, const bf16* __restrict__ qkvi,
    const bf16* __restrict__ vtr, const bf16* __restrict__ vti,
    bf16* __restrict__ aor, bf16* __restrict__ aoi) {
    __shared__ __align__(16) bf16 sK[2][2][32][64];  // double buffer
    __shared__ __align__(16) bf16 sV[3][64][64];     // triple ring (fused planes)
    __shared__ __align__(16) bf16 sP[4][16][40];

    const int tid = threadIdx.x;
    const int w = tid >> 6, lane = tid & 63;
    const int lg = lane >> 4, lr = lane & 15;
    const int qb = blockIdx.x, h = blockIdx.y, b = blockIdx.z;
    const int ld = 2304;

    const int s_krow = lane >> 3;
    const int s_kch8 = ((lane & 7) ^ s_krow) * 8;
    const int s_vlog = (lane & 7) ^ s_krow;
    const int s_vpl = s_vlog >> 2;
    const int s_vk8 = (s_vlog & 3) * 8;

    const bf16* kbase0 = qkvr + (size_t)b * 2048 * ld + 768 + h * 64;
    const bf16* kbase1 = qkvi + (size_t)b * 2048 * ld + 768 + h * 64;
    const bf16* vbase = (s_vpl ? vti : vtr) + (size_t)(b * 12 + h) * 64 * 2048;

    const bf16* kp0 = kbase0 + (size_t)(w * 8 + s_krow) * ld + s_kch8;
    const bf16* kp1 = kbase1 + (size_t)(w * 8 + s_krow) * ld + s_kch8;
    const bf16* vp0 = vbase + (size_t)(w * 8 + s_krow) * 2048 + s_vk8;
    const bf16* vp1 = vbase + (size_t)((4 + w) * 8 + s_krow) * 2048 + s_vk8;

    auto stage = [&](int kb, int vs) {
        gl_lds16(kp0, &sK[kb][0][w * 8][0]);
        gl_lds16(kp1, &sK[kb][1][w * 8][0]);
        gl_lds16(vp0, &sV[vs][w * 8][0]);
        gl_lds16(vp1, &sV[vs][(4 + w) * 8][0]);
        kp0 += 32 * ld;
        kp1 += 32 * ld;
        vp0 += 32;
        vp1 += 32;
    };

    stage(0, 0);

    const size_t qoff = (size_t)(b * 2048 + qb * 64 + w * 16 + lr) * ld + h * 64;
    bf16x8 aqr[2], aqi[2];
#pragma unroll
    for (int ks = 0; ks < 2; ++ks) {
        aqr[ks] = *(const bf16x8*)(qkvr + qoff + ks * 32 + lg * 8);
        aqi[ks] = *(const bf16x8*)(qkvi + qoff + ks * 32 + lg * 8);
    }

    f32x4 our[4], oui[4];
#pragma unroll
    for (int d = 0; d < 4; ++d) {
        our[d] = zero4();
        oui[d] = zero4();
    }
    const float C1 = 0.125f * LOG2E;
    float mrun = -1e30f, lrun = 0.0f;
    float thr2 = -1.0f;
    float mC2 = 0.0f;

    bf16x8 pfPrev = __builtin_bit_cast(bf16x8, u32x4{0u, 0u, 0u, 0u});
    int vcur = 0, vlast = 0;
    const int slr = lg ^ (lr & 7);        // V real slot for this lane's rows
    const int sli = (4 + lg) ^ (lr & 7);  // V imag slot

    for (int kt = 0; kt < 64; ++kt) {
        const int kcur = kt & 1;
        int vnext = vcur + 1;
        if (vnext == 3) vnext = 0;
        if (kt < 63) {
            stage(kcur ^ 1, vnext);
            __builtin_amdgcn_sched_barrier(0);
            asm volatile("s_waitcnt vmcnt(4)" ::: "memory");
        } else {
            asm volatile("s_waitcnt vmcnt(0)" ::: "memory");
        }
        __builtin_amdgcn_sched_barrier(0);
        __builtin_amdgcn_s_barrier();
        __builtin_amdgcn_sched_barrier(0);

        // ---- QK^T(kt) + PV(kt-1): one MFMA region ----
        f32x4 str[2], sti[2];
        str[0] = zero4(); str[1] = zero4();
        sti[0] = zero4(); sti[1] = zero4();
        __builtin_amdgcn_s_setprio(1);
#pragma unroll
        for (int t = 0; t < 2; ++t) {
#pragma unroll
            for (int ks = 0; ks < 2; ++ks) {
                const int ch = ((ks << 2) | lg) ^ (lr & 7);
                const bf16x8 kr8 = *(const bf16x8*)(&sK[kcur][0][t * 16 + lr][ch * 8]);
                const bf16x8 ki8 = *(const bf16x8*)(&sK[kcur][1][t * 16 + lr][ch * 8]);
                const bf16x8 kn8 = bneg8(kr8);
                str[t] = MFMA16(kr8, aqr[ks], str[t]);
                str[t] = MFMA16(ki8, aqi[ks], str[t]);
                sti[t] = MFMA16(ki8, aqr[ks], sti[t]);
                sti[t] = MFMA16(kn8, aqi[ks], sti[t]);
            }
        }
        if (kt > 0) {
#pragma unroll
            for (int d = 0; d < 4; ++d) {
                const bf16x8 vr8 = *(const bf16x8*)(&sV[vlast][d * 16 + lr][slr * 8]);
                const bf16x8 vi8 = *(const bf16x8*)(&sV[vlast][d * 16 + lr][sli * 8]);
                our[d] = MFMA16(pfPrev, vr8, our[d]);
                oui[d] = MFMA16(pfPrev, vi8, oui[d]);
            }
        }
        __builtin_amdgcn_s_setprio(0);

        // ---- softmax(kt): squared magnitudes, defer-max, fused exp2 ----
        float v[8];
        float vmax = 0.0f;
#pragma unroll
        for (int t = 0; t < 2; ++t)
#pragma unroll
            for (int j = 0; j < 4; ++j) {
                const float sr = str[t][j], si = sti[t][j];
                const float vv = fmaf(sr, sr, fmaf(si, si, 1e-8f));
                v[t * 4 + j] = vv;
                vmax = fmaxf(vmax, vv);
            }
        vmax = fmaxf(vmax, __shfl_xor(vmax, 16));
        vmax = fmaxf(vmax, __shfl_xor(vmax, 32));

        if (!__all(vmax <= thr2)) {
            // rescale AFTER PV(kt-1) has accumulated (data dep enforces order)
            const float tm = __builtin_amdgcn_sqrtf(vmax) * 0.125f;
            const float mnew = fmaxf(mrun, tm);
            const float corr = __builtin_amdgcn_exp2f((mrun - mnew) * LOG2E);
            float cj[4];
#pragma unroll
            for (int j = 0; j < 4; ++j) cj[j] = __shfl(corr, lg * 4 + j);
#pragma unroll
            for (int d = 0; d < 4; ++d)
#pragma unroll
                for (int j = 0; j < 4; ++j) {
                    our[d][j] *= cj[j];
                    oui[d][j] *= cj[j];
                }
            lrun *= corr;
            mrun = mnew;
            const float m8 = mrun + 8.0f;
            thr2 = 64.0f * m8 * m8;
            mC2 = -mrun * LOG2E;
        }

        float p[8];
        float ls = 0.0f;
#pragma unroll
        for (int i = 0; i < 8; ++i) {
            p[i] = __builtin_amdgcn_exp2f(
                fmaf(__builtin_amdgcn_sqrtf(v[i]), C1, mC2));
            ls += p[i];
        }
        ls += __shfl_xor(ls, 16);
        ls += __shfl_xor(ls, 32);
        lrun += ls;

        // ---- pack P(kt) -> LDS -> pfPrev (consumed next iter) ----
#pragma unroll
        for (int t = 0; t < 2; ++t) {
            bf16x4 pk;
#pragma unroll
            for (int j = 0; j < 4; ++j) pk[j] = (bf16)p[t * 4 + j];
            *(bf16x4*)(&sP[w][lr][t * 16 + lg * 4]) = pk;
        }
        pfPrev = *(const bf16x8*)(&sP[w][lr][lg * 8]);

        vlast = vcur;
        vcur = vnext;

        __builtin_amdgcn_sched_barrier(0);
        __builtin_amdgcn_s_barrier();
        __builtin_amdgcn_sched_barrier(0);
    }

    // final PV for tile 63
#pragma unroll
    for (int d = 0; d < 4; ++d) {
        const bf16x8 vr8 = *(const bf16x8*)(&sV[vlast][d * 16 + lr][slr * 8]);
        const bf16x8 vi8 = *(const bf16x8*)(&sV[vlast][d * 16 + lr][sli * 8]);
        our[d] = MFMA16(pfPrev, vr8, our[d]);
        oui[d] = MFMA16(pfPrev, vi8, oui[d]);
    }

    float linv[4];
#pragma unroll
    for (int j = 0; j < 4; ++j) {
        const float lj = __shfl(lrun, lg * 4 + j);
        linv[j] = __builtin_amdgcn_rcpf(lj);
    }
#pragma unroll
    for (int d = 0; d < 4; ++d)
#pragma unroll
        for (int j = 0; j < 4; ++j) {
            const int row = b * 2048 + qb * 64 + w * 16 + lg * 4 + j;
            const int col = h * 64 + d * 16 + lr;
            aor[(size_t)row * 768 + col] = (bf16)(our[d][j] * linv[j]);
            aoi[(size_t)row * 768 + col] = (bf16)(oui[d][j] * linv[j]);
        }
}

// ---------------------------------------------------------------------------
// host launch
// ---------------------------------------------------------------------------
extern "C" void kernel_launch(void* const* d_in, const int* in_sizes, int n_in,
                              void* d_out, int out_size, void* d_ws, size_t ws_size,
                              hipStream_t stream) {
    const float* x      = (const float*)d_in[0];
    const float* n1g    = (const float*)d_in[1];
    const float* n1b    = (const float*)d_in[2];
    const float* qkvwr  = (const float*)d_in[3];
    const float* qkvwi  = (const float*)d_in[4];
    const float* qkvbr  = (const float*)d_in[5];
    const float* qkvbi  = (const float*)d_in[6];
    const float* projwr = (const float*)d_in[7];
    const float* projwi = (const float*)d_in[8];
    const float* projbr = (const float*)d_in[9];
    const float* projbi = (const float*)d_in[10];
    const float* n2g    = (const float*)d_in[11];
    const float* n2b    = (const float*)d_in[12];
    const float* fc1wr  = (const float*)d_in[13];
    const float* fc1wi  = (const float*)d_in[14];
    const float* fc1br  = (const float*)d_in[15];
    const float* fc1bi  = (const float*)d_in[16];
    const float* fc2wr  = (const float*)d_in[17];
    const float* fc2wi  = (const float*)d_in[18];
    const float* fc2br  = (const float*)d_in[19];
    const float* fc2bi  = (const float*)d_in[20];

    const int M = 4096, E = 768, E3 = 2304, HH = 1536;

    char* base = (char*)d_ws;
    size_t off = 0;
    auto alloc = [&](size_t bytes) -> void* {
        void* p = base + off;
        off += (bytes + 255) & ~(size_t)255;
        return p;
    };
    float* xr2 = (float*)alloc((size_t)M * E * 4);
    float* xi2 = (float*)alloc((size_t)M * E * 4);
    bf16* nr   = (bf16*)alloc((size_t)M * E * 2);
    bf16* ni   = (bf16*)alloc((size_t)M * E * 2);
    bf16* wqr  = (bf16*)alloc((size_t)E3 * E * 2);
    bf16* wqi  = (bf16*)alloc((size_t)E3 * E * 2);
    bf16* wpr  = (bf16*)alloc((size_t)E * E * 2);
    bf16* wpi  = (bf16*)alloc((size_t)E * E * 2);
    bf16* w1r  = (bf16*)alloc((size_t)HH * E * 2);
    bf16* w1i  = (bf16*)alloc((size_t)HH * E * 2);
    bf16* w2r  = (bf16*)alloc((size_t)E * HH * 2);
    bf16* w2i  = (bf16*)alloc((size_t)E * HH * 2);
    bf16* qkr  = (bf16*)alloc((size_t)M * E3 * 2);
    bf16* qki  = (bf16*)alloc((size_t)M * E3 * 2);
    bf16* vtr  = (bf16*)alloc((size_t)24 * 64 * 2048 * 2);
    bf16* vti  = (bf16*)alloc((size_t)24 * 64 * 2048 * 2);
    bf16* aor  = (bf16*)alloc((size_t)M * E * 2);
    bf16* aoi  = (bf16*)alloc((size_t)M * E * 2);
    bf16* hr   = (bf16*)alloc((size_t)M * HH * 2);
    bf16* hi   = (bf16*)alloc((size_t)M * HH * 2);

    if (off > ws_size) {
        fill_kernel<<<1024, 256, 0, stream>>>((float*)d_out, 1.0e9f, out_size);
        return;
    }

    // fused weight conversion
    Cvt8 c;
    c.s[0] = qkvwr; c.d[0] = wqr;
    c.s[1] = qkvwi; c.d[1] = wqi;
    c.s[2] = projwr; c.d[2] = wpr;
    c.s[3] = projwi; c.d[3] = wpi;
    c.s[4] = fc1wr; c.d[4] = w1r;
    c.s[5] = fc1wi; c.d[5] = w1i;
    c.s[6] = fc2wr; c.d[6] = w2r;
    c.s[7] = fc2wi; c.d[7] = w2i;
    const int nseg[8] = {E3 * E, E3 * E, E * E, E * E, HH * E, HH * E, E * HH, E * HH};
    int cum = 0;
    for (int k = 0; k < 8; ++k) {
        c.boff[k] = cum;
        cum += nseg[k] / 1024;
    }
    c.boff[8] = cum;
    cvt8_kernel<<<cum, 256, 0, stream>>>(c);

    // LN1 (reads interleaved x directly)
    cln_kernel<true><<<M, 256, 0, stream>>>(x, nullptr, n1g, n1b, nr, ni);
    // QKV: 128x128, dbuf+counted vmcnt, grid 576
    cgemm_kernel<128, 128, 0, 2><<<dim3(32, 18), 256, 0, stream>>>(
        nr, ni, wqr, wqi, qkvbr, qkvbi, nullptr, nullptr, nullptr, nullptr,
        qkr, qki, E3, E);
    // V transpose
    vtrans_kernel<<<dim3(32, 12, 2), 256, 0, stream>>>(qkr, qki, vtr, vti);
    // attention (64 q-rows per block; 768 blocks = 3/CU exact)
    cattn_kernel<<<dim3(32, 12, 2), 256, 0, stream>>>(qkr, qki, vtr, vti, aor, aoi);
    // proj + interleaved-x residual: 128x64, grid 384
    cgemm_kernel<128, 64, 1, 3><<<dim3(32, 12), 256, 0, stream>>>(
        aor, aoi, wpr, wpi, projbr, projbi, x, nullptr, xr2, xi2, nullptr, nullptr,
        E, E);
    // LN2
    cln_kernel<false><<<M, 256, 0, stream>>>(xr2, xi2, n2g, n2b, nr, ni);
    // FC1 + fast GELU: 128x128, grid 384
    cgemm_kernel<128, 128, 2, 2><<<dim3(32, 12), 256, 0, stream>>>(
        nr, ni, w1r, w1i, fc1br, fc1bi, nullptr, nullptr, nullptr, nullptr,
        hr, hi, HH, E);
    // FC2 + residual -> interleaved d_out: 128x64, grid 384
    cgemm_kernel<128, 64, 3, 3><<<dim3(32, 12), 256, 0, stream>>>(
        hr, hi, w2r, w2i, fc2br, fc2bi, xr2, xi2, (float*)d_out, nullptr,
        nullptr, nullptr, E, HH);
}

// Round 11
// 340.394 us; speedup vs baseline: 1.3217x; 1.0431x over previous
//
#include <hip/hip_runtime.h>
#include <cmath>

typedef __bf16 bf16;
typedef __bf16 bf16x8 __attribute__((ext_vector_type(8)));
typedef __bf16 bf16x4 __attribute__((ext_vector_type(4)));
typedef float  f32x4  __attribute__((ext_vector_type(4)));
typedef unsigned int u32x4 __attribute__((ext_vector_type(4)));

#define MFMA16(a, b, c) __builtin_amdgcn_mfma_f32_16x16x32_bf16((a), (b), (c), 0, 0, 0)
#define LOG2E 1.44269504088896f

static __device__ __forceinline__ void gl_lds16(const void* g, void* l) {
    __builtin_amdgcn_global_load_lds((const __attribute__((address_space(1))) void*)g,
                                     (__attribute__((address_space(3))) void*)l, 16, 0, 0);
}

static __device__ __forceinline__ bf16x8 bneg8(bf16x8 x) {
    u32x4 u = __builtin_bit_cast(u32x4, x);
    u = u ^ 0x80008000u;
    return __builtin_bit_cast(bf16x8, u);
}

static __device__ __forceinline__ f32x4 zero4() {
    return f32x4{0.0f, 0.0f, 0.0f, 0.0f};
}

// ---------------------------------------------------------------------------
// small utility kernels
// ---------------------------------------------------------------------------
__global__ void fill_kernel(float* p, float v, int n) {
    for (int i = blockIdx.x * blockDim.x + threadIdx.x; i < n; i += gridDim.x * blockDim.x)
        p[i] = v;
}

// fused 8-way f32 -> bf16 weight conversion (all sizes % 1024 == 0)
struct Cvt8 {
    const float* s[8];
    bf16* d[8];
    int boff[9];
};
__global__ __launch_bounds__(256) void cvt8_kernel(Cvt8 c) {
    int blk = blockIdx.x;
    int seg = 0;
#pragma unroll
    for (int k = 0; k < 7; ++k)
        if (blk >= c.boff[k + 1]) seg = k + 1;
    const int local = blk - c.boff[seg];
    const int i = local * 1024 + threadIdx.x * 4;
    const float4 v = *(const float4*)(c.s[seg] + i);
    bf16x4 o;
    o[0] = (bf16)v.x; o[1] = (bf16)v.y; o[2] = (bf16)v.z; o[3] = (bf16)v.w;
    *(bf16x4*)(c.d[seg] + i) = o;
}

// ---------------------------------------------------------------------------
// complex magnitude layernorm. ILV=true: xa is interleaved float2 [row][768][2]
// ---------------------------------------------------------------------------
template <bool ILV>
__global__ __launch_bounds__(256) void cln_kernel(
    const float* __restrict__ xa, const float* __restrict__ xb,
    const float* __restrict__ gamma, const float* __restrict__ beta,
    bf16* __restrict__ nr, bf16* __restrict__ ni) {
    __shared__ float red[4];
    const int t = threadIdx.x;
    const size_t base = (size_t)blockIdx.x * 768;

    float r[3], im[3], mg[3];
#pragma unroll
    for (int j = 0; j < 3; ++j) {
        const int f = t + j * 256;
        if (ILV) {
            const float2 v = ((const float2*)xa)[base + f];
            r[j] = v.x;
            im[j] = v.y;
        } else {
            r[j] = xa[base + f];
            im[j] = xb[base + f];
        }
        mg[j] = __builtin_amdgcn_sqrtf(r[j] * r[j] + im[j] * im[j] + 1e-6f);
    }
    float s = mg[0] + mg[1] + mg[2];
#pragma unroll
    for (int m = 32; m >= 1; m >>= 1) s += __shfl_xor(s, m);
    if ((t & 63) == 0) red[t >> 6] = s;
    __syncthreads();
    const float mean = (red[0] + red[1] + red[2] + red[3]) * (1.0f / 768.0f);
    __syncthreads();

    float v2 = 0.0f;
#pragma unroll
    for (int j = 0; j < 3; ++j) {
        const float d = mg[j] - mean;
        v2 += d * d;
    }
#pragma unroll
    for (int m = 32; m >= 1; m >>= 1) v2 += __shfl_xor(v2, m);
    if ((t & 63) == 0) red[t >> 6] = v2;
    __syncthreads();
    const float var = (red[0] + red[1] + red[2] + red[3]) * (1.0f / 768.0f);
    const float rstd = rsqrtf(var + 1e-6f);

#pragma unroll
    for (int j = 0; j < 3; ++j) {
        const int f = t + j * 256;
        const float sc = (mg[j] - mean) * rstd / (mg[j] + 1e-6f);
        nr[base + f] = (bf16)(gamma[2 * f] * (r[j] * sc) + beta[2 * f]);
        ni[base + f] = (bf16)(gamma[2 * f + 1] * (im[j] * sc) + beta[2 * f + 1]);
    }
}

// ---------------------------------------------------------------------------
// complex GEMM (NT): double-buffered fused-plane LDS, counted vmcnt,
// SINGLE barrier per K-step (bottom barrier proven redundant: per-wave
// vmcnt guards staged-data visibility; read-before-overwrite ordered by
// the top barrier since iter t-1 reads are consumed before arrival).
// ---------------------------------------------------------------------------
template <int BM, int BN, int MODE, int OCC>
__global__ __launch_bounds__(256, OCC) void cgemm_kernel(
    const bf16* __restrict__ Ar, const bf16* __restrict__ Ai,
    const bf16* __restrict__ Wr, const bf16* __restrict__ Wi,
    const float* __restrict__ br, const float* __restrict__ bi,
    const float* __restrict__ resr, const float* __restrict__ resi,
    float* __restrict__ outFr, float* __restrict__ outFi,
    bf16* __restrict__ outBr, bf16* __restrict__ outBi,
    int N, int K) {
    constexpr int MR = BM / 32;
    constexpr int NR = BN / 32;
    constexpr int ASEG = BM / 8;
    constexpr int NSEG = (BM + BN) / 8;
    constexpr int SPW = NSEG / 4;

    __shared__ __align__(16) bf16 sA[2][BM][64];  // row = [real 32 | imag 32]
    __shared__ __align__(16) bf16 sB[2][BN][64];

    const int tid = threadIdx.x;
    const int wave = tid >> 6, lane = tid & 63;
    const int lg = lane >> 4, lr = lane & 15;

    const int nwgx = gridDim.x;
    int wg = blockIdx.y * nwgx + blockIdx.x;
    const int cpx = (nwgx * gridDim.y) >> 3;
    wg = (wg & 7) * cpx + (wg >> 3);
    const int row0 = (wg % nwgx) * BM, col0 = (wg / nwgx) * BN;

    const int wm = (wave >> 1) * (BM / 2), wn = (wave & 1) * (BN / 2);

    const int srow = lane >> 3;
    const int schunk = (lane & 7) ^ srow;
    const int spl = schunk >> 2;
    const int sc8 = (schunk & 3) * 8;

    auto issue = [&](int buf, int kt) {
#pragma unroll
        for (int s = 0; s < SPW; ++s) {
            const int id = wave * SPW + s;
            if (id < ASEG) {
                const int row = id * 8 + srow;
                gl_lds16((spl ? Ai : Ar) + (size_t)(row0 + row) * K + kt + sc8,
                         &sA[buf][id * 8][0]);
            } else {
                const int row = (id - ASEG) * 8 + srow;
                gl_lds16((spl ? Wi : Wr) + (size_t)(col0 + row) * K + kt + sc8,
                         &sB[buf][(id - ASEG) * 8][0]);
            }
        }
    };

    f32x4 accr[MR][NR], acci[MR][NR];
#pragma unroll
    for (int a = 0; a < MR; ++a)
#pragma unroll
        for (int b2 = 0; b2 < NR; ++b2) {
            accr[a][b2] = zero4();
            acci[a][b2] = zero4();
        }

    issue(0, 0);

    const int KT = K / 32;
    for (int kt = 0; kt < KT; ++kt) {
        const int buf = kt & 1;
        if (kt + 1 < KT) {
            issue(buf ^ 1, (kt + 1) * 32);
            __builtin_amdgcn_sched_barrier(0);
            if constexpr (SPW == 8)
                asm volatile("s_waitcnt vmcnt(8)" ::: "memory");
            else if constexpr (SPW == 6)
                asm volatile("s_waitcnt vmcnt(6)" ::: "memory");
            else
                asm volatile("s_waitcnt vmcnt(0)" ::: "memory");
        } else {
            asm volatile("s_waitcnt vmcnt(0)" ::: "memory");
        }
        __builtin_amdgcn_sched_barrier(0);
        __builtin_amdgcn_s_barrier();  // the only barrier per K-step
        __builtin_amdgcn_sched_barrier(0);

        bf16x8 ar[MR], ai[MR], an[MR];
#pragma unroll
        for (int mt = 0; mt < MR; ++mt) {
            const int rr = wm + mt * 16 + lr;
            const int slr = lg ^ (rr & 7);
            const int sli = (4 + lg) ^ (rr & 7);
            ar[mt] = *(const bf16x8*)(&sA[buf][rr][slr * 8]);
            ai[mt] = *(const bf16x8*)(&sA[buf][rr][sli * 8]);
            an[mt] = bneg8(ai[mt]);
        }
#pragma unroll
        for (int nt = 0; nt < NR; ++nt) {
            const int rr = wn + nt * 16 + lr;
            const int slr = lg ^ (rr & 7);
            const int sli = (4 + lg) ^ (rr & 7);
            const bf16x8 br8 = *(const bf16x8*)(&sB[buf][rr][slr * 8]);
            const bf16x8 bi8 = *(const bf16x8*)(&sB[buf][rr][sli * 8]);
#pragma unroll
            for (int mt = 0; mt < MR; ++mt) {
                accr[mt][nt] = MFMA16(ar[mt], br8, accr[mt][nt]);
                accr[mt][nt] = MFMA16(an[mt], bi8, accr[mt][nt]);
                acci[mt][nt] = MFMA16(ar[mt], bi8, acci[mt][nt]);
                acci[mt][nt] = MFMA16(ai[mt], br8, acci[mt][nt]);
            }
        }
    }

#pragma unroll
    for (int nt = 0; nt < NR; ++nt) {
        const int col = col0 + wn + nt * 16 + lr;
        const float bre = br[col], bie = bi[col];
#pragma unroll
        for (int mt = 0; mt < MR; ++mt) {
#pragma unroll
            for (int j = 0; j < 4; ++j) {
                const int row = row0 + wm + mt * 16 + lg * 4 + j;
                float vr = accr[mt][nt][j] + bre;
                float vi = acci[mt][nt][j] + bie;
                const size_t o = (size_t)row * N + col;
                if (MODE == 0) {
                    outBr[o] = (bf16)vr;
                    outBi[o] = (bf16)vi;
                } else if (MODE == 1) {
                    const float2 rv = ((const float2*)resr)[(size_t)row * 768 + col];
                    outFr[o] = rv.x + vr;
                    outFi[o] = rv.y + vi;
                } else if (MODE == 2) {
                    // fast tanh-GELU
                    const float t2r = fmaf(vr * vr, 0.044715f, 1.0f);
                    const float er = __builtin_amdgcn_exp2f(vr * t2r * 2.3022082f);
                    vr = vr - vr * __builtin_amdgcn_rcpf(er + 1.0f);
                    const float t2i = fmaf(vi * vi, 0.044715f, 1.0f);
                    const float ei = __builtin_amdgcn_exp2f(vi * t2i * 2.3022082f);
                    vi = vi - vi * __builtin_amdgcn_rcpf(ei + 1.0f);
                    outBr[o] = (bf16)vr;
                    outBi[o] = (bf16)vi;
                } else {
                    const size_t ro = (size_t)row * 768 + col;
                    outFr[(size_t)row * 1536 + 2 * col]     = resr[ro] + vr;
                    outFr[(size_t)row * 1536 + 2 * col + 1] = resi[ro] + vi;
                }
            }
        }
    }
}

// ---------------------------------------------------------------------------
// transpose V slice of qkv into [B*nH][64 d][2048 n] bf16 planes
// ---------------------------------------------------------------------------
__global__ __launch_bounds__(256) void vtrans_kernel(
    const bf16* __restrict__ qkvr, const bf16* __restrict__ qkvi,
    bf16* __restrict__ vtr, bf16* __restrict__ vti) {
    __shared__ bf16 sr[64][65];
    __shared__ bf16 si[64][65];
    const int t = threadIdx.x;
    const int nb = blockIdx.x, h = blockIdx.y, b = blockIdx.z;
    const size_t ld = 2304;
    const bf16* srcr = qkvr + (size_t)(b * 2048 + nb * 64) * ld + 1536 + h * 64;
    const bf16* srci = qkvi + (size_t)(b * 2048 + nb * 64) * ld + 1536 + h * 64;
#pragma unroll
    for (int j = 0; j < 16; ++j) {
        const int idx = t + 256 * j;
        const int n = idx >> 6, d = idx & 63;
        sr[n][d] = srcr[(size_t)n * ld + d];
        si[n][d] = srci[(size_t)n * ld + d];
    }
    __syncthreads();
    bf16* dstr = vtr + (size_t)(b * 12 + h) * 64 * 2048 + nb * 64;
    bf16* dsti = vti + (size_t)(b * 12 + h) * 64 * 2048 + nb * 64;
#pragma unroll
    for (int j = 0; j < 16; ++j) {
        const int idx = t + 256 * j;
        const int d = idx >> 6, n = idx & 63;
        dstr[(size_t)d * 2048 + n] = sr[n][d];
        dsti[(size_t)d * 2048 + n] = si[n][d];
    }
}

// ---------------------------------------------------------------------------
// fused complex flash attention v9:
// single barrier per iteration (K dbuf + V ring-3 make the bottom barrier
// redundant); steady-state shuffle-free softmax (vmax reduce only inside the
// rare rescale branch; per-lane partial lrun reduced once at the end);
// deferred-PV pipeline (T15); defer-max (T13); setprio on MFMA clusters.
// ---------------------------------------------------------------------------
__global__ __launch_bounds__(256, 3) void cattn_kernel(
    const bf16* __restrict__ qkvr, const bf16* __restrict__ qkvi,
    const bf16* __restrict__ vtr, const bf16* __restrict__ vti,
    bf16* __restrict__ aor, bf16* __restrict__ aoi) {
    __shared__ __align__(16) bf16 sK[2][2][32][64];  // double buffer
    __shared__ __align__(16) bf16 sV[3][64][64];     // triple ring (fused planes)
    __shared__ __align__(16) bf16 sP[4][16][40];

    const int tid = threadIdx.x;
    const int w = tid >> 6, lane = tid & 63;
    const int lg = lane >> 4, lr = lane & 15;
    const int qb = blockIdx.x, h = blockIdx.y, b = blockIdx.z;
    const int ld = 2304;

    const int s_krow = lane >> 3;
    const int s_kch8 = ((lane & 7) ^ s_krow) * 8;
    const int s_vlog = (lane & 7) ^ s_krow;
    const int s_vpl = s_vlog >> 2;
    const int s_vk8 = (s_vlog & 3) * 8;

    const bf16* kbase0 = qkvr + (size_t)b * 2048 * ld + 768 + h * 64;
    const bf16* kbase1 = qkvi + (size_t)b * 2048 * ld + 768 + h * 64;
    const bf16* vbase = (s_vpl ? vti : vtr) + (size_t)(b * 12 + h) * 64 * 2048;

    const bf16* kp0 = kbase0 + (size_t)(w * 8 + s_krow) * ld + s_kch8;
    const bf16* kp1 = kbase1 + (size_t)(w * 8 + s_krow) * ld + s_kch8;
    const bf16* vp0 = vbase + (size_t)(w * 8 + s_krow) * 2048 + s_vk8;
    const bf16* vp1 = vbase + (size_t)((4 + w) * 8 + s_krow) * 2048 + s_vk8;

    auto stage = [&](int kb, int vs) {
        gl_lds16(kp0, &sK[kb][0][w * 8][0]);
        gl_lds16(kp1, &sK[kb][1][w * 8][0]);
        gl_lds16(vp0, &sV[vs][w * 8][0]);
        gl_lds16(vp1, &sV[vs][(4 + w) * 8][0]);
        kp0 += 32 * ld;
        kp1 += 32 * ld;
        vp0 += 32;
        vp1 += 32;
    };

    stage(0, 0);

    const size_t qoff = (size_t)(b * 2048 + qb * 64 + w * 16 + lr) * ld + h * 64;
    bf16x8 aqr[2], aqi[2];
#pragma unroll
    for (int ks = 0; ks < 2; ++ks) {
        aqr[ks] = *(const bf16x8*)(qkvr + qoff + ks * 32 + lg * 8);
        aqi[ks] = *(const bf16x8*)(qkvi + qoff + ks * 32 + lg * 8);
    }

    f32x4 our[4], oui[4];
#pragma unroll
    for (int d = 0; d < 4; ++d) {
        our[d] = zero4();
        oui[d] = zero4();
    }
    const float C1 = 0.125f * LOG2E;
    float mrun = -1e30f;
    float lrun_p = 0.0f;  // per-lane partial (all of lane lr's scores are q=lr)
    float thr2 = -1.0f;
    float mC2 = 0.0f;

    bf16x8 pfPrev = __builtin_bit_cast(bf16x8, u32x4{0u, 0u, 0u, 0u});
    int vcur = 0, vlast = 0;
    const int slr = lg ^ (lr & 7);
    const int sli = (4 + lg) ^ (lr & 7);

    for (int kt = 0; kt < 64; ++kt) {
        const int kcur = kt & 1;
        int vnext = vcur + 1;
        if (vnext == 3) vnext = 0;
        if (kt < 63) {
            stage(kcur ^ 1, vnext);
            __builtin_amdgcn_sched_barrier(0);
            asm volatile("s_waitcnt vmcnt(4)" ::: "memory");
        } else {
            asm volatile("s_waitcnt vmcnt(0)" ::: "memory");
        }
        __builtin_amdgcn_sched_barrier(0);
        __builtin_amdgcn_s_barrier();  // the only barrier per iteration
        __builtin_amdgcn_sched_barrier(0);

        // ---- QK^T(kt) + PV(kt-1) ----
        f32x4 str[2], sti[2];
        str[0] = zero4(); str[1] = zero4();
        sti[0] = zero4(); sti[1] = zero4();
        __builtin_amdgcn_s_setprio(1);
#pragma unroll
        for (int t = 0; t < 2; ++t) {
#pragma unroll
            for (int ks = 0; ks < 2; ++ks) {
                const int ch = ((ks << 2) | lg) ^ (lr & 7);
                const bf16x8 kr8 = *(const bf16x8*)(&sK[kcur][0][t * 16 + lr][ch * 8]);
                const bf16x8 ki8 = *(const bf16x8*)(&sK[kcur][1][t * 16 + lr][ch * 8]);
                const bf16x8 kn8 = bneg8(kr8);
                str[t] = MFMA16(kr8, aqr[ks], str[t]);
                str[t] = MFMA16(ki8, aqi[ks], str[t]);
                sti[t] = MFMA16(ki8, aqr[ks], sti[t]);
                sti[t] = MFMA16(kn8, aqi[ks], sti[t]);
            }
        }
        if (kt > 0) {
#pragma unroll
            for (int d = 0; d < 4; ++d) {
                const bf16x8 vr8 = *(const bf16x8*)(&sV[vlast][d * 16 + lr][slr * 8]);
                const bf16x8 vi8 = *(const bf16x8*)(&sV[vlast][d * 16 + lr][sli * 8]);
                our[d] = MFMA16(pfPrev, vr8, our[d]);
                oui[d] = MFMA16(pfPrev, vi8, oui[d]);
            }
        }
        __builtin_amdgcn_s_setprio(0);

        // ---- squared magnitudes; per-lane max only (no shuffles) ----
        float v[8];
        float vmax = 0.0f;
#pragma unroll
        for (int t = 0; t < 2; ++t)
#pragma unroll
            for (int j = 0; j < 4; ++j) {
                const float sr = str[t][j], si = sti[t][j];
                const float vv = fmaf(sr, sr, fmaf(si, si, 1e-8f));
                v[t * 4 + j] = vv;
                vmax = fmaxf(vmax, vv);
            }

        // defer-max: __all covers the wave-wide check; group reduce only
        // when the rescale actually fires (rare after the first tiles)
        if (!__all(vmax <= thr2)) {
            vmax = fmaxf(vmax, __shfl_xor(vmax, 16));
            vmax = fmaxf(vmax, __shfl_xor(vmax, 32));
            const float tm = __builtin_amdgcn_sqrtf(vmax) * 0.125f;
            const float mnew = fmaxf(mrun, tm);
            const float corr = __builtin_amdgcn_exp2f((mrun - mnew) * LOG2E);
            float cj[4];
#pragma unroll
            for (int j = 0; j < 4; ++j) cj[j] = __shfl(corr, lg * 4 + j);
#pragma unroll
            for (int d = 0; d < 4; ++d)
#pragma unroll
                for (int j = 0; j < 4; ++j) {
                    our[d][j] *= cj[j];
                    oui[d][j] *= cj[j];
                }
            lrun_p *= corr;  // corr is uniform across the 4 lanes of group q=lr
            mrun = mnew;
            const float m8 = mrun + 8.0f;
            thr2 = 64.0f * m8 * m8;
            mC2 = -mrun * LOG2E;
        }

        float p[8];
        float ls = 0.0f;
#pragma unroll
        for (int i = 0; i < 8; ++i) {
            p[i] = __builtin_amdgcn_exp2f(
                fmaf(__builtin_amdgcn_sqrtf(v[i]), C1, mC2));
            ls += p[i];
        }
        lrun_p += ls;  // no reduce: deferred to epilogue

        // ---- pack P(kt) -> LDS -> pfPrev ----
#pragma unroll
        for (int t = 0; t < 2; ++t) {
            bf16x4 pk;
#pragma unroll
            for (int j = 0; j < 4; ++j) pk[j] = (bf16)p[t * 4 + j];
            *(bf16x4*)(&sP[w][lr][t * 16 + lg * 4]) = pk;
        }
        pfPrev = *(const bf16x8*)(&sP[w][lr][lg * 8]);

        vlast = vcur;
        vcur = vnext;
    }

    // final PV for tile 63
#pragma unroll
    for (int d = 0; d < 4; ++d) {
        const bf16x8 vr8 = *(const bf16x8*)(&sV[vlast][d * 16 + lr][slr * 8]);
        const bf16x8 vi8 = *(const bf16x8*)(&sV[vlast][d * 16 + lr][sli * 8]);
        our[d] = MFMA16(pfPrev, vr8, our[d]);
        oui[d] = MFMA16(pfPrev, vi8, oui[d]);
    }

    // deferred lrun reduce (once)
    float lsum = lrun_p;
    lsum += __shfl_xor(lsum, 16);
    lsum += __shfl_xor(lsum, 32);

    float linv[4];
#pragma unroll
    for (int j = 0; j < 4; ++j) {
        const float lj = __shfl(lsum, lg * 4 + j);
        linv[j] = __builtin_amdgcn_rcpf(lj);
    }
#pragma unroll
    for (int d = 0; d < 4; ++d)
#pragma unroll
        for (int j = 0; j < 4; ++j) {
            const int row = b * 2048 + qb * 64 + w * 16 + lg * 4 + j;
            const int col = h * 64 + d * 16 + lr;
            aor[(size_t)row * 768 + col] = (bf16)(our[d][j] * linv[j]);
            aoi[(size_t)row * 768 + col] = (bf16)(oui[d][j] * linv[j]);
        }
}

// ---------------------------------------------------------------------------
// host launch
// ---------------------------------------------------------------------------
extern "C" void kernel_launch(void* const* d_in, const int* in_sizes, int n_in,
                              void* d_out, int out_size, void* d_ws, size_t ws_size,
                              hipStream_t stream) {
    const float* x      = (const float*)d_in[0];
    const float* n1g    = (const float*)d_in[1];
    const float* n1b    = (const float*)d_in[2];
    const float* qkvwr  = (const float*)d_in[3];
    const float* qkvwi  = (const float*)d_in[4];
    const float* qkvbr  = (const float*)d_in[5];
    const float* qkvbi  = (const float*)d_in[6];
    const float* projwr = (const float*)d_in[7];
    const float* projwi = (const float*)d_in[8];
    const float* projbr = (const float*)d_in[9];
    const float* projbi = (const float*)d_in[10];
    const float* n2g    = (const float*)d_in[11];
    const float* n2b    = (const float*)d_in[12];
    const float* fc1wr  = (const float*)d_in[13];
    const float* fc1wi  = (const float*)d_in[14];
    const float* fc1br  = (const float*)d_in[15];
    const float* fc1bi  = (const float*)d_in[16];
    const float* fc2wr  = (const float*)d_in[17];
    const float* fc2wi  = (const float*)d_in[18];
    const float* fc2br  = (const float*)d_in[19];
    const float* fc2bi  = (const float*)d_in[20];

    const int M = 4096, E = 768, E3 = 2304, HH = 1536;

    char* base = (char*)d_ws;
    size_t off = 0;
    auto alloc = [&](size_t bytes) -> void* {
        void* p = base + off;
        off += (bytes + 255) & ~(size_t)255;
        return p;
    };
    float* xr2 = (float*)alloc((size_t)M * E * 4);
    float* xi2 = (float*)alloc((size_t)M * E * 4);
    bf16* nr   = (bf16*)alloc((size_t)M * E * 2);
    bf16* ni   = (bf16*)alloc((size_t)M * E * 2);
    bf16* wqr  = (bf16*)alloc((size_t)E3 * E * 2);
    bf16* wqi  = (bf16*)alloc((size_t)E3 * E * 2);
    bf16* wpr  = (bf16*)alloc((size_t)E * E * 2);
    bf16* wpi  = (bf16*)alloc((size_t)E * E * 2);
    bf16* w1r  = (bf16*)alloc((size_t)HH * E * 2);
    bf16* w1i  = (bf16*)alloc((size_t)HH * E * 2);
    bf16* w2r  = (bf16*)alloc((size_t)E * HH * 2);
    bf16* w2i  = (bf16*)alloc((size_t)E * HH * 2);
    bf16* qkr  = (bf16*)alloc((size_t)M * E3 * 2);
    bf16* qki  = (bf16*)alloc((size_t)M * E3 * 2);
    bf16* vtr  = (bf16*)alloc((size_t)24 * 64 * 2048 * 2);
    bf16* vti  = (bf16*)alloc((size_t)24 * 64 * 2048 * 2);
    bf16* aor  = (bf16*)alloc((size_t)M * E * 2);
    bf16* aoi  = (bf16*)alloc((size_t)M * E * 2);
    bf16* hr   = (bf16*)alloc((size_t)M * HH * 2);
    bf16* hi   = (bf16*)alloc((size_t)M * HH * 2);

    if (off > ws_size) {
        fill_kernel<<<1024, 256, 0, stream>>>((float*)d_out, 1.0e9f, out_size);
        return;
    }

    // fused weight conversion
    Cvt8 c;
    c.s[0] = qkvwr; c.d[0] = wqr;
    c.s[1] = qkvwi; c.d[1] = wqi;
    c.s[2] = projwr; c.d[2] = wpr;
    c.s[3] = projwi; c.d[3] = wpi;
    c.s[4] = fc1wr; c.d[4] = w1r;
    c.s[5] = fc1wi; c.d[5] = w1i;
    c.s[6] = fc2wr; c.d[6] = w2r;
    c.s[7] = fc2wi; c.d[7] = w2i;
    const int nseg[8] = {E3 * E, E3 * E, E * E, E * E, HH * E, HH * E, E * HH, E * HH};
    int cum = 0;
    for (int k = 0; k < 8; ++k) {
        c.boff[k] = cum;
        cum += nseg[k] / 1024;
    }
    c.boff[8] = cum;
    cvt8_kernel<<<cum, 256, 0, stream>>>(c);

    // LN1 (reads interleaved x directly)
    cln_kernel<true><<<M, 256, 0, stream>>>(x, nullptr, n1g, n1b, nr, ni);
    // QKV: 128x128, dbuf+counted vmcnt+single barrier, grid 576
    cgemm_kernel<128, 128, 0, 2><<<dim3(32, 18), 256, 0, stream>>>(
        nr, ni, wqr, wqi, qkvbr, qkvbi, nullptr, nullptr, nullptr, nullptr,
        qkr, qki, E3, E);
    // V transpose
    vtrans_kernel<<<dim3(32, 12, 2), 256, 0, stream>>>(qkr, qki, vtr, vti);
    // attention (64 q-rows per block; 768 blocks = 3/CU exact)
    cattn_kernel<<<dim3(32, 12, 2), 256, 0, stream>>>(qkr, qki, vtr, vti, aor, aoi);
    // proj + interleaved-x residual: 128x64, grid 384
    cgemm_kernel<128, 64, 1, 3><<<dim3(32, 12), 256, 0, stream>>>(
        aor, aoi, wpr, wpi, projbr, projbi, x, nullptr, xr2, xi2, nullptr, nullptr,
        E, E);
    // LN2
    cln_kernel<false><<<M, 256, 0, stream>>>(xr2, xi2, n2g, n2b, nr, ni);
    // FC1 + fast GELU: 128x128, grid 384
    cgemm_kernel<128, 128, 2, 2><<<dim3(32, 12), 256, 0, stream>>>(
        nr, ni, w1r, w1i, fc1br, fc1bi, nullptr, nullptr, nullptr, nullptr,
        hr, hi, HH, E);
    // FC2 + residual -> interleaved d_out: 128x64, grid 384
    cgemm_kernel<128, 64, 3, 3><<<dim3(32, 12), 256, 0, stream>>>(
        hr, hi, w2r, w2i, fc2br, fc2bi, xr2, xi2, (float*)d_out, nullptr,
        nullptr, nullptr, E, HH);
}

// Round 12
// 334.190 us; speedup vs baseline: 1.3463x; 1.0186x over previous
//
#include <hip/hip_runtime.h>
#include <cmath>

typedef __bf16 bf16;
typedef __bf16 bf16x8 __attribute__((ext_vector_type(8)));
typedef __bf16 bf16x4 __attribute__((ext_vector_type(4)));
typedef float  f32x4  __attribute__((ext_vector_type(4)));
typedef unsigned int u32x4 __attribute__((ext_vector_type(4)));

#define MFMA16(a, b, c) __builtin_amdgcn_mfma_f32_16x16x32_bf16((a), (b), (c), 0, 0, 0)
#define LOG2E 1.44269504088896f

static __device__ __forceinline__ void gl_lds16(const void* g, void* l) {
    __builtin_amdgcn_global_load_lds((const __attribute__((address_space(1))) void*)g,
                                     (__attribute__((address_space(3))) void*)l, 16, 0, 0);
}

static __device__ __forceinline__ bf16x8 bneg8(bf16x8 x) {
    u32x4 u = __builtin_bit_cast(u32x4, x);
    u = u ^ 0x80008000u;
    return __builtin_bit_cast(bf16x8, u);
}

static __device__ __forceinline__ f32x4 zero4() {
    return f32x4{0.0f, 0.0f, 0.0f, 0.0f};
}

// ---------------------------------------------------------------------------
// small utility kernels
// ---------------------------------------------------------------------------
__global__ void fill_kernel(float* p, float v, int n) {
    for (int i = blockIdx.x * blockDim.x + threadIdx.x; i < n; i += gridDim.x * blockDim.x)
        p[i] = v;
}

// fused 8-way f32 -> bf16 weight conversion (all sizes % 1024 == 0)
struct Cvt8 {
    const float* s[8];
    bf16* d[8];
    int boff[9];
};
__global__ __launch_bounds__(256) void cvt8_kernel(Cvt8 c) {
    int blk = blockIdx.x;
    int seg = 0;
#pragma unroll
    for (int k = 0; k < 7; ++k)
        if (blk >= c.boff[k + 1]) seg = k + 1;
    const int local = blk - c.boff[seg];
    const int i = local * 1024 + threadIdx.x * 4;
    const float4 v = *(const float4*)(c.s[seg] + i);
    bf16x4 o;
    o[0] = (bf16)v.x; o[1] = (bf16)v.y; o[2] = (bf16)v.z; o[3] = (bf16)v.w;
    *(bf16x4*)(c.d[seg] + i) = o;
}

// ---------------------------------------------------------------------------
// complex magnitude layernorm. ILV=true: xa is interleaved float2 [row][768][2]
// ---------------------------------------------------------------------------
template <bool ILV>
__global__ __launch_bounds__(256) void cln_kernel(
    const float* __restrict__ xa, const float* __restrict__ xb,
    const float* __restrict__ gamma, const float* __restrict__ beta,
    bf16* __restrict__ nr, bf16* __restrict__ ni) {
    __shared__ float red[4];
    const int t = threadIdx.x;
    const size_t base = (size_t)blockIdx.x * 768;

    float r[3], im[3], mg[3];
#pragma unroll
    for (int j = 0; j < 3; ++j) {
        const int f = t + j * 256;
        if (ILV) {
            const float2 v = ((const float2*)xa)[base + f];
            r[j] = v.x;
            im[j] = v.y;
        } else {
            r[j] = xa[base + f];
            im[j] = xb[base + f];
        }
        mg[j] = __builtin_amdgcn_sqrtf(r[j] * r[j] + im[j] * im[j] + 1e-6f);
    }
    float s = mg[0] + mg[1] + mg[2];
#pragma unroll
    for (int m = 32; m >= 1; m >>= 1) s += __shfl_xor(s, m);
    if ((t & 63) == 0) red[t >> 6] = s;
    __syncthreads();
    const float mean = (red[0] + red[1] + red[2] + red[3]) * (1.0f / 768.0f);
    __syncthreads();

    float v2 = 0.0f;
#pragma unroll
    for (int j = 0; j < 3; ++j) {
        const float d = mg[j] - mean;
        v2 += d * d;
    }
#pragma unroll
    for (int m = 32; m >= 1; m >>= 1) v2 += __shfl_xor(v2, m);
    if ((t & 63) == 0) red[t >> 6] = v2;
    __syncthreads();
    const float var = (red[0] + red[1] + red[2] + red[3]) * (1.0f / 768.0f);
    const float rstd = rsqrtf(var + 1e-6f);

#pragma unroll
    for (int j = 0; j < 3; ++j) {
        const int f = t + j * 256;
        const float sc = (mg[j] - mean) * rstd / (mg[j] + 1e-6f);
        nr[base + f] = (bf16)(gamma[2 * f] * (r[j] * sc) + beta[2 * f]);
        ni[base + f] = (bf16)(gamma[2 * f + 1] * (im[j] * sc) + beta[2 * f + 1]);
    }
}

// ---------------------------------------------------------------------------
// complex GEMM (NT): double-buffered fused-plane LDS, counted vmcnt,
// single barrier per K-step, XCD-aware block swizzle.
// MODE 0: bf16 planes (bias by col)      MODE 1: f32 planes = float2-res + out
// MODE 2: fast-GELU -> bf16 planes       MODE 3: interleaved f32 = res + out
// MODE 4: bf16 planes, bias by ROW (for V^T = Wv @ norm^T)
// ---------------------------------------------------------------------------
template <int BM, int BN, int MODE, int OCC>
__global__ __launch_bounds__(256, OCC) void cgemm_kernel(
    const bf16* __restrict__ Ar, const bf16* __restrict__ Ai,
    const bf16* __restrict__ Wr, const bf16* __restrict__ Wi,
    const float* __restrict__ br, const float* __restrict__ bi,
    const float* __restrict__ resr, const float* __restrict__ resi,
    float* __restrict__ outFr, float* __restrict__ outFi,
    bf16* __restrict__ outBr, bf16* __restrict__ outBi,
    int N, int K) {
    constexpr int MR = BM / 32;
    constexpr int NR = BN / 32;
    constexpr int ASEG = BM / 8;
    constexpr int NSEG = (BM + BN) / 8;
    constexpr int SPW = NSEG / 4;

    __shared__ __align__(16) bf16 sA[2][BM][64];  // row = [real 32 | imag 32]
    __shared__ __align__(16) bf16 sB[2][BN][64];

    const int tid = threadIdx.x;
    const int wave = tid >> 6, lane = tid & 63;
    const int lg = lane >> 4, lr = lane & 15;

    const int nwgx = gridDim.x;
    int wg = blockIdx.y * nwgx + blockIdx.x;
    const int cpx = (nwgx * gridDim.y) >> 3;
    wg = (wg & 7) * cpx + (wg >> 3);
    const int row0 = (wg % nwgx) * BM, col0 = (wg / nwgx) * BN;

    const int wm = (wave >> 1) * (BM / 2), wn = (wave & 1) * (BN / 2);

    const int srow = lane >> 3;
    const int schunk = (lane & 7) ^ srow;
    const int spl = schunk >> 2;
    const int sc8 = (schunk & 3) * 8;

    auto issue = [&](int buf, int kt) {
#pragma unroll
        for (int s = 0; s < SPW; ++s) {
            const int id = wave * SPW + s;
            if (id < ASEG) {
                const int row = id * 8 + srow;
                gl_lds16((spl ? Ai : Ar) + (size_t)(row0 + row) * K + kt + sc8,
                         &sA[buf][id * 8][0]);
            } else {
                const int row = (id - ASEG) * 8 + srow;
                gl_lds16((spl ? Wi : Wr) + (size_t)(col0 + row) * K + kt + sc8,
                         &sB[buf][(id - ASEG) * 8][0]);
            }
        }
    };

    f32x4 accr[MR][NR], acci[MR][NR];
#pragma unroll
    for (int a = 0; a < MR; ++a)
#pragma unroll
        for (int b2 = 0; b2 < NR; ++b2) {
            accr[a][b2] = zero4();
            acci[a][b2] = zero4();
        }

    issue(0, 0);

    const int KT = K / 32;
    for (int kt = 0; kt < KT; ++kt) {
        const int buf = kt & 1;
        if (kt + 1 < KT) {
            issue(buf ^ 1, (kt + 1) * 32);
            __builtin_amdgcn_sched_barrier(0);
            if constexpr (SPW == 8)
                asm volatile("s_waitcnt vmcnt(8)" ::: "memory");
            else if constexpr (SPW == 6)
                asm volatile("s_waitcnt vmcnt(6)" ::: "memory");
            else
                asm volatile("s_waitcnt vmcnt(0)" ::: "memory");
        } else {
            asm volatile("s_waitcnt vmcnt(0)" ::: "memory");
        }
        __builtin_amdgcn_sched_barrier(0);
        __builtin_amdgcn_s_barrier();  // the only barrier per K-step
        __builtin_amdgcn_sched_barrier(0);

        bf16x8 ar[MR], ai[MR], an[MR];
#pragma unroll
        for (int mt = 0; mt < MR; ++mt) {
            const int rr = wm + mt * 16 + lr;
            const int slr = lg ^ (rr & 7);
            const int sli = (4 + lg) ^ (rr & 7);
            ar[mt] = *(const bf16x8*)(&sA[buf][rr][slr * 8]);
            ai[mt] = *(const bf16x8*)(&sA[buf][rr][sli * 8]);
            an[mt] = bneg8(ai[mt]);
        }
#pragma unroll
        for (int nt = 0; nt < NR; ++nt) {
            const int rr = wn + nt * 16 + lr;
            const int slr = lg ^ (rr & 7);
            const int sli = (4 + lg) ^ (rr & 7);
            const bf16x8 br8 = *(const bf16x8*)(&sB[buf][rr][slr * 8]);
            const bf16x8 bi8 = *(const bf16x8*)(&sB[buf][rr][sli * 8]);
#pragma unroll
            for (int mt = 0; mt < MR; ++mt) {
                accr[mt][nt] = MFMA16(ar[mt], br8, accr[mt][nt]);
                accr[mt][nt] = MFMA16(an[mt], bi8, accr[mt][nt]);
                acci[mt][nt] = MFMA16(ar[mt], bi8, acci[mt][nt]);
                acci[mt][nt] = MFMA16(ai[mt], br8, acci[mt][nt]);
            }
        }
    }

#pragma unroll
    for (int nt = 0; nt < NR; ++nt) {
        const int col = col0 + wn + nt * 16 + lr;
        const float bre = (MODE == 4) ? 0.0f : br[col];
        const float bie = (MODE == 4) ? 0.0f : bi[col];
#pragma unroll
        for (int mt = 0; mt < MR; ++mt) {
#pragma unroll
            for (int j = 0; j < 4; ++j) {
                const int row = row0 + wm + mt * 16 + lg * 4 + j;
                float vr = accr[mt][nt][j];
                float vi = acci[mt][nt][j];
                if (MODE == 4) {
                    vr += br[row];
                    vi += bi[row];
                } else {
                    vr += bre;
                    vi += bie;
                }
                const size_t o = (size_t)row * N + col;
                if (MODE == 0 || MODE == 4) {
                    outBr[o] = (bf16)vr;
                    outBi[o] = (bf16)vi;
                } else if (MODE == 1) {
                    const float2 rv = ((const float2*)resr)[(size_t)row * 768 + col];
                    outFr[o] = rv.x + vr;
                    outFi[o] = rv.y + vi;
                } else if (MODE == 2) {
                    // fast tanh-GELU
                    const float t2r = fmaf(vr * vr, 0.044715f, 1.0f);
                    const float er = __builtin_amdgcn_exp2f(vr * t2r * 2.3022082f);
                    vr = vr - vr * __builtin_amdgcn_rcpf(er + 1.0f);
                    const float t2i = fmaf(vi * vi, 0.044715f, 1.0f);
                    const float ei = __builtin_amdgcn_exp2f(vi * t2i * 2.3022082f);
                    vi = vi - vi * __builtin_amdgcn_rcpf(ei + 1.0f);
                    outBr[o] = (bf16)vr;
                    outBi[o] = (bf16)vi;
                } else {
                    const size_t ro = (size_t)row * 768 + col;
                    outFr[(size_t)row * 1536 + 2 * col]     = resr[ro] + vr;
                    outFr[(size_t)row * 1536 + 2 * col + 1] = resi[ro] + vi;
                }
            }
        }
    }
}

// ---------------------------------------------------------------------------
// fused complex flash attention v10: v9 + hoisted negated-Q fragment
// (removes per-iter K negation), QK buffer ld=1536, V^T planes [768][4096].
// ---------------------------------------------------------------------------
__global__ __launch_bounds__(256, 3) void cattn_kernel(
    const bf16* __restrict__ qkr, const bf16* __restrict__ qki,
    const bf16* __restrict__ vtr, const bf16* __restrict__ vti,
    bf16* __restrict__ aor, bf16* __restrict__ aoi) {
    __shared__ __align__(16) bf16 sK[2][2][32][64];  // double buffer
    __shared__ __align__(16) bf16 sV[3][64][64];     // triple ring (fused planes)
    __shared__ __align__(16) bf16 sP[4][16][40];

    const int tid = threadIdx.x;
    const int w = tid >> 6, lane = tid & 63;
    const int lg = lane >> 4, lr = lane & 15;
    const int qb = blockIdx.x, h = blockIdx.y, b = blockIdx.z;
    const int ld = 1536;

    const int s_krow = lane >> 3;
    const int s_kch8 = ((lane & 7) ^ s_krow) * 8;
    const int s_vlog = (lane & 7) ^ s_krow;
    const int s_vpl = s_vlog >> 2;
    const int s_vk8 = (s_vlog & 3) * 8;

    const bf16* kbase0 = qkr + (size_t)b * 2048 * ld + 768 + h * 64;
    const bf16* kbase1 = qki + (size_t)b * 2048 * ld + 768 + h * 64;
    // V^T planes: [c = h*64+d][tok = b*2048+n], row stride 4096
    const bf16* vbase = (s_vpl ? vti : vtr) + (size_t)(h * 64) * 4096 + b * 2048;

    const bf16* kp0 = kbase0 + (size_t)(w * 8 + s_krow) * ld + s_kch8;
    const bf16* kp1 = kbase1 + (size_t)(w * 8 + s_krow) * ld + s_kch8;
    const bf16* vp0 = vbase + (size_t)(w * 8 + s_krow) * 4096 + s_vk8;
    const bf16* vp1 = vbase + (size_t)((4 + w) * 8 + s_krow) * 4096 + s_vk8;

    auto stage = [&](int kb, int vs) {
        gl_lds16(kp0, &sK[kb][0][w * 8][0]);
        gl_lds16(kp1, &sK[kb][1][w * 8][0]);
        gl_lds16(vp0, &sV[vs][w * 8][0]);
        gl_lds16(vp1, &sV[vs][(4 + w) * 8][0]);
        kp0 += 32 * ld;
        kp1 += 32 * ld;
        vp0 += 32;
        vp1 += 32;
    };

    stage(0, 0);

    const size_t qoff = (size_t)(b * 2048 + qb * 64 + w * 16 + lr) * ld + h * 64;
    bf16x8 aqr[2], aqi[2], aqin[2];
#pragma unroll
    for (int ks = 0; ks < 2; ++ks) {
        aqr[ks] = *(const bf16x8*)(qkr + qoff + ks * 32 + lg * 8);
        aqi[ks] = *(const bf16x8*)(qki + qoff + ks * 32 + lg * 8);
        aqin[ks] = bneg8(aqi[ks]);
    }

    f32x4 our[4], oui[4];
#pragma unroll
    for (int d = 0; d < 4; ++d) {
        our[d] = zero4();
        oui[d] = zero4();
    }
    const float C1 = 0.125f * LOG2E;
    float mrun = -1e30f;
    float lrun_p = 0.0f;
    float thr2 = -1.0f;
    float mC2 = 0.0f;

    bf16x8 pfPrev = __builtin_bit_cast(bf16x8, u32x4{0u, 0u, 0u, 0u});
    int vcur = 0, vlast = 0;
    const int slr = lg ^ (lr & 7);
    const int sli = (4 + lg) ^ (lr & 7);

    for (int kt = 0; kt < 64; ++kt) {
        const int kcur = kt & 1;
        int vnext = vcur + 1;
        if (vnext == 3) vnext = 0;
        if (kt < 63) {
            stage(kcur ^ 1, vnext);
            __builtin_amdgcn_sched_barrier(0);
            asm volatile("s_waitcnt vmcnt(4)" ::: "memory");
        } else {
            asm volatile("s_waitcnt vmcnt(0)" ::: "memory");
        }
        __builtin_amdgcn_sched_barrier(0);
        __builtin_amdgcn_s_barrier();  // the only barrier per iteration
        __builtin_amdgcn_sched_barrier(0);

        // ---- QK^T(kt) + PV(kt-1) ----
        f32x4 str[2], sti[2];
        str[0] = zero4(); str[1] = zero4();
        sti[0] = zero4(); sti[1] = zero4();
        __builtin_amdgcn_s_setprio(1);
#pragma unroll
        for (int t = 0; t < 2; ++t) {
#pragma unroll
            for (int ks = 0; ks < 2; ++ks) {
                const int ch = ((ks << 2) | lg) ^ (lr & 7);
                const bf16x8 kr8 = *(const bf16x8*)(&sK[kcur][0][t * 16 + lr][ch * 8]);
                const bf16x8 ki8 = *(const bf16x8*)(&sK[kcur][1][t * 16 + lr][ch * 8]);
                str[t] = MFMA16(kr8, aqr[ks], str[t]);
                str[t] = MFMA16(ki8, aqi[ks], str[t]);
                sti[t] = MFMA16(ki8, aqr[ks], sti[t]);
                sti[t] = MFMA16(kr8, aqin[ks], sti[t]);
            }
        }
        if (kt > 0) {
#pragma unroll
            for (int d = 0; d < 4; ++d) {
                const bf16x8 vr8 = *(const bf16x8*)(&sV[vlast][d * 16 + lr][slr * 8]);
                const bf16x8 vi8 = *(const bf16x8*)(&sV[vlast][d * 16 + lr][sli * 8]);
                our[d] = MFMA16(pfPrev, vr8, our[d]);
                oui[d] = MFMA16(pfPrev, vi8, oui[d]);
            }
        }
        __builtin_amdgcn_s_setprio(0);

        // ---- squared magnitudes; per-lane max only ----
        float v[8];
        float vmax = 0.0f;
#pragma unroll
        for (int t = 0; t < 2; ++t)
#pragma unroll
            for (int j = 0; j < 4; ++j) {
                const float sr = str[t][j], si = sti[t][j];
                const float vv = fmaf(sr, sr, fmaf(si, si, 1e-8f));
                v[t * 4 + j] = vv;
                vmax = fmaxf(vmax, vv);
            }

        if (!__all(vmax <= thr2)) {
            vmax = fmaxf(vmax, __shfl_xor(vmax, 16));
            vmax = fmaxf(vmax, __shfl_xor(vmax, 32));
            const float tm = __builtin_amdgcn_sqrtf(vmax) * 0.125f;
            const float mnew = fmaxf(mrun, tm);
            const float corr = __builtin_amdgcn_exp2f((mrun - mnew) * LOG2E);
            float cj[4];
#pragma unroll
            for (int j = 0; j < 4; ++j) cj[j] = __shfl(corr, lg * 4 + j);
#pragma unroll
            for (int d = 0; d < 4; ++d)
#pragma unroll
                for (int j = 0; j < 4; ++j) {
                    our[d][j] *= cj[j];
                    oui[d][j] *= cj[j];
                }
            lrun_p *= corr;
            mrun = mnew;
            const float m8 = mrun + 8.0f;
            thr2 = 64.0f * m8 * m8;
            mC2 = -mrun * LOG2E;
        }

        float p[8];
        float ls = 0.0f;
#pragma unroll
        for (int i = 0; i < 8; ++i) {
            p[i] = __builtin_amdgcn_exp2f(
                fmaf(__builtin_amdgcn_sqrtf(v[i]), C1, mC2));
            ls += p[i];
        }
        lrun_p += ls;

        // ---- pack P(kt) -> LDS -> pfPrev ----
#pragma unroll
        for (int t = 0; t < 2; ++t) {
            bf16x4 pk;
#pragma unroll
            for (int j = 0; j < 4; ++j) pk[j] = (bf16)p[t * 4 + j];
            *(bf16x4*)(&sP[w][lr][t * 16 + lg * 4]) = pk;
        }
        pfPrev = *(const bf16x8*)(&sP[w][lr][lg * 8]);

        vlast = vcur;
        vcur = vnext;
    }

    // final PV for tile 63
#pragma unroll
    for (int d = 0; d < 4; ++d) {
        const bf16x8 vr8 = *(const bf16x8*)(&sV[vlast][d * 16 + lr][slr * 8]);
        const bf16x8 vi8 = *(const bf16x8*)(&sV[vlast][d * 16 + lr][sli * 8]);
        our[d] = MFMA16(pfPrev, vr8, our[d]);
        oui[d] = MFMA16(pfPrev, vi8, oui[d]);
    }

    float lsum = lrun_p;
    lsum += __shfl_xor(lsum, 16);
    lsum += __shfl_xor(lsum, 32);

    float linv[4];
#pragma unroll
    for (int j = 0; j < 4; ++j) {
        const float lj = __shfl(lsum, lg * 4 + j);
        linv[j] = __builtin_amdgcn_rcpf(lj);
    }
#pragma unroll
    for (int d = 0; d < 4; ++d)
#pragma unroll
        for (int j = 0; j < 4; ++j) {
            const int row = b * 2048 + qb * 64 + w * 16 + lg * 4 + j;
            const int col = h * 64 + d * 16 + lr;
            aor[(size_t)row * 768 + col] = (bf16)(our[d][j] * linv[j]);
            aoi[(size_t)row * 768 + col] = (bf16)(oui[d][j] * linv[j]);
        }
}

// ---------------------------------------------------------------------------
// host launch
// ---------------------------------------------------------------------------
extern "C" void kernel_launch(void* const* d_in, const int* in_sizes, int n_in,
                              void* d_out, int out_size, void* d_ws, size_t ws_size,
                              hipStream_t stream) {
    const float* x      = (const float*)d_in[0];
    const float* n1g    = (const float*)d_in[1];
    const float* n1b    = (const float*)d_in[2];
    const float* qkvwr  = (const float*)d_in[3];
    const float* qkvwi  = (const float*)d_in[4];
    const float* qkvbr  = (const float*)d_in[5];
    const float* qkvbi  = (const float*)d_in[6];
    const float* projwr = (const float*)d_in[7];
    const float* projwi = (const float*)d_in[8];
    const float* projbr = (const float*)d_in[9];
    const float* projbi = (const float*)d_in[10];
    const float* n2g    = (const float*)d_in[11];
    const float* n2b    = (const float*)d_in[12];
    const float* fc1wr  = (const float*)d_in[13];
    const float* fc1wi  = (const float*)d_in[14];
    const float* fc1br  = (const float*)d_in[15];
    const float* fc1bi  = (const float*)d_in[16];
    const float* fc2wr  = (const float*)d_in[17];
    const float* fc2wi  = (const float*)d_in[18];
    const float* fc2br  = (const float*)d_in[19];
    const float* fc2bi  = (const float*)d_in[20];

    const int M = 4096, E = 768, E3 = 2304, HH = 1536;

    char* base = (char*)d_ws;
    size_t off = 0;
    auto alloc = [&](size_t bytes) -> void* {
        void* p = base + off;
        off += (bytes + 255) & ~(size_t)255;
        return p;
    };
    float* xr2 = (float*)alloc((size_t)M * E * 4);
    float* xi2 = (float*)alloc((size_t)M * E * 4);
    bf16* nr   = (bf16*)alloc((size_t)M * E * 2);
    bf16* ni   = (bf16*)alloc((size_t)M * E * 2);
    bf16* wqr  = (bf16*)alloc((size_t)E3 * E * 2);
    bf16* wqi  = (bf16*)alloc((size_t)E3 * E * 2);
    bf16* wpr  = (bf16*)alloc((size_t)E * E * 2);
    bf16* wpi  = (bf16*)alloc((size_t)E * E * 2);
    bf16* w1r  = (bf16*)alloc((size_t)HH * E * 2);
    bf16* w1i  = (bf16*)alloc((size_t)HH * E * 2);
    bf16* w2r  = (bf16*)alloc((size_t)E * HH * 2);
    bf16* w2i  = (bf16*)alloc((size_t)E * HH * 2);
    bf16* qkr  = (bf16*)alloc((size_t)M * HH * 2);   // [4096][1536] Q|K
    bf16* qki  = (bf16*)alloc((size_t)M * HH * 2);
    bf16* vtr  = (bf16*)alloc((size_t)E * M * 2);    // V^T [768][4096]
    bf16* vti  = (bf16*)alloc((size_t)E * M * 2);
    bf16* aor  = (bf16*)alloc((size_t)M * E * 2);
    bf16* aoi  = (bf16*)alloc((size_t)M * E * 2);
    bf16* hr   = (bf16*)alloc((size_t)M * HH * 2);
    bf16* hi   = (bf16*)alloc((size_t)M * HH * 2);

    if (off > ws_size) {
        fill_kernel<<<1024, 256, 0, stream>>>((float*)d_out, 1.0e9f, out_size);
        return;
    }

    // fused weight conversion
    Cvt8 c;
    c.s[0] = qkvwr; c.d[0] = wqr;
    c.s[1] = qkvwi; c.d[1] = wqi;
    c.s[2] = projwr; c.d[2] = wpr;
    c.s[3] = projwi; c.d[3] = wpi;
    c.s[4] = fc1wr; c.d[4] = w1r;
    c.s[5] = fc1wi; c.d[5] = w1i;
    c.s[6] = fc2wr; c.d[6] = w2r;
    c.s[7] = fc2wi; c.d[7] = w2i;
    const int nseg[8] = {E3 * E, E3 * E, E * E, E * E, HH * E, HH * E, E * HH, E * HH};
    int cum = 0;
    for (int k = 0; k < 8; ++k) {
        c.boff[k] = cum;
        cum += nseg[k] / 1024;
    }
    c.boff[8] = cum;
    cvt8_kernel<<<cum, 256, 0, stream>>>(c);

    // LN1 (reads interleaved x directly)
    cln_kernel<true><<<M, 256, 0, stream>>>(x, nullptr, n1g, n1b, nr, ni);
    // QK GEMM: first 1536 weight rows; 64x128 tiles, grid 768 = 3/CU
    cgemm_kernel<64, 128, 0, 3><<<dim3(64, 12), 256, 0, stream>>>(
        nr, ni, wqr, wqi, qkvbr, qkvbi, nullptr, nullptr, nullptr, nullptr,
        qkr, qki, HH, E);
    // V^T GEMM: out[c][tok] = Wv @ norm^T; 64x128 tiles, grid 384
    cgemm_kernel<64, 128, 4, 3><<<dim3(12, 32), 256, 0, stream>>>(
        wqr + (size_t)HH * E, wqi + (size_t)HH * E, nr, ni,
        qkvbr + HH, qkvbi + HH, nullptr, nullptr, nullptr, nullptr,
        vtr, vti, M, E);
    // attention (64 q-rows per block; 768 blocks = 3/CU exact)
    cattn_kernel<<<dim3(32, 12, 2), 256, 0, stream>>>(qkr, qki, vtr, vti, aor, aoi);
    // proj + interleaved-x residual: 128x64, grid 384
    cgemm_kernel<128, 64, 1, 3><<<dim3(32, 12), 256, 0, stream>>>(
        aor, aoi, wpr, wpi, projbr, projbi, x, nullptr, xr2, xi2, nullptr, nullptr,
        E, E);
    // LN2
    cln_kernel<false><<<M, 256, 0, stream>>>(xr2, xi2, n2g, n2b, nr, ni);
    // FC1 + fast GELU: 64x128 tiles, grid 768 = 3/CU
    cgemm_kernel<64, 128, 2, 3><<<dim3(64, 12), 256, 0, stream>>>(
        nr, ni, w1r, w1i, fc1br, fc1bi, nullptr, nullptr, nullptr, nullptr,
        hr, hi, HH, E);
    // FC2 + residual -> interleaved d_out: 128x64, grid 384
    cgemm_kernel<128, 64, 3, 3><<<dim3(32, 12), 256, 0, stream>>>(
        hr, hi, w2r, w2i, fc2br, fc2bi, xr2, xi2, (float*)d_out, nullptr,
        nullptr, nullptr, E, HH);
}

// Round 13
// 309.320 us; speedup vs baseline: 1.4545x; 1.0804x over previous
//
#include <hip/hip_runtime.h>
#include <cmath>

typedef __bf16 bf16;
typedef __bf16 bf16x8 __attribute__((ext_vector_type(8)));
typedef __bf16 bf16x4 __attribute__((ext_vector_type(4)));
typedef float  f32x4  __attribute__((ext_vector_type(4)));
typedef unsigned int u32x4 __attribute__((ext_vector_type(4)));

#define MFMA16(a, b, c) __builtin_amdgcn_mfma_f32_16x16x32_bf16((a), (b), (c), 0, 0, 0)
#define LOG2E 1.44269504088896f

static __device__ __forceinline__ void gl_lds16(const void* g, void* l) {
    __builtin_amdgcn_global_load_lds((const __attribute__((address_space(1))) void*)g,
                                     (__attribute__((address_space(3))) void*)l, 16, 0, 0);
}

static __device__ __forceinline__ bf16x8 bneg8(bf16x8 x) {
    u32x4 u = __builtin_bit_cast(u32x4, x);
    u = u ^ 0x80008000u;
    return __builtin_bit_cast(bf16x8, u);
}

static __device__ __forceinline__ f32x4 zero4() {
    return f32x4{0.0f, 0.0f, 0.0f, 0.0f};
}

// ---------------------------------------------------------------------------
// small utility kernels
// ---------------------------------------------------------------------------
__global__ void fill_kernel(float* p, float v, int n) {
    for (int i = blockIdx.x * blockDim.x + threadIdx.x; i < n; i += gridDim.x * blockDim.x)
        p[i] = v;
}

// fused 8-way f32 -> bf16 weight conversion (all sizes % 1024 == 0)
struct Cvt8 {
    const float* s[8];
    bf16* d[8];
    int boff[9];
};
__global__ __launch_bounds__(256) void cvt8_kernel(Cvt8 c) {
    int blk = blockIdx.x;
    int seg = 0;
#pragma unroll
    for (int k = 0; k < 7; ++k)
        if (blk >= c.boff[k + 1]) seg = k + 1;
    const int local = blk - c.boff[seg];
    const int i = local * 1024 + threadIdx.x * 4;
    const float4 v = *(const float4*)(c.s[seg] + i);
    bf16x4 o;
    o[0] = (bf16)v.x; o[1] = (bf16)v.y; o[2] = (bf16)v.z; o[3] = (bf16)v.w;
    *(bf16x4*)(c.d[seg] + i) = o;
}

// ---------------------------------------------------------------------------
// complex magnitude layernorm. ILV=true: xa is interleaved float2 [row][768][2]
// ---------------------------------------------------------------------------
template <bool ILV>
__global__ __launch_bounds__(256) void cln_kernel(
    const float* __restrict__ xa, const float* __restrict__ xb,
    const float* __restrict__ gamma, const float* __restrict__ beta,
    bf16* __restrict__ nr, bf16* __restrict__ ni) {
    __shared__ float red[4];
    const int t = threadIdx.x;
    const size_t base = (size_t)blockIdx.x * 768;

    float r[3], im[3], mg[3];
#pragma unroll
    for (int j = 0; j < 3; ++j) {
        const int f = t + j * 256;
        if (ILV) {
            const float2 v = ((const float2*)xa)[base + f];
            r[j] = v.x;
            im[j] = v.y;
        } else {
            r[j] = xa[base + f];
            im[j] = xb[base + f];
        }
        mg[j] = __builtin_amdgcn_sqrtf(r[j] * r[j] + im[j] * im[j] + 1e-6f);
    }
    float s = mg[0] + mg[1] + mg[2];
#pragma unroll
    for (int m = 32; m >= 1; m >>= 1) s += __shfl_xor(s, m);
    if ((t & 63) == 0) red[t >> 6] = s;
    __syncthreads();
    const float mean = (red[0] + red[1] + red[2] + red[3]) * (1.0f / 768.0f);
    __syncthreads();

    float v2 = 0.0f;
#pragma unroll
    for (int j = 0; j < 3; ++j) {
        const float d = mg[j] - mean;
        v2 += d * d;
    }
#pragma unroll
    for (int m = 32; m >= 1; m >>= 1) v2 += __shfl_xor(v2, m);
    if ((t & 63) == 0) red[t >> 6] = v2;
    __syncthreads();
    const float var = (red[0] + red[1] + red[2] + red[3]) * (1.0f / 768.0f);
    const float rstd = rsqrtf(var + 1e-6f);

#pragma unroll
    for (int j = 0; j < 3; ++j) {
        const int f = t + j * 256;
        const float sc = (mg[j] - mean) * rstd / (mg[j] + 1e-6f);
        nr[base + f] = (bf16)(gamma[2 * f] * (r[j] * sc) + beta[2 * f]);
        ni[base + f] = (bf16)(gamma[2 * f + 1] * (im[j] * sc) + beta[2 * f + 1]);
    }
}

// ---------------------------------------------------------------------------
// complex GEMM (NT): double-buffered fused-plane LDS, counted vmcnt,
// single barrier per K-step. XCD-OWNERSHIP swizzle: each XCD owns a
// contiguous slice of the larger re-read axis (rows when !SWZC, cols when
// SWZC), iterated owned-axis-inner so the opposing panel stays L2-hot.
// Requires owned-axis block count % 8 == 0 (all call sites satisfy).
// MODE 0: bf16 planes (bias by col)      MODE 1: f32 planes = float2-res + out
// MODE 2: fast-GELU -> bf16 planes       MODE 3: interleaved f32 = res + out
// MODE 4: bf16 planes, bias by ROW (for V^T = Wv @ norm^T)
// ---------------------------------------------------------------------------
template <int BM, int BN, int MODE, int OCC, bool SWZC>
__global__ __launch_bounds__(256, OCC) void cgemm_kernel(
    const bf16* __restrict__ Ar, const bf16* __restrict__ Ai,
    const bf16* __restrict__ Wr, const bf16* __restrict__ Wi,
    const float* __restrict__ br, const float* __restrict__ bi,
    const float* __restrict__ resr, const float* __restrict__ resi,
    float* __restrict__ outFr, float* __restrict__ outFi,
    bf16* __restrict__ outBr, bf16* __restrict__ outBi,
    int N, int K) {
    constexpr int MR = BM / 32;
    constexpr int NR = BN / 32;
    constexpr int ASEG = BM / 8;
    constexpr int NSEG = (BM + BN) / 8;
    constexpr int SPW = NSEG / 4;

    __shared__ __align__(16) bf16 sA[2][BM][64];  // row = [real 32 | imag 32]
    __shared__ __align__(16) bf16 sB[2][BN][64];

    const int tid = threadIdx.x;
    const int wave = tid >> 6, lane = tid & 63;
    const int lg = lane >> 4, lr = lane & 15;

    // XCD-ownership decode
    const int bid = blockIdx.y * gridDim.x + blockIdx.x;
    const int xcd = bid & 7;
    const int i = bid >> 3;
    int rowb, colb;
    if (SWZC) {
        const int cpx = gridDim.y >> 3;  // col-blocks per XCD
        colb = xcd * cpx + (i % cpx);
        rowb = i / cpx;
    } else {
        const int rpx = gridDim.x >> 3;  // row-blocks per XCD
        rowb = xcd * rpx + (i % rpx);
        colb = i / rpx;
    }
    const int row0 = rowb * BM, col0 = colb * BN;

    const int wm = (wave >> 1) * (BM / 2), wn = (wave & 1) * (BN / 2);

    const int srow = lane >> 3;
    const int schunk = (lane & 7) ^ srow;
    const int spl = schunk >> 2;
    const int sc8 = (schunk & 3) * 8;

    auto issue = [&](int buf, int kt) {
#pragma unroll
        for (int s = 0; s < SPW; ++s) {
            const int id = wave * SPW + s;
            if (id < ASEG) {
                const int row = id * 8 + srow;
                gl_lds16((spl ? Ai : Ar) + (size_t)(row0 + row) * K + kt + sc8,
                         &sA[buf][id * 8][0]);
            } else {
                const int row = (id - ASEG) * 8 + srow;
                gl_lds16((spl ? Wi : Wr) + (size_t)(col0 + row) * K + kt + sc8,
                         &sB[buf][(id - ASEG) * 8][0]);
            }
        }
    };

    f32x4 accr[MR][NR], acci[MR][NR];
#pragma unroll
    for (int a = 0; a < MR; ++a)
#pragma unroll
        for (int b2 = 0; b2 < NR; ++b2) {
            accr[a][b2] = zero4();
            acci[a][b2] = zero4();
        }

    issue(0, 0);

    const int KT = K / 32;
    for (int kt = 0; kt < KT; ++kt) {
        const int buf = kt & 1;
        if (kt + 1 < KT) {
            issue(buf ^ 1, (kt + 1) * 32);
            __builtin_amdgcn_sched_barrier(0);
            if constexpr (SPW == 8)
                asm volatile("s_waitcnt vmcnt(8)" ::: "memory");
            else if constexpr (SPW == 6)
                asm volatile("s_waitcnt vmcnt(6)" ::: "memory");
            else
                asm volatile("s_waitcnt vmcnt(0)" ::: "memory");
        } else {
            asm volatile("s_waitcnt vmcnt(0)" ::: "memory");
        }
        __builtin_amdgcn_sched_barrier(0);
        __builtin_amdgcn_s_barrier();  // the only barrier per K-step
        __builtin_amdgcn_sched_barrier(0);

        bf16x8 ar[MR], ai[MR], an[MR];
#pragma unroll
        for (int mt = 0; mt < MR; ++mt) {
            const int rr = wm + mt * 16 + lr;
            const int slr = lg ^ (rr & 7);
            const int sli = (4 + lg) ^ (rr & 7);
            ar[mt] = *(const bf16x8*)(&sA[buf][rr][slr * 8]);
            ai[mt] = *(const bf16x8*)(&sA[buf][rr][sli * 8]);
            an[mt] = bneg8(ai[mt]);
        }
#pragma unroll
        for (int nt = 0; nt < NR; ++nt) {
            const int rr = wn + nt * 16 + lr;
            const int slr = lg ^ (rr & 7);
            const int sli = (4 + lg) ^ (rr & 7);
            const bf16x8 br8 = *(const bf16x8*)(&sB[buf][rr][slr * 8]);
            const bf16x8 bi8 = *(const bf16x8*)(&sB[buf][rr][sli * 8]);
#pragma unroll
            for (int mt = 0; mt < MR; ++mt) {
                accr[mt][nt] = MFMA16(ar[mt], br8, accr[mt][nt]);
                accr[mt][nt] = MFMA16(an[mt], bi8, accr[mt][nt]);
                acci[mt][nt] = MFMA16(ar[mt], bi8, acci[mt][nt]);
                acci[mt][nt] = MFMA16(ai[mt], br8, acci[mt][nt]);
            }
        }
    }

#pragma unroll
    for (int nt = 0; nt < NR; ++nt) {
        const int col = col0 + wn + nt * 16 + lr;
        const float bre = (MODE == 4) ? 0.0f : br[col];
        const float bie = (MODE == 4) ? 0.0f : bi[col];
#pragma unroll
        for (int mt = 0; mt < MR; ++mt) {
#pragma unroll
            for (int j = 0; j < 4; ++j) {
                const int row = row0 + wm + mt * 16 + lg * 4 + j;
                float vr = accr[mt][nt][j];
                float vi = acci[mt][nt][j];
                if (MODE == 4) {
                    vr += br[row];
                    vi += bi[row];
                } else {
                    vr += bre;
                    vi += bie;
                }
                const size_t o = (size_t)row * N + col;
                if (MODE == 0 || MODE == 4) {
                    outBr[o] = (bf16)vr;
                    outBi[o] = (bf16)vi;
                } else if (MODE == 1) {
                    const float2 rv = ((const float2*)resr)[(size_t)row * 768 + col];
                    outFr[o] = rv.x + vr;
                    outFi[o] = rv.y + vi;
                } else if (MODE == 2) {
                    // fast tanh-GELU
                    const float t2r = fmaf(vr * vr, 0.044715f, 1.0f);
                    const float er = __builtin_amdgcn_exp2f(vr * t2r * 2.3022082f);
                    vr = vr - vr * __builtin_amdgcn_rcpf(er + 1.0f);
                    const float t2i = fmaf(vi * vi, 0.044715f, 1.0f);
                    const float ei = __builtin_amdgcn_exp2f(vi * t2i * 2.3022082f);
                    vi = vi - vi * __builtin_amdgcn_rcpf(ei + 1.0f);
                    outBr[o] = (bf16)vr;
                    outBi[o] = (bf16)vi;
                } else {
                    const size_t ro = (size_t)row * 768 + col;
                    outFr[(size_t)row * 1536 + 2 * col]     = resr[ro] + vr;
                    outFr[(size_t)row * 1536 + 2 * col + 1] = resi[ro] + vi;
                }
            }
        }
    }
}

// ---------------------------------------------------------------------------
// fused complex flash attention v10 (unchanged from R12: 91 us, passed)
// ---------------------------------------------------------------------------
__global__ __launch_bounds__(256, 3) void cattn_kernel(
    const bf16* __restrict__ qkr, const bf16* __restrict__ qki,
    const bf16* __restrict__ vtr, const bf16* __restrict__ vti,
    bf16* __restrict__ aor, bf16* __restrict__ aoi) {
    __shared__ __align__(16) bf16 sK[2][2][32][64];  // double buffer
    __shared__ __align__(16) bf16 sV[3][64][64];     // triple ring (fused planes)
    __shared__ __align__(16) bf16 sP[4][16][40];

    const int tid = threadIdx.x;
    const int w = tid >> 6, lane = tid & 63;
    const int lg = lane >> 4, lr = lane & 15;
    const int qb = blockIdx.x, h = blockIdx.y, b = blockIdx.z;
    const int ld = 1536;

    const int s_krow = lane >> 3;
    const int s_kch8 = ((lane & 7) ^ s_krow) * 8;
    const int s_vlog = (lane & 7) ^ s_krow;
    const int s_vpl = s_vlog >> 2;
    const int s_vk8 = (s_vlog & 3) * 8;

    const bf16* kbase0 = qkr + (size_t)b * 2048 * ld + 768 + h * 64;
    const bf16* kbase1 = qki + (size_t)b * 2048 * ld + 768 + h * 64;
    const bf16* vbase = (s_vpl ? vti : vtr) + (size_t)(h * 64) * 4096 + b * 2048;

    const bf16* kp0 = kbase0 + (size_t)(w * 8 + s_krow) * ld + s_kch8;
    const bf16* kp1 = kbase1 + (size_t)(w * 8 + s_krow) * ld + s_kch8;
    const bf16* vp0 = vbase + (size_t)(w * 8 + s_krow) * 4096 + s_vk8;
    const bf16* vp1 = vbase + (size_t)((4 + w) * 8 + s_krow) * 4096 + s_vk8;

    auto stage = [&](int kb, int vs) {
        gl_lds16(kp0, &sK[kb][0][w * 8][0]);
        gl_lds16(kp1, &sK[kb][1][w * 8][0]);
        gl_lds16(vp0, &sV[vs][w * 8][0]);
        gl_lds16(vp1, &sV[vs][(4 + w) * 8][0]);
        kp0 += 32 * ld;
        kp1 += 32 * ld;
        vp0 += 32;
        vp1 += 32;
    };

    stage(0, 0);

    const size_t qoff = (size_t)(b * 2048 + qb * 64 + w * 16 + lr) * ld + h * 64;
    bf16x8 aqr[2], aqi[2], aqin[2];
#pragma unroll
    for (int ks = 0; ks < 2; ++ks) {
        aqr[ks] = *(const bf16x8*)(qkr + qoff + ks * 32 + lg * 8);
        aqi[ks] = *(const bf16x8*)(qki + qoff + ks * 32 + lg * 8);
        aqin[ks] = bneg8(aqi[ks]);
    }

    f32x4 our[4], oui[4];
#pragma unroll
    for (int d = 0; d < 4; ++d) {
        our[d] = zero4();
        oui[d] = zero4();
    }
    const float C1 = 0.125f * LOG2E;
    float mrun = -1e30f;
    float lrun_p = 0.0f;
    float thr2 = -1.0f;
    float mC2 = 0.0f;

    bf16x8 pfPrev = __builtin_bit_cast(bf16x8, u32x4{0u, 0u, 0u, 0u});
    int vcur = 0, vlast = 0;
    const int slr = lg ^ (lr & 7);
    const int sli = (4 + lg) ^ (lr & 7);

    for (int kt = 0; kt < 64; ++kt) {
        const int kcur = kt & 1;
        int vnext = vcur + 1;
        if (vnext == 3) vnext = 0;
        if (kt < 63) {
            stage(kcur ^ 1, vnext);
            __builtin_amdgcn_sched_barrier(0);
            asm volatile("s_waitcnt vmcnt(4)" ::: "memory");
        } else {
            asm volatile("s_waitcnt vmcnt(0)" ::: "memory");
        }
        __builtin_amdgcn_sched_barrier(0);
        __builtin_amdgcn_s_barrier();  // the only barrier per iteration
        __builtin_amdgcn_sched_barrier(0);

        // ---- QK^T(kt) + PV(kt-1) ----
        f32x4 str[2], sti[2];
        str[0] = zero4(); str[1] = zero4();
        sti[0] = zero4(); sti[1] = zero4();
        __builtin_amdgcn_s_setprio(1);
#pragma unroll
        for (int t = 0; t < 2; ++t) {
#pragma unroll
            for (int ks = 0; ks < 2; ++ks) {
                const int ch = ((ks << 2) | lg) ^ (lr & 7);
                const bf16x8 kr8 = *(const bf16x8*)(&sK[kcur][0][t * 16 + lr][ch * 8]);
                const bf16x8 ki8 = *(const bf16x8*)(&sK[kcur][1][t * 16 + lr][ch * 8]);
                str[t] = MFMA16(kr8, aqr[ks], str[t]);
                str[t] = MFMA16(ki8, aqi[ks], str[t]);
                sti[t] = MFMA16(ki8, aqr[ks], sti[t]);
                sti[t] = MFMA16(kr8, aqin[ks], sti[t]);
            }
        }
        if (kt > 0) {
#pragma unroll
            for (int d = 0; d < 4; ++d) {
                const bf16x8 vr8 = *(const bf16x8*)(&sV[vlast][d * 16 + lr][slr * 8]);
                const bf16x8 vi8 = *(const bf16x8*)(&sV[vlast][d * 16 + lr][sli * 8]);
                our[d] = MFMA16(pfPrev, vr8, our[d]);
                oui[d] = MFMA16(pfPrev, vi8, oui[d]);
            }
        }
        __builtin_amdgcn_s_setprio(0);

        // ---- squared magnitudes; per-lane max only ----
        float v[8];
        float vmax = 0.0f;
#pragma unroll
        for (int t = 0; t < 2; ++t)
#pragma unroll
            for (int j = 0; j < 4; ++j) {
                const float sr = str[t][j], si = sti[t][j];
                const float vv = fmaf(sr, sr, fmaf(si, si, 1e-8f));
                v[t * 4 + j] = vv;
                vmax = fmaxf(vmax, vv);
            }

        if (!__all(vmax <= thr2)) {
            vmax = fmaxf(vmax, __shfl_xor(vmax, 16));
            vmax = fmaxf(vmax, __shfl_xor(vmax, 32));
            const float tm = __builtin_amdgcn_sqrtf(vmax) * 0.125f;
            const float mnew = fmaxf(mrun, tm);
            const float corr = __builtin_amdgcn_exp2f((mrun - mnew) * LOG2E);
            float cj[4];
#pragma unroll
            for (int j = 0; j < 4; ++j) cj[j] = __shfl(corr, lg * 4 + j);
#pragma unroll
            for (int d = 0; d < 4; ++d)
#pragma unroll
                for (int j = 0; j < 4; ++j) {
                    our[d][j] *= cj[j];
                    oui[d][j] *= cj[j];
                }
            lrun_p *= corr;
            mrun = mnew;
            const float m8 = mrun + 8.0f;
            thr2 = 64.0f * m8 * m8;
            mC2 = -mrun * LOG2E;
        }

        float p[8];
        float ls = 0.0f;
#pragma unroll
        for (int i = 0; i < 8; ++i) {
            p[i] = __builtin_amdgcn_exp2f(
                fmaf(__builtin_amdgcn_sqrtf(v[i]), C1, mC2));
            ls += p[i];
        }
        lrun_p += ls;

        // ---- pack P(kt) -> LDS -> pfPrev ----
#pragma unroll
        for (int t = 0; t < 2; ++t) {
            bf16x4 pk;
#pragma unroll
            for (int j = 0; j < 4; ++j) pk[j] = (bf16)p[t * 4 + j];
            *(bf16x4*)(&sP[w][lr][t * 16 + lg * 4]) = pk;
        }
        pfPrev = *(const bf16x8*)(&sP[w][lr][lg * 8]);

        vlast = vcur;
        vcur = vnext;
    }

    // final PV for tile 63
#pragma unroll
    for (int d = 0; d < 4; ++d) {
        const bf16x8 vr8 = *(const bf16x8*)(&sV[vlast][d * 16 + lr][slr * 8]);
        const bf16x8 vi8 = *(const bf16x8*)(&sV[vlast][d * 16 + lr][sli * 8]);
        our[d] = MFMA16(pfPrev, vr8, our[d]);
        oui[d] = MFMA16(pfPrev, vi8, oui[d]);
    }

    float lsum = lrun_p;
    lsum += __shfl_xor(lsum, 16);
    lsum += __shfl_xor(lsum, 32);

    float linv[4];
#pragma unroll
    for (int j = 0; j < 4; ++j) {
        const float lj = __shfl(lsum, lg * 4 + j);
        linv[j] = __builtin_amdgcn_rcpf(lj);
    }
#pragma unroll
    for (int d = 0; d < 4; ++d)
#pragma unroll
        for (int j = 0; j < 4; ++j) {
            const int row = b * 2048 + qb * 64 + w * 16 + lg * 4 + j;
            const int col = h * 64 + d * 16 + lr;
            aor[(size_t)row * 768 + col] = (bf16)(our[d][j] * linv[j]);
            aoi[(size_t)row * 768 + col] = (bf16)(oui[d][j] * linv[j]);
        }
}

// ---------------------------------------------------------------------------
// host launch
// ---------------------------------------------------------------------------
extern "C" void kernel_launch(void* const* d_in, const int* in_sizes, int n_in,
                              void* d_out, int out_size, void* d_ws, size_t ws_size,
                              hipStream_t stream) {
    const float* x      = (const float*)d_in[0];
    const float* n1g    = (const float*)d_in[1];
    const float* n1b    = (const float*)d_in[2];
    const float* qkvwr  = (const float*)d_in[3];
    const float* qkvwi  = (const float*)d_in[4];
    const float* qkvbr  = (const float*)d_in[5];
    const float* qkvbi  = (const float*)d_in[6];
    const float* projwr = (const float*)d_in[7];
    const float* projwi = (const float*)d_in[8];
    const float* projbr = (const float*)d_in[9];
    const float* projbi = (const float*)d_in[10];
    const float* n2g    = (const float*)d_in[11];
    const float* n2b    = (const float*)d_in[12];
    const float* fc1wr  = (const float*)d_in[13];
    const float* fc1wi  = (const float*)d_in[14];
    const float* fc1br  = (const float*)d_in[15];
    const float* fc1bi  = (const float*)d_in[16];
    const float* fc2wr  = (const float*)d_in[17];
    const float* fc2wi  = (const float*)d_in[18];
    const float* fc2br  = (const float*)d_in[19];
    const float* fc2bi  = (const float*)d_in[20];

    const int M = 4096, E = 768, E3 = 2304, HH = 1536;

    char* base = (char*)d_ws;
    size_t off = 0;
    auto alloc = [&](size_t bytes) -> void* {
        void* p = base + off;
        off += (bytes + 255) & ~(size_t)255;
        return p;
    };
    float* xr2 = (float*)alloc((size_t)M * E * 4);
    float* xi2 = (float*)alloc((size_t)M * E * 4);
    bf16* nr   = (bf16*)alloc((size_t)M * E * 2);
    bf16* ni   = (bf16*)alloc((size_t)M * E * 2);
    bf16* wqr  = (bf16*)alloc((size_t)E3 * E * 2);
    bf16* wqi  = (bf16*)alloc((size_t)E3 * E * 2);
    bf16* wpr  = (bf16*)alloc((size_t)E * E * 2);
    bf16* wpi  = (bf16*)alloc((size_t)E * E * 2);
    bf16* w1r  = (bf16*)alloc((size_t)HH * E * 2);
    bf16* w1i  = (bf16*)alloc((size_t)HH * E * 2);
    bf16* w2r  = (bf16*)alloc((size_t)E * HH * 2);
    bf16* w2i  = (bf16*)alloc((size_t)E * HH * 2);
    bf16* qkr  = (bf16*)alloc((size_t)M * HH * 2);   // [4096][1536] Q|K
    bf16* qki  = (bf16*)alloc((size_t)M * HH * 2);
    bf16* vtr  = (bf16*)alloc((size_t)E * M * 2);    // V^T [768][4096]
    bf16* vti  = (bf16*)alloc((size_t)E * M * 2);
    bf16* aor  = (bf16*)alloc((size_t)M * E * 2);
    bf16* aoi  = (bf16*)alloc((size_t)M * E * 2);
    bf16* hr   = (bf16*)alloc((size_t)M * HH * 2);
    bf16* hi   = (bf16*)alloc((size_t)M * HH * 2);

    if (off > ws_size) {
        fill_kernel<<<1024, 256, 0, stream>>>((float*)d_out, 1.0e9f, out_size);
        return;
    }

    // fused weight conversion
    Cvt8 c;
    c.s[0] = qkvwr; c.d[0] = wqr;
    c.s[1] = qkvwi; c.d[1] = wqi;
    c.s[2] = projwr; c.d[2] = wpr;
    c.s[3] = projwi; c.d[3] = wpi;
    c.s[4] = fc1wr; c.d[4] = w1r;
    c.s[5] = fc1wi; c.d[5] = w1i;
    c.s[6] = fc2wr; c.d[6] = w2r;
    c.s[7] = fc2wi; c.d[7] = w2i;
    const int nseg[8] = {E3 * E, E3 * E, E * E, E * E, HH * E, HH * E, E * HH, E * HH};
    int cum = 0;
    for (int k = 0; k < 8; ++k) {
        c.boff[k] = cum;
        cum += nseg[k] / 1024;
    }
    c.boff[8] = cum;
    cvt8_kernel<<<cum, 256, 0, stream>>>(c);

    // LN1 (reads interleaved x directly)
    cln_kernel<true><<<M, 256, 0, stream>>>(x, nullptr, n1g, n1b, nr, ni);
    // QK GEMM: 64x128, grid 768 = 3/CU; XCD owns 8 row-blocks (A-slice 1.6MB)
    cgemm_kernel<64, 128, 0, 3, false><<<dim3(64, 12), 256, 0, stream>>>(
        nr, ni, wqr, wqi, qkvbr, qkvbi, nullptr, nullptr, nullptr, nullptr,
        qkr, qki, HH, E);
    // V^T GEMM: 64x128, grid 384; XCD owns 4 col-blocks (B-slice 1.6MB)
    cgemm_kernel<64, 128, 4, 3, true><<<dim3(12, 32), 256, 0, stream>>>(
        wqr + (size_t)HH * E, wqi + (size_t)HH * E, nr, ni,
        qkvbr + HH, qkvbi + HH, nullptr, nullptr, nullptr, nullptr,
        vtr, vti, M, E);
    // attention (64 q-rows per block; 768 blocks = 3/CU exact)
    cattn_kernel<<<dim3(32, 12, 2), 256, 0, stream>>>(qkr, qki, vtr, vti, aor, aoi);
    // proj + interleaved-x residual: 128x64, grid 384; XCD owns 4 row-blocks
    cgemm_kernel<128, 64, 1, 3, false><<<dim3(32, 12), 256, 0, stream>>>(
        aor, aoi, wpr, wpi, projbr, projbi, x, nullptr, xr2, xi2, nullptr, nullptr,
        E, E);
    // LN2
    cln_kernel<false><<<M, 256, 0, stream>>>(xr2, xi2, n2g, n2b, nr, ni);
    // FC1 + fast GELU: 64x128, grid 768; XCD owns 8 row-blocks
    cgemm_kernel<64, 128, 2, 3, false><<<dim3(64, 12), 256, 0, stream>>>(
        nr, ni, w1r, w1i, fc1br, fc1bi, nullptr, nullptr, nullptr, nullptr,
        hr, hi, HH, E);
    // FC2 + residual -> interleaved d_out: 128x64, grid 384; XCD owns 4 row-blocks
    cgemm_kernel<128, 64, 3, 3, false><<<dim3(32, 12), 256, 0, stream>>>(
        hr, hi, w2r, w2i, fc2br, fc2bi, xr2, xi2, (float*)d_out, nullptr,
        nullptr, nullptr, E, HH);
}

// Round 14
// 305.049 us; speedup vs baseline: 1.4749x; 1.0140x over previous
//
#include <hip/hip_runtime.h>
#include <cmath>

typedef __bf16 bf16;
typedef __bf16 bf16x8 __attribute__((ext_vector_type(8)));
typedef __bf16 bf16x4 __attribute__((ext_vector_type(4)));
typedef float  f32x4  __attribute__((ext_vector_type(4)));
typedef unsigned int u32x4 __attribute__((ext_vector_type(4)));

#define MFMA16(a, b, c) __builtin_amdgcn_mfma_f32_16x16x32_bf16((a), (b), (c), 0, 0, 0)
#define LOG2E 1.44269504088896f

static __device__ __forceinline__ void gl_lds16(const void* g, void* l) {
    __builtin_amdgcn_global_load_lds((const __attribute__((address_space(1))) void*)g,
                                     (__attribute__((address_space(3))) void*)l, 16, 0, 0);
}

static __device__ __forceinline__ bf16x8 bneg8(bf16x8 x) {
    u32x4 u = __builtin_bit_cast(u32x4, x);
    u = u ^ 0x80008000u;
    return __builtin_bit_cast(bf16x8, u);
}

static __device__ __forceinline__ f32x4 zero4() {
    return f32x4{0.0f, 0.0f, 0.0f, 0.0f};
}

// ---------------------------------------------------------------------------
// small utility kernels
// ---------------------------------------------------------------------------
__global__ void fill_kernel(float* p, float v, int n) {
    for (int i = blockIdx.x * blockDim.x + threadIdx.x; i < n; i += gridDim.x * blockDim.x)
        p[i] = v;
}

// fused 8-way f32 -> bf16 weight conversion (all sizes % 1024 == 0)
struct Cvt8 {
    const float* s[8];
    bf16* d[8];
    int boff[9];
};
__global__ __launch_bounds__(256) void cvt8_kernel(Cvt8 c) {
    int blk = blockIdx.x;
    int seg = 0;
#pragma unroll
    for (int k = 0; k < 7; ++k)
        if (blk >= c.boff[k + 1]) seg = k + 1;
    const int local = blk - c.boff[seg];
    const int i = local * 1024 + threadIdx.x * 4;
    const float4 v = *(const float4*)(c.s[seg] + i);
    bf16x4 o;
    o[0] = (bf16)v.x; o[1] = (bf16)v.y; o[2] = (bf16)v.z; o[3] = (bf16)v.w;
    *(bf16x4*)(c.d[seg] + i) = o;
}

// ---------------------------------------------------------------------------
// complex magnitude layernorm. ILV=true: xa is interleaved float2 [row][768][2]
// ---------------------------------------------------------------------------
template <bool ILV>
__global__ __launch_bounds__(256) void cln_kernel(
    const float* __restrict__ xa, const float* __restrict__ xb,
    const float* __restrict__ gamma, const float* __restrict__ beta,
    bf16* __restrict__ nr, bf16* __restrict__ ni) {
    __shared__ float red[4];
    const int t = threadIdx.x;
    const size_t base = (size_t)blockIdx.x * 768;

    float r[3], im[3], mg[3];
#pragma unroll
    for (int j = 0; j < 3; ++j) {
        const int f = t + j * 256;
        if (ILV) {
            const float2 v = ((const float2*)xa)[base + f];
            r[j] = v.x;
            im[j] = v.y;
        } else {
            r[j] = xa[base + f];
            im[j] = xb[base + f];
        }
        mg[j] = __builtin_amdgcn_sqrtf(r[j] * r[j] + im[j] * im[j] + 1e-6f);
    }
    float s = mg[0] + mg[1] + mg[2];
#pragma unroll
    for (int m = 32; m >= 1; m >>= 1) s += __shfl_xor(s, m);
    if ((t & 63) == 0) red[t >> 6] = s;
    __syncthreads();
    const float mean = (red[0] + red[1] + red[2] + red[3]) * (1.0f / 768.0f);
    __syncthreads();

    float v2 = 0.0f;
#pragma unroll
    for (int j = 0; j < 3; ++j) {
        const float d = mg[j] - mean;
        v2 += d * d;
    }
#pragma unroll
    for (int m = 32; m >= 1; m >>= 1) v2 += __shfl_xor(v2, m);
    if ((t & 63) == 0) red[t >> 6] = v2;
    __syncthreads();
    const float var = (red[0] + red[1] + red[2] + red[3]) * (1.0f / 768.0f);
    const float rstd = rsqrtf(var + 1e-6f);

#pragma unroll
    for (int j = 0; j < 3; ++j) {
        const int f = t + j * 256;
        const float sc = (mg[j] - mean) * rstd / (mg[j] + 1e-6f);
        nr[base + f] = (bf16)(gamma[2 * f] * (r[j] * sc) + beta[2 * f]);
        ni[base + f] = (bf16)(gamma[2 * f + 1] * (im[j] * sc) + beta[2 * f + 1]);
    }
}

// ---------------------------------------------------------------------------
// complex GEMM (NT): double-buffered fused-plane LDS, counted vmcnt,
// single barrier per K-step. XCD-OWNERSHIP swizzle (R13).
// MODE 0: bf16 planes (bias by col)      MODE 1: f32 planes = float2-res + out
// MODE 2: fast-GELU -> bf16 planes       MODE 3: interleaved f32 = res + out
// MODE 4: bf16 planes, bias by ROW (for V^T = Wv @ norm^T)
// ---------------------------------------------------------------------------
template <int BM, int BN, int MODE, int OCC, bool SWZC>
__global__ __launch_bounds__(256, OCC) void cgemm_kernel(
    const bf16* __restrict__ Ar, const bf16* __restrict__ Ai,
    const bf16* __restrict__ Wr, const bf16* __restrict__ Wi,
    const float* __restrict__ br, const float* __restrict__ bi,
    const float* __restrict__ resr, const float* __restrict__ resi,
    float* __restrict__ outFr, float* __restrict__ outFi,
    bf16* __restrict__ outBr, bf16* __restrict__ outBi,
    int N, int K) {
    constexpr int MR = BM / 32;
    constexpr int NR = BN / 32;
    constexpr int ASEG = BM / 8;
    constexpr int NSEG = (BM + BN) / 8;
    constexpr int SPW = NSEG / 4;

    __shared__ __align__(16) bf16 sA[2][BM][64];  // row = [real 32 | imag 32]
    __shared__ __align__(16) bf16 sB[2][BN][64];

    const int tid = threadIdx.x;
    const int wave = tid >> 6, lane = tid & 63;
    const int lg = lane >> 4, lr = lane & 15;

    // XCD-ownership decode
    const int bid = blockIdx.y * gridDim.x + blockIdx.x;
    const int xcd = bid & 7;
    const int i = bid >> 3;
    int rowb, colb;
    if (SWZC) {
        const int cpx = gridDim.y >> 3;
        colb = xcd * cpx + (i % cpx);
        rowb = i / cpx;
    } else {
        const int rpx = gridDim.x >> 3;
        rowb = xcd * rpx + (i % rpx);
        colb = i / rpx;
    }
    const int row0 = rowb * BM, col0 = colb * BN;

    const int wm = (wave >> 1) * (BM / 2), wn = (wave & 1) * (BN / 2);

    const int srow = lane >> 3;
    const int schunk = (lane & 7) ^ srow;
    const int spl = schunk >> 2;
    const int sc8 = (schunk & 3) * 8;

    auto issue = [&](int buf, int kt) {
#pragma unroll
        for (int s = 0; s < SPW; ++s) {
            const int id = wave * SPW + s;
            if (id < ASEG) {
                const int row = id * 8 + srow;
                gl_lds16((spl ? Ai : Ar) + (size_t)(row0 + row) * K + kt + sc8,
                         &sA[buf][id * 8][0]);
            } else {
                const int row = (id - ASEG) * 8 + srow;
                gl_lds16((spl ? Wi : Wr) + (size_t)(col0 + row) * K + kt + sc8,
                         &sB[buf][(id - ASEG) * 8][0]);
            }
        }
    };

    f32x4 accr[MR][NR], acci[MR][NR];
#pragma unroll
    for (int a = 0; a < MR; ++a)
#pragma unroll
        for (int b2 = 0; b2 < NR; ++b2) {
            accr[a][b2] = zero4();
            acci[a][b2] = zero4();
        }

    issue(0, 0);

    const int KT = K / 32;
    for (int kt = 0; kt < KT; ++kt) {
        const int buf = kt & 1;
        if (kt + 1 < KT) {
            issue(buf ^ 1, (kt + 1) * 32);
            __builtin_amdgcn_sched_barrier(0);
            if constexpr (SPW == 8)
                asm volatile("s_waitcnt vmcnt(8)" ::: "memory");
            else if constexpr (SPW == 6)
                asm volatile("s_waitcnt vmcnt(6)" ::: "memory");
            else
                asm volatile("s_waitcnt vmcnt(0)" ::: "memory");
        } else {
            asm volatile("s_waitcnt vmcnt(0)" ::: "memory");
        }
        __builtin_amdgcn_sched_barrier(0);
        __builtin_amdgcn_s_barrier();  // the only barrier per K-step
        __builtin_amdgcn_sched_barrier(0);

        bf16x8 ar[MR], ai[MR], an[MR];
#pragma unroll
        for (int mt = 0; mt < MR; ++mt) {
            const int rr = wm + mt * 16 + lr;
            const int slr = lg ^ (rr & 7);
            const int sli = (4 + lg) ^ (rr & 7);
            ar[mt] = *(const bf16x8*)(&sA[buf][rr][slr * 8]);
            ai[mt] = *(const bf16x8*)(&sA[buf][rr][sli * 8]);
            an[mt] = bneg8(ai[mt]);
        }
#pragma unroll
        for (int nt = 0; nt < NR; ++nt) {
            const int rr = wn + nt * 16 + lr;
            const int slr = lg ^ (rr & 7);
            const int sli = (4 + lg) ^ (rr & 7);
            const bf16x8 br8 = *(const bf16x8*)(&sB[buf][rr][slr * 8]);
            const bf16x8 bi8 = *(const bf16x8*)(&sB[buf][rr][sli * 8]);
#pragma unroll
            for (int mt = 0; mt < MR; ++mt) {
                accr[mt][nt] = MFMA16(ar[mt], br8, accr[mt][nt]);
                accr[mt][nt] = MFMA16(an[mt], bi8, accr[mt][nt]);
                acci[mt][nt] = MFMA16(ar[mt], bi8, acci[mt][nt]);
                acci[mt][nt] = MFMA16(ai[mt], br8, acci[mt][nt]);
            }
        }
    }

#pragma unroll
    for (int nt = 0; nt < NR; ++nt) {
        const int col = col0 + wn + nt * 16 + lr;
        const float bre = (MODE == 4) ? 0.0f : br[col];
        const float bie = (MODE == 4) ? 0.0f : bi[col];
#pragma unroll
        for (int mt = 0; mt < MR; ++mt) {
#pragma unroll
            for (int j = 0; j < 4; ++j) {
                const int row = row0 + wm + mt * 16 + lg * 4 + j;
                float vr = accr[mt][nt][j];
                float vi = acci[mt][nt][j];
                if (MODE == 4) {
                    vr += br[row];
                    vi += bi[row];
                } else {
                    vr += bre;
                    vi += bie;
                }
                const size_t o = (size_t)row * N + col;
                if (MODE == 0 || MODE == 4) {
                    outBr[o] = (bf16)vr;
                    outBi[o] = (bf16)vi;
                } else if (MODE == 1) {
                    const float2 rv = ((const float2*)resr)[(size_t)row * 768 + col];
                    outFr[o] = rv.x + vr;
                    outFi[o] = rv.y + vi;
                } else if (MODE == 2) {
                    // fast tanh-GELU
                    const float t2r = fmaf(vr * vr, 0.044715f, 1.0f);
                    const float er = __builtin_amdgcn_exp2f(vr * t2r * 2.3022082f);
                    vr = vr - vr * __builtin_amdgcn_rcpf(er + 1.0f);
                    const float t2i = fmaf(vi * vi, 0.044715f, 1.0f);
                    const float ei = __builtin_amdgcn_exp2f(vi * t2i * 2.3022082f);
                    vi = vi - vi * __builtin_amdgcn_rcpf(ei + 1.0f);
                    outBr[o] = (bf16)vr;
                    outBi[o] = (bf16)vi;
                } else {
                    const size_t ro = (size_t)row * 768 + col;
                    outFr[(size_t)row * 1536 + 2 * col]     = resr[ro] + vr;
                    outFr[(size_t)row * 1536 + 2 * col + 1] = resi[ro] + vi;
                }
            }
        }
    }
}

// ---------------------------------------------------------------------------
// fused complex flash attention v11: v10 + XCD-group swizzle — all 32
// qb-blocks of one (h,b) land on the same XCD so its 1MB K/V panel stays
// L2-resident (staging loads become L2 hits; 1-iter prefetch covers them).
// Launched 1D: grid 768 = 8 XCD x 3 (h,b)-groups x 32 qb.
// ---------------------------------------------------------------------------
__global__ __launch_bounds__(256, 3) void cattn_kernel(
    const bf16* __restrict__ qkr, const bf16* __restrict__ qki,
    const bf16* __restrict__ vtr, const bf16* __restrict__ vti,
    bf16* __restrict__ aor, bf16* __restrict__ aoi) {
    __shared__ __align__(16) bf16 sK[2][2][32][64];  // double buffer
    __shared__ __align__(16) bf16 sV[3][64][64];     // triple ring (fused planes)
    __shared__ __align__(16) bf16 sP[4][16][40];

    const int tid = threadIdx.x;
    const int w = tid >> 6, lane = tid & 63;
    const int lg = lane >> 4, lr = lane & 15;

    // XCD-group decode: bid = qb + 32*grp_local + 96*xcd pattern inverted
    const int bid = blockIdx.x;
    const int xcd = bid & 7;
    const int i = bid >> 3;                 // 0..95
    const int grp = xcd * 3 + (i >> 5);     // 0..23: this XCD owns 3 groups
    const int qb = i & 31;
    const int h = grp % 12, b = grp / 12;
    const int ld = 1536;

    const int s_krow = lane >> 3;
    const int s_kch8 = ((lane & 7) ^ s_krow) * 8;
    const int s_vlog = (lane & 7) ^ s_krow;
    const int s_vpl = s_vlog >> 2;
    const int s_vk8 = (s_vlog & 3) * 8;

    const bf16* kbase0 = qkr + (size_t)b * 2048 * ld + 768 + h * 64;
    const bf16* kbase1 = qki + (size_t)b * 2048 * ld + 768 + h * 64;
    const bf16* vbase = (s_vpl ? vti : vtr) + (size_t)(h * 64) * 4096 + b * 2048;

    const bf16* kp0 = kbase0 + (size_t)(w * 8 + s_krow) * ld + s_kch8;
    const bf16* kp1 = kbase1 + (size_t)(w * 8 + s_krow) * ld + s_kch8;
    const bf16* vp0 = vbase + (size_t)(w * 8 + s_krow) * 4096 + s_vk8;
    const bf16* vp1 = vbase + (size_t)((4 + w) * 8 + s_krow) * 4096 + s_vk8;

    auto stage = [&](int kb, int vs) {
        gl_lds16(kp0, &sK[kb][0][w * 8][0]);
        gl_lds16(kp1, &sK[kb][1][w * 8][0]);
        gl_lds16(vp0, &sV[vs][w * 8][0]);
        gl_lds16(vp1, &sV[vs][(4 + w) * 8][0]);
        kp0 += 32 * ld;
        kp1 += 32 * ld;
        vp0 += 32;
        vp1 += 32;
    };

    stage(0, 0);

    const size_t qoff = (size_t)(b * 2048 + qb * 64 + w * 16 + lr) * ld + h * 64;
    bf16x8 aqr[2], aqi[2], aqin[2];
#pragma unroll
    for (int ks = 0; ks < 2; ++ks) {
        aqr[ks] = *(const bf16x8*)(qkr + qoff + ks * 32 + lg * 8);
        aqi[ks] = *(const bf16x8*)(qki + qoff + ks * 32 + lg * 8);
        aqin[ks] = bneg8(aqi[ks]);
    }

    f32x4 our[4], oui[4];
#pragma unroll
    for (int d = 0; d < 4; ++d) {
        our[d] = zero4();
        oui[d] = zero4();
    }
    const float C1 = 0.125f * LOG2E;
    float mrun = -1e30f;
    float lrun_p = 0.0f;
    float thr2 = -1.0f;
    float mC2 = 0.0f;

    bf16x8 pfPrev = __builtin_bit_cast(bf16x8, u32x4{0u, 0u, 0u, 0u});
    int vcur = 0, vlast = 0;
    const int slr = lg ^ (lr & 7);
    const int sli = (4 + lg) ^ (lr & 7);

    for (int kt = 0; kt < 64; ++kt) {
        const int kcur = kt & 1;
        int vnext = vcur + 1;
        if (vnext == 3) vnext = 0;
        if (kt < 63) {
            stage(kcur ^ 1, vnext);
            __builtin_amdgcn_sched_barrier(0);
            asm volatile("s_waitcnt vmcnt(4)" ::: "memory");
        } else {
            asm volatile("s_waitcnt vmcnt(0)" ::: "memory");
        }
        __builtin_amdgcn_sched_barrier(0);
        __builtin_amdgcn_s_barrier();  // the only barrier per iteration
        __builtin_amdgcn_sched_barrier(0);

        // ---- QK^T(kt) + PV(kt-1) ----
        f32x4 str[2], sti[2];
        str[0] = zero4(); str[1] = zero4();
        sti[0] = zero4(); sti[1] = zero4();
        __builtin_amdgcn_s_setprio(1);
#pragma unroll
        for (int t = 0; t < 2; ++t) {
#pragma unroll
            for (int ks = 0; ks < 2; ++ks) {
                const int ch = ((ks << 2) | lg) ^ (lr & 7);
                const bf16x8 kr8 = *(const bf16x8*)(&sK[kcur][0][t * 16 + lr][ch * 8]);
                const bf16x8 ki8 = *(const bf16x8*)(&sK[kcur][1][t * 16 + lr][ch * 8]);
                str[t] = MFMA16(kr8, aqr[ks], str[t]);
                str[t] = MFMA16(ki8, aqi[ks], str[t]);
                sti[t] = MFMA16(ki8, aqr[ks], sti[t]);
                sti[t] = MFMA16(kr8, aqin[ks], sti[t]);
            }
        }
        if (kt > 0) {
#pragma unroll
            for (int d = 0; d < 4; ++d) {
                const bf16x8 vr8 = *(const bf16x8*)(&sV[vlast][d * 16 + lr][slr * 8]);
                const bf16x8 vi8 = *(const bf16x8*)(&sV[vlast][d * 16 + lr][sli * 8]);
                our[d] = MFMA16(pfPrev, vr8, our[d]);
                oui[d] = MFMA16(pfPrev, vi8, oui[d]);
            }
        }
        __builtin_amdgcn_s_setprio(0);

        // ---- squared magnitudes; per-lane max only ----
        float v[8];
        float vmax = 0.0f;
#pragma unroll
        for (int t = 0; t < 2; ++t)
#pragma unroll
            for (int j = 0; j < 4; ++j) {
                const float sr = str[t][j], si = sti[t][j];
                const float vv = fmaf(sr, sr, fmaf(si, si, 1e-8f));
                v[t * 4 + j] = vv;
                vmax = fmaxf(vmax, vv);
            }

        if (!__all(vmax <= thr2)) {
            vmax = fmaxf(vmax, __shfl_xor(vmax, 16));
            vmax = fmaxf(vmax, __shfl_xor(vmax, 32));
            const float tm = __builtin_amdgcn_sqrtf(vmax) * 0.125f;
            const float mnew = fmaxf(mrun, tm);
            const float corr = __builtin_amdgcn_exp2f((mrun - mnew) * LOG2E);
            float cj[4];
#pragma unroll
            for (int j = 0; j < 4; ++j) cj[j] = __shfl(corr, lg * 4 + j);
#pragma unroll
            for (int d = 0; d < 4; ++d)
#pragma unroll
                for (int j = 0; j < 4; ++j) {
                    our[d][j] *= cj[j];
                    oui[d][j] *= cj[j];
                }
            lrun_p *= corr;
            mrun = mnew;
            const float m8 = mrun + 8.0f;
            thr2 = 64.0f * m8 * m8;
            mC2 = -mrun * LOG2E;
        }

        float p[8];
        float ls = 0.0f;
#pragma unroll
        for (int i2 = 0; i2 < 8; ++i2) {
            p[i2] = __builtin_amdgcn_exp2f(
                fmaf(__builtin_amdgcn_sqrtf(v[i2]), C1, mC2));
            ls += p[i2];
        }
        lrun_p += ls;

        // ---- pack P(kt) -> LDS -> pfPrev ----
#pragma unroll
        for (int t = 0; t < 2; ++t) {
            bf16x4 pk;
#pragma unroll
            for (int j = 0; j < 4; ++j) pk[j] = (bf16)p[t * 4 + j];
            *(bf16x4*)(&sP[w][lr][t * 16 + lg * 4]) = pk;
        }
        pfPrev = *(const bf16x8*)(&sP[w][lr][lg * 8]);

        vlast = vcur;
        vcur = vnext;
    }

    // final PV for tile 63
#pragma unroll
    for (int d = 0; d < 4; ++d) {
        const bf16x8 vr8 = *(const bf16x8*)(&sV[vlast][d * 16 + lr][slr * 8]);
        const bf16x8 vi8 = *(const bf16x8*)(&sV[vlast][d * 16 + lr][sli * 8]);
        our[d] = MFMA16(pfPrev, vr8, our[d]);
        oui[d] = MFMA16(pfPrev, vi8, oui[d]);
    }

    float lsum = lrun_p;
    lsum += __shfl_xor(lsum, 16);
    lsum += __shfl_xor(lsum, 32);

    float linv[4];
#pragma unroll
    for (int j = 0; j < 4; ++j) {
        const float lj = __shfl(lsum, lg * 4 + j);
        linv[j] = __builtin_amdgcn_rcpf(lj);
    }
#pragma unroll
    for (int d = 0; d < 4; ++d)
#pragma unroll
        for (int j = 0; j < 4; ++j) {
            const int row = b * 2048 + qb * 64 + w * 16 + lg * 4 + j;
            const int col = h * 64 + d * 16 + lr;
            aor[(size_t)row * 768 + col] = (bf16)(our[d][j] * linv[j]);
            aoi[(size_t)row * 768 + col] = (bf16)(oui[d][j] * linv[j]);
        }
}

// ---------------------------------------------------------------------------
// host launch
// ---------------------------------------------------------------------------
extern "C" void kernel_launch(void* const* d_in, const int* in_sizes, int n_in,
                              void* d_out, int out_size, void* d_ws, size_t ws_size,
                              hipStream_t stream) {
    const float* x      = (const float*)d_in[0];
    const float* n1g    = (const float*)d_in[1];
    const float* n1b    = (const float*)d_in[2];
    const float* qkvwr  = (const float*)d_in[3];
    const float* qkvwi  = (const float*)d_in[4];
    const float* qkvbr  = (const float*)d_in[5];
    const float* qkvbi  = (const float*)d_in[6];
    const float* projwr = (const float*)d_in[7];
    const float* projwi = (const float*)d_in[8];
    const float* projbr = (const float*)d_in[9];
    const float* projbi = (const float*)d_in[10];
    const float* n2g    = (const float*)d_in[11];
    const float* n2b    = (const float*)d_in[12];
    const float* fc1wr  = (const float*)d_in[13];
    const float* fc1wi  = (const float*)d_in[14];
    const float* fc1br  = (const float*)d_in[15];
    const float* fc1bi  = (const float*)d_in[16];
    const float* fc2wr  = (const float*)d_in[17];
    const float* fc2wi  = (const float*)d_in[18];
    const float* fc2br  = (const float*)d_in[19];
    const float* fc2bi  = (const float*)d_in[20];

    const int M = 4096, E = 768, E3 = 2304, HH = 1536;

    char* base = (char*)d_ws;
    size_t off = 0;
    auto alloc = [&](size_t bytes) -> void* {
        void* p = base + off;
        off += (bytes + 255) & ~(size_t)255;
        return p;
    };
    float* xr2 = (float*)alloc((size_t)M * E * 4);
    float* xi2 = (float*)alloc((size_t)M * E * 4);
    bf16* nr   = (bf16*)alloc((size_t)M * E * 2);
    bf16* ni   = (bf16*)alloc((size_t)M * E * 2);
    bf16* wqr  = (bf16*)alloc((size_t)E3 * E * 2);
    bf16* wqi  = (bf16*)alloc((size_t)E3 * E * 2);
    bf16* wpr  = (bf16*)alloc((size_t)E * E * 2);
    bf16* wpi  = (bf16*)alloc((size_t)E * E * 2);
    bf16* w1r  = (bf16*)alloc((size_t)HH * E * 2);
    bf16* w1i  = (bf16*)alloc((size_t)HH * E * 2);
    bf16* w2r  = (bf16*)alloc((size_t)E * HH * 2);
    bf16* w2i  = (bf16*)alloc((size_t)E * HH * 2);
    bf16* qkr  = (bf16*)alloc((size_t)M * HH * 2);   // [4096][1536] Q|K
    bf16* qki  = (bf16*)alloc((size_t)M * HH * 2);
    bf16* vtr  = (bf16*)alloc((size_t)E * M * 2);    // V^T [768][4096]
    bf16* vti  = (bf16*)alloc((size_t)E * M * 2);
    bf16* aor  = (bf16*)alloc((size_t)M * E * 2);
    bf16* aoi  = (bf16*)alloc((size_t)M * E * 2);
    bf16* hr   = (bf16*)alloc((size_t)M * HH * 2);
    bf16* hi   = (bf16*)alloc((size_t)M * HH * 2);

    if (off > ws_size) {
        fill_kernel<<<1024, 256, 0, stream>>>((float*)d_out, 1.0e9f, out_size);
        return;
    }

    // fused weight conversion
    Cvt8 c;
    c.s[0] = qkvwr; c.d[0] = wqr;
    c.s[1] = qkvwi; c.d[1] = wqi;
    c.s[2] = projwr; c.d[2] = wpr;
    c.s[3] = projwi; c.d[3] = wpi;
    c.s[4] = fc1wr; c.d[4] = w1r;
    c.s[5] = fc1wi; c.d[5] = w1i;
    c.s[6] = fc2wr; c.d[6] = w2r;
    c.s[7] = fc2wi; c.d[7] = w2i;
    const int nseg[8] = {E3 * E, E3 * E, E * E, E * E, HH * E, HH * E, E * HH, E * HH};
    int cum = 0;
    for (int k = 0; k < 8; ++k) {
        c.boff[k] = cum;
        cum += nseg[k] / 1024;
    }
    c.boff[8] = cum;
    cvt8_kernel<<<cum, 256, 0, stream>>>(c);

    // LN1 (reads interleaved x directly)
    cln_kernel<true><<<M, 256, 0, stream>>>(x, nullptr, n1g, n1b, nr, ni);
    // QK GEMM: 64x128, grid 768 = 3/CU; XCD owns 8 row-blocks
    cgemm_kernel<64, 128, 0, 3, false><<<dim3(64, 12), 256, 0, stream>>>(
        nr, ni, wqr, wqi, qkvbr, qkvbi, nullptr, nullptr, nullptr, nullptr,
        qkr, qki, HH, E);
    // V^T GEMM: 64x128, grid 384; XCD owns 4 col-blocks
    cgemm_kernel<64, 128, 4, 3, true><<<dim3(12, 32), 256, 0, stream>>>(
        wqr + (size_t)HH * E, wqi + (size_t)HH * E, nr, ni,
        qkvbr + HH, qkvbi + HH, nullptr, nullptr, nullptr, nullptr,
        vtr, vti, M, E);
    // attention: 1D grid 768; per-XCD (h,b) grouping for K/V L2 residency
    cattn_kernel<<<768, 256, 0, stream>>>(qkr, qki, vtr, vti, aor, aoi);
    // proj + interleaved-x residual: 128x64, grid 384; XCD owns 4 row-blocks
    cgemm_kernel<128, 64, 1, 3, false><<<dim3(32, 12), 256, 0, stream>>>(
        aor, aoi, wpr, wpi, projbr, projbi, x, nullptr, xr2, xi2, nullptr, nullptr,
        E, E);
    // LN2
    cln_kernel<false><<<M, 256, 0, stream>>>(xr2, xi2, n2g, n2b, nr, ni);
    // FC1 + fast GELU: 64x128, grid 768; XCD owns 8 row-blocks
    cgemm_kernel<64, 128, 2, 3, false><<<dim3(64, 12), 256, 0, stream>>>(
        nr, ni, w1r, w1i, fc1br, fc1bi, nullptr, nullptr, nullptr, nullptr,
        hr, hi, HH, E);
    // FC2 + residual -> interleaved d_out: 128x64, grid 384; XCD owns 4 row-blocks
    cgemm_kernel<128, 64, 3, 3, false><<<dim3(32, 12), 256, 0, stream>>>(
        hr, hi, w2r, w2i, fc2br, fc2bi, xr2, xi2, (float*)d_out, nullptr,
        nullptr, nullptr, E, HH);
}

// Round 15
// 300.839 us; speedup vs baseline: 1.4955x; 1.0140x over previous
//
#include <hip/hip_runtime.h>
#include <cmath>

typedef __bf16 bf16;
typedef __bf16 bf16x8 __attribute__((ext_vector_type(8)));
typedef __bf16 bf16x4 __attribute__((ext_vector_type(4)));
typedef float  f32x4  __attribute__((ext_vector_type(4)));
typedef unsigned int u32x4 __attribute__((ext_vector_type(4)));

#define MFMA16(a, b, c) __builtin_amdgcn_mfma_f32_16x16x32_bf16((a), (b), (c), 0, 0, 0)
#define LOG2E 1.44269504088896f

static __device__ __forceinline__ void gl_lds16(const void* g, void* l) {
    __builtin_amdgcn_global_load_lds((const __attribute__((address_space(1))) void*)g,
                                     (__attribute__((address_space(3))) void*)l, 16, 0, 0);
}

static __device__ __forceinline__ bf16x8 bneg8(bf16x8 x) {
    u32x4 u = __builtin_bit_cast(u32x4, x);
    u = u ^ 0x80008000u;
    return __builtin_bit_cast(bf16x8, u);
}

static __device__ __forceinline__ f32x4 zero4() {
    return f32x4{0.0f, 0.0f, 0.0f, 0.0f};
}

// ---------------------------------------------------------------------------
// small utility kernels
// ---------------------------------------------------------------------------
__global__ void fill_kernel(float* p, float v, int n) {
    for (int i = blockIdx.x * blockDim.x + threadIdx.x; i < n; i += gridDim.x * blockDim.x)
        p[i] = v;
}

// fused 8-way f32 -> bf16 weight conversion (all sizes % 1024 == 0)
struct Cvt8 {
    const float* s[8];
    bf16* d[8];
    int boff[9];
};
__global__ __launch_bounds__(256) void cvt8_kernel(Cvt8 c) {
    int blk = blockIdx.x;
    int seg = 0;
#pragma unroll
    for (int k = 0; k < 7; ++k)
        if (blk >= c.boff[k + 1]) seg = k + 1;
    const int local = blk - c.boff[seg];
    const int i = local * 1024 + threadIdx.x * 4;
    const float4 v = *(const float4*)(c.s[seg] + i);
    bf16x4 o;
    o[0] = (bf16)v.x; o[1] = (bf16)v.y; o[2] = (bf16)v.z; o[3] = (bf16)v.w;
    *(bf16x4*)(c.d[seg] + i) = o;
}

// ---------------------------------------------------------------------------
// complex magnitude layernorm.
// SRC 1: xa = interleaved float2 [row][768][2]
// SRC 2: xa, xb = bf16 planes
// ---------------------------------------------------------------------------
template <int SRC>
__global__ __launch_bounds__(256) void cln_kernel(
    const void* __restrict__ xa, const void* __restrict__ xb,
    const float* __restrict__ gamma, const float* __restrict__ beta,
    bf16* __restrict__ nr, bf16* __restrict__ ni) {
    __shared__ float red[4];
    const int t = threadIdx.x;
    const size_t base = (size_t)blockIdx.x * 768;

    float r[3], im[3], mg[3];
#pragma unroll
    for (int j = 0; j < 3; ++j) {
        const int f = t + j * 256;
        if (SRC == 1) {
            const float2 v = ((const float2*)xa)[base + f];
            r[j] = v.x;
            im[j] = v.y;
        } else {
            r[j] = (float)((const bf16*)xa)[base + f];
            im[j] = (float)((const bf16*)xb)[base + f];
        }
        mg[j] = __builtin_amdgcn_sqrtf(r[j] * r[j] + im[j] * im[j] + 1e-6f);
    }
    float s = mg[0] + mg[1] + mg[2];
#pragma unroll
    for (int m = 32; m >= 1; m >>= 1) s += __shfl_xor(s, m);
    if ((t & 63) == 0) red[t >> 6] = s;
    __syncthreads();
    const float mean = (red[0] + red[1] + red[2] + red[3]) * (1.0f / 768.0f);
    __syncthreads();

    float v2 = 0.0f;
#pragma unroll
    for (int j = 0; j < 3; ++j) {
        const float d = mg[j] - mean;
        v2 += d * d;
    }
#pragma unroll
    for (int m = 32; m >= 1; m >>= 1) v2 += __shfl_xor(v2, m);
    if ((t & 63) == 0) red[t >> 6] = v2;
    __syncthreads();
    const float var = (red[0] + red[1] + red[2] + red[3]) * (1.0f / 768.0f);
    const float rstd = rsqrtf(var + 1e-6f);

#pragma unroll
    for (int j = 0; j < 3; ++j) {
        const int f = t + j * 256;
        const float sc = (mg[j] - mean) * rstd / (mg[j] + 1e-6f);
        nr[base + f] = (bf16)(gamma[2 * f] * (r[j] * sc) + beta[2 * f]);
        ni[base + f] = (bf16)(gamma[2 * f + 1] * (im[j] * sc) + beta[2 * f + 1]);
    }
}

// ---------------------------------------------------------------------------
// complex GEMM (NT): double-buffered fused-plane LDS, counted vmcnt,
// single barrier per K-step, XCD-ownership swizzle, setprio on MFMA cluster.
// MODE 0: bf16 planes (bias by col)
// MODE 1: bf16 planes = float2-res + out   (residual add, bf16 store)
// MODE 2: fast-GELU -> bf16 planes
// MODE 3: interleaved f32 d_out = bf16-res-planes + out
// MODE 4: bf16 planes, bias by ROW (for V^T = Wv @ norm^T)
// ---------------------------------------------------------------------------
template <int BM, int BN, int MODE, int OCC, bool SWZC>
__global__ __launch_bounds__(256, OCC) void cgemm_kernel(
    const bf16* __restrict__ Ar, const bf16* __restrict__ Ai,
    const bf16* __restrict__ Wr, const bf16* __restrict__ Wi,
    const float* __restrict__ br, const float* __restrict__ bi,
    const void* __restrict__ resr, const void* __restrict__ resi,
    float* __restrict__ outFr, float* __restrict__ outFi,
    bf16* __restrict__ outBr, bf16* __restrict__ outBi,
    int N, int K) {
    constexpr int MR = BM / 32;
    constexpr int NR = BN / 32;
    constexpr int ASEG = BM / 8;
    constexpr int NSEG = (BM + BN) / 8;
    constexpr int SPW = NSEG / 4;

    __shared__ __align__(16) bf16 sA[2][BM][64];  // row = [real 32 | imag 32]
    __shared__ __align__(16) bf16 sB[2][BN][64];

    const int tid = threadIdx.x;
    const int wave = tid >> 6, lane = tid & 63;
    const int lg = lane >> 4, lr = lane & 15;

    // XCD-ownership decode
    const int bid = blockIdx.y * gridDim.x + blockIdx.x;
    const int xcd = bid & 7;
    const int i = bid >> 3;
    int rowb, colb;
    if (SWZC) {
        const int cpx = gridDim.y >> 3;
        colb = xcd * cpx + (i % cpx);
        rowb = i / cpx;
    } else {
        const int rpx = gridDim.x >> 3;
        rowb = xcd * rpx + (i % rpx);
        colb = i / rpx;
    }
    const int row0 = rowb * BM, col0 = colb * BN;

    const int wm = (wave >> 1) * (BM / 2), wn = (wave & 1) * (BN / 2);

    const int srow = lane >> 3;
    const int schunk = (lane & 7) ^ srow;
    const int spl = schunk >> 2;
    const int sc8 = (schunk & 3) * 8;

    auto issue = [&](int buf, int kt) {
#pragma unroll
        for (int s = 0; s < SPW; ++s) {
            const int id = wave * SPW + s;
            if (id < ASEG) {
                const int row = id * 8 + srow;
                gl_lds16((spl ? Ai : Ar) + (size_t)(row0 + row) * K + kt + sc8,
                         &sA[buf][id * 8][0]);
            } else {
                const int row = (id - ASEG) * 8 + srow;
                gl_lds16((spl ? Wi : Wr) + (size_t)(col0 + row) * K + kt + sc8,
                         &sB[buf][(id - ASEG) * 8][0]);
            }
        }
    };

    f32x4 accr[MR][NR], acci[MR][NR];
#pragma unroll
    for (int a = 0; a < MR; ++a)
#pragma unroll
        for (int b2 = 0; b2 < NR; ++b2) {
            accr[a][b2] = zero4();
            acci[a][b2] = zero4();
        }

    issue(0, 0);

    const int KT = K / 32;
    for (int kt = 0; kt < KT; ++kt) {
        const int buf = kt & 1;
        if (kt + 1 < KT) {
            issue(buf ^ 1, (kt + 1) * 32);
            __builtin_amdgcn_sched_barrier(0);
            if constexpr (SPW == 8)
                asm volatile("s_waitcnt vmcnt(8)" ::: "memory");
            else if constexpr (SPW == 6)
                asm volatile("s_waitcnt vmcnt(6)" ::: "memory");
            else
                asm volatile("s_waitcnt vmcnt(0)" ::: "memory");
        } else {
            asm volatile("s_waitcnt vmcnt(0)" ::: "memory");
        }
        __builtin_amdgcn_sched_barrier(0);
        __builtin_amdgcn_s_barrier();  // the only barrier per K-step
        __builtin_amdgcn_sched_barrier(0);

        bf16x8 ar[MR], ai[MR], an[MR];
#pragma unroll
        for (int mt = 0; mt < MR; ++mt) {
            const int rr = wm + mt * 16 + lr;
            const int slr = lg ^ (rr & 7);
            const int sli = (4 + lg) ^ (rr & 7);
            ar[mt] = *(const bf16x8*)(&sA[buf][rr][slr * 8]);
            ai[mt] = *(const bf16x8*)(&sA[buf][rr][sli * 8]);
            an[mt] = bneg8(ai[mt]);
        }
        __builtin_amdgcn_s_setprio(1);
#pragma unroll
        for (int nt = 0; nt < NR; ++nt) {
            const int rr = wn + nt * 16 + lr;
            const int slr = lg ^ (rr & 7);
            const int sli = (4 + lg) ^ (rr & 7);
            const bf16x8 br8 = *(const bf16x8*)(&sB[buf][rr][slr * 8]);
            const bf16x8 bi8 = *(const bf16x8*)(&sB[buf][rr][sli * 8]);
#pragma unroll
            for (int mt = 0; mt < MR; ++mt) {
                accr[mt][nt] = MFMA16(ar[mt], br8, accr[mt][nt]);
                accr[mt][nt] = MFMA16(an[mt], bi8, accr[mt][nt]);
                acci[mt][nt] = MFMA16(ar[mt], bi8, acci[mt][nt]);
                acci[mt][nt] = MFMA16(ai[mt], br8, acci[mt][nt]);
            }
        }
        __builtin_amdgcn_s_setprio(0);
    }

#pragma unroll
    for (int nt = 0; nt < NR; ++nt) {
        const int col = col0 + wn + nt * 16 + lr;
        const float bre = (MODE == 4) ? 0.0f : br[col];
        const float bie = (MODE == 4) ? 0.0f : bi[col];
#pragma unroll
        for (int mt = 0; mt < MR; ++mt) {
#pragma unroll
            for (int j = 0; j < 4; ++j) {
                const int row = row0 + wm + mt * 16 + lg * 4 + j;
                float vr = accr[mt][nt][j];
                float vi = acci[mt][nt][j];
                if (MODE == 4) {
                    vr += br[row];
                    vi += bi[row];
                } else {
                    vr += bre;
                    vi += bie;
                }
                const size_t o = (size_t)row * N + col;
                if (MODE == 0 || MODE == 4) {
                    outBr[o] = (bf16)vr;
                    outBi[o] = (bf16)vi;
                } else if (MODE == 1) {
                    const float2 rv = ((const float2*)resr)[(size_t)row * 768 + col];
                    outBr[o] = (bf16)(rv.x + vr);
                    outBi[o] = (bf16)(rv.y + vi);
                } else if (MODE == 2) {
                    // fast tanh-GELU
                    const float t2r = fmaf(vr * vr, 0.044715f, 1.0f);
                    const float er = __builtin_amdgcn_exp2f(vr * t2r * 2.3022082f);
                    vr = vr - vr * __builtin_amdgcn_rcpf(er + 1.0f);
                    const float t2i = fmaf(vi * vi, 0.044715f, 1.0f);
                    const float ei = __builtin_amdgcn_exp2f(vi * t2i * 2.3022082f);
                    vi = vi - vi * __builtin_amdgcn_rcpf(ei + 1.0f);
                    outBr[o] = (bf16)vr;
                    outBi[o] = (bf16)vi;
                } else {
                    const size_t ro = (size_t)row * 768 + col;
                    outFr[(size_t)row * 1536 + 2 * col] =
                        (float)((const bf16*)resr)[ro] + vr;
                    outFr[(size_t)row * 1536 + 2 * col + 1] =
                        (float)((const bf16*)resi)[ro] + vi;
                }
            }
        }
    }
}

// ---------------------------------------------------------------------------
// fused complex flash attention v11 (unchanged from R14: 88.5 us, passed)
// ---------------------------------------------------------------------------
__global__ __launch_bounds__(256, 3) void cattn_kernel(
    const bf16* __restrict__ qkr, const bf16* __restrict__ qki,
    const bf16* __restrict__ vtr, const bf16* __restrict__ vti,
    bf16* __restrict__ aor, bf16* __restrict__ aoi) {
    __shared__ __align__(16) bf16 sK[2][2][32][64];
    __shared__ __align__(16) bf16 sV[3][64][64];
    __shared__ __align__(16) bf16 sP[4][16][40];

    const int tid = threadIdx.x;
    const int w = tid >> 6, lane = tid & 63;
    const int lg = lane >> 4, lr = lane & 15;

    const int bid = blockIdx.x;
    const int xcd = bid & 7;
    const int i = bid >> 3;
    const int grp = xcd * 3 + (i >> 5);
    const int qb = i & 31;
    const int h = grp % 12, b = grp / 12;
    const int ld = 1536;

    const int s_krow = lane >> 3;
    const int s_kch8 = ((lane & 7) ^ s_krow) * 8;
    const int s_vlog = (lane & 7) ^ s_krow;
    const int s_vpl = s_vlog >> 2;
    const int s_vk8 = (s_vlog & 3) * 8;

    const bf16* kbase0 = qkr + (size_t)b * 2048 * ld + 768 + h * 64;
    const bf16* kbase1 = qki + (size_t)b * 2048 * ld + 768 + h * 64;
    const bf16* vbase = (s_vpl ? vti : vtr) + (size_t)(h * 64) * 4096 + b * 2048;

    const bf16* kp0 = kbase0 + (size_t)(w * 8 + s_krow) * ld + s_kch8;
    const bf16* kp1 = kbase1 + (size_t)(w * 8 + s_krow) * ld + s_kch8;
    const bf16* vp0 = vbase + (size_t)(w * 8 + s_krow) * 4096 + s_vk8;
    const bf16* vp1 = vbase + (size_t)((4 + w) * 8 + s_krow) * 4096 + s_vk8;

    auto stage = [&](int kb, int vs) {
        gl_lds16(kp0, &sK[kb][0][w * 8][0]);
        gl_lds16(kp1, &sK[kb][1][w * 8][0]);
        gl_lds16(vp0, &sV[vs][w * 8][0]);
        gl_lds16(vp1, &sV[vs][(4 + w) * 8][0]);
        kp0 += 32 * ld;
        kp1 += 32 * ld;
        vp0 += 32;
        vp1 += 32;
    };

    stage(0, 0);

    const size_t qoff = (size_t)(b * 2048 + qb * 64 + w * 16 + lr) * ld + h * 64;
    bf16x8 aqr[2], aqi[2], aqin[2];
#pragma unroll
    for (int ks = 0; ks < 2; ++ks) {
        aqr[ks] = *(const bf16x8*)(qkr + qoff + ks * 32 + lg * 8);
        aqi[ks] = *(const bf16x8*)(qki + qoff + ks * 32 + lg * 8);
        aqin[ks] = bneg8(aqi[ks]);
    }

    f32x4 our[4], oui[4];
#pragma unroll
    for (int d = 0; d < 4; ++d) {
        our[d] = zero4();
        oui[d] = zero4();
    }
    const float C1 = 0.125f * LOG2E;
    float mrun = -1e30f;
    float lrun_p = 0.0f;
    float thr2 = -1.0f;
    float mC2 = 0.0f;

    bf16x8 pfPrev = __builtin_bit_cast(bf16x8, u32x4{0u, 0u, 0u, 0u});
    int vcur = 0, vlast = 0;
    const int slr = lg ^ (lr & 7);
    const int sli = (4 + lg) ^ (lr & 7);

    for (int kt = 0; kt < 64; ++kt) {
        const int kcur = kt & 1;
        int vnext = vcur + 1;
        if (vnext == 3) vnext = 0;
        if (kt < 63) {
            stage(kcur ^ 1, vnext);
            __builtin_amdgcn_sched_barrier(0);
            asm volatile("s_waitcnt vmcnt(4)" ::: "memory");
        } else {
            asm volatile("s_waitcnt vmcnt(0)" ::: "memory");
        }
        __builtin_amdgcn_sched_barrier(0);
        __builtin_amdgcn_s_barrier();
        __builtin_amdgcn_sched_barrier(0);

        // ---- QK^T(kt) + PV(kt-1) ----
        f32x4 str[2], sti[2];
        str[0] = zero4(); str[1] = zero4();
        sti[0] = zero4(); sti[1] = zero4();
        __builtin_amdgcn_s_setprio(1);
#pragma unroll
        for (int t = 0; t < 2; ++t) {
#pragma unroll
            for (int ks = 0; ks < 2; ++ks) {
                const int ch = ((ks << 2) | lg) ^ (lr & 7);
                const bf16x8 kr8 = *(const bf16x8*)(&sK[kcur][0][t * 16 + lr][ch * 8]);
                const bf16x8 ki8 = *(const bf16x8*)(&sK[kcur][1][t * 16 + lr][ch * 8]);
                str[t] = MFMA16(kr8, aqr[ks], str[t]);
                str[t] = MFMA16(ki8, aqi[ks], str[t]);
                sti[t] = MFMA16(ki8, aqr[ks], sti[t]);
                sti[t] = MFMA16(kr8, aqin[ks], sti[t]);
            }
        }
        if (kt > 0) {
#pragma unroll
            for (int d = 0; d < 4; ++d) {
                const bf16x8 vr8 = *(const bf16x8*)(&sV[vlast][d * 16 + lr][slr * 8]);
                const bf16x8 vi8 = *(const bf16x8*)(&sV[vlast][d * 16 + lr][sli * 8]);
                our[d] = MFMA16(pfPrev, vr8, our[d]);
                oui[d] = MFMA16(pfPrev, vi8, oui[d]);
            }
        }
        __builtin_amdgcn_s_setprio(0);

        // ---- squared magnitudes; per-lane max only ----
        float v[8];
        float vmax = 0.0f;
#pragma unroll
        for (int t = 0; t < 2; ++t)
#pragma unroll
            for (int j = 0; j < 4; ++j) {
                const float sr = str[t][j], si = sti[t][j];
                const float vv = fmaf(sr, sr, fmaf(si, si, 1e-8f));
                v[t * 4 + j] = vv;
                vmax = fmaxf(vmax, vv);
            }

        if (!__all(vmax <= thr2)) {
            vmax = fmaxf(vmax, __shfl_xor(vmax, 16));
            vmax = fmaxf(vmax, __shfl_xor(vmax, 32));
            const float tm = __builtin_amdgcn_sqrtf(vmax) * 0.125f;
            const float mnew = fmaxf(mrun, tm);
            const float corr = __builtin_amdgcn_exp2f((mrun - mnew) * LOG2E);
            float cj[4];
#pragma unroll
            for (int j = 0; j < 4; ++j) cj[j] = __shfl(corr, lg * 4 + j);
#pragma unroll
            for (int d = 0; d < 4; ++d)
#pragma unroll
                for (int j = 0; j < 4; ++j) {
                    our[d][j] *= cj[j];
                    oui[d][j] *= cj[j];
                }
            lrun_p *= corr;
            mrun = mnew;
            const float m8 = mrun + 8.0f;
            thr2 = 64.0f * m8 * m8;
            mC2 = -mrun * LOG2E;
        }

        float p[8];
        float ls = 0.0f;
#pragma unroll
        for (int i2 = 0; i2 < 8; ++i2) {
            p[i2] = __builtin_amdgcn_exp2f(
                fmaf(__builtin_amdgcn_sqrtf(v[i2]), C1, mC2));
            ls += p[i2];
        }
        lrun_p += ls;

        // ---- pack P(kt) -> LDS -> pfPrev ----
#pragma unroll
        for (int t = 0; t < 2; ++t) {
            bf16x4 pk;
#pragma unroll
            for (int j = 0; j < 4; ++j) pk[j] = (bf16)p[t * 4 + j];
            *(bf16x4*)(&sP[w][lr][t * 16 + lg * 4]) = pk;
        }
        pfPrev = *(const bf16x8*)(&sP[w][lr][lg * 8]);

        vlast = vcur;
        vcur = vnext;
    }

    // final PV for tile 63
#pragma unroll
    for (int d = 0; d < 4; ++d) {
        const bf16x8 vr8 = *(const bf16x8*)(&sV[vlast][d * 16 + lr][slr * 8]);
        const bf16x8 vi8 = *(const bf16x8*)(&sV[vlast][d * 16 + lr][sli * 8]);
        our[d] = MFMA16(pfPrev, vr8, our[d]);
        oui[d] = MFMA16(pfPrev, vi8, oui[d]);
    }

    float lsum = lrun_p;
    lsum += __shfl_xor(lsum, 16);
    lsum += __shfl_xor(lsum, 32);

    float linv[4];
#pragma unroll
    for (int j = 0; j < 4; ++j) {
        const float lj = __shfl(lsum, lg * 4 + j);
        linv[j] = __builtin_amdgcn_rcpf(lj);
    }
#pragma unroll
    for (int d = 0; d < 4; ++d)
#pragma unroll
        for (int j = 0; j < 4; ++j) {
            const int row = b * 2048 + qb * 64 + w * 16 + lg * 4 + j;
            const int col = h * 64 + d * 16 + lr;
            aor[(size_t)row * 768 + col] = (bf16)(our[d][j] * linv[j]);
            aoi[(size_t)row * 768 + col] = (bf16)(oui[d][j] * linv[j]);
        }
}

// ---------------------------------------------------------------------------
// host launch
// ---------------------------------------------------------------------------
extern "C" void kernel_launch(void* const* d_in, const int* in_sizes, int n_in,
                              void* d_out, int out_size, void* d_ws, size_t ws_size,
                              hipStream_t stream) {
    const float* x      = (const float*)d_in[0];
    const float* n1g    = (const float*)d_in[1];
    const float* n1b    = (const float*)d_in[2];
    const float* qkvwr  = (const float*)d_in[3];
    const float* qkvwi  = (const float*)d_in[4];
    const float* qkvbr  = (const float*)d_in[5];
    const float* qkvbi  = (const float*)d_in[6];
    const float* projwr = (const float*)d_in[7];
    const float* projwi = (const float*)d_in[8];
    const float* projbr = (const float*)d_in[9];
    const float* projbi = (const float*)d_in[10];
    const float* n2g    = (const float*)d_in[11];
    const float* n2b    = (const float*)d_in[12];
    const float* fc1wr  = (const float*)d_in[13];
    const float* fc1wi  = (const float*)d_in[14];
    const float* fc1br  = (const float*)d_in[15];
    const float* fc1bi  = (const float*)d_in[16];
    const float* fc2wr  = (const float*)d_in[17];
    const float* fc2wi  = (const float*)d_in[18];
    const float* fc2br  = (const float*)d_in[19];
    const float* fc2bi  = (const float*)d_in[20];

    const int M = 4096, E = 768, E3 = 2304, HH = 1536;

    char* base = (char*)d_ws;
    size_t off = 0;
    auto alloc = [&](size_t bytes) -> void* {
        void* p = base + off;
        off += (bytes + 255) & ~(size_t)255;
        return p;
    };
    bf16* xr2  = (bf16*)alloc((size_t)M * E * 2);   // bf16 residual planes
    bf16* xi2  = (bf16*)alloc((size_t)M * E * 2);
    bf16* nr   = (bf16*)alloc((size_t)M * E * 2);
    bf16* ni   = (bf16*)alloc((size_t)M * E * 2);
    bf16* wqr  = (bf16*)alloc((size_t)E3 * E * 2);
    bf16* wqi  = (bf16*)alloc((size_t)E3 * E * 2);
    bf16* wpr  = (bf16*)alloc((size_t)E * E * 2);
    bf16* wpi  = (bf16*)alloc((size_t)E * E * 2);
    bf16* w1r  = (bf16*)alloc((size_t)HH * E * 2);
    bf16* w1i  = (bf16*)alloc((size_t)HH * E * 2);
    bf16* w2r  = (bf16*)alloc((size_t)E * HH * 2);
    bf16* w2i  = (bf16*)alloc((size_t)E * HH * 2);
    bf16* qkr  = (bf16*)alloc((size_t)M * HH * 2);
    bf16* qki  = (bf16*)alloc((size_t)M * HH * 2);
    bf16* vtr  = (bf16*)alloc((size_t)E * M * 2);
    bf16* vti  = (bf16*)alloc((size_t)E * M * 2);
    bf16* aor  = (bf16*)alloc((size_t)M * E * 2);
    bf16* aoi  = (bf16*)alloc((size_t)M * E * 2);
    bf16* hr   = (bf16*)alloc((size_t)M * HH * 2);
    bf16* hi   = (bf16*)alloc((size_t)M * HH * 2);

    if (off > ws_size) {
        fill_kernel<<<1024, 256, 0, stream>>>((float*)d_out, 1.0e9f, out_size);
        return;
    }

    // fused weight conversion
    Cvt8 c;
    c.s[0] = qkvwr; c.d[0] = wqr;
    c.s[1] = qkvwi; c.d[1] = wqi;
    c.s[2] = projwr; c.d[2] = wpr;
    c.s[3] = projwi; c.d[3] = wpi;
    c.s[4] = fc1wr; c.d[4] = w1r;
    c.s[5] = fc1wi; c.d[5] = w1i;
    c.s[6] = fc2wr; c.d[6] = w2r;
    c.s[7] = fc2wi; c.d[7] = w2i;
    const int nseg[8] = {E3 * E, E3 * E, E * E, E * E, HH * E, HH * E, E * HH, E * HH};
    int cum = 0;
    for (int k = 0; k < 8; ++k) {
        c.boff[k] = cum;
        cum += nseg[k] / 1024;
    }
    c.boff[8] = cum;
    cvt8_kernel<<<cum, 256, 0, stream>>>(c);

    // LN1 (reads interleaved x directly)
    cln_kernel<1><<<M, 256, 0, stream>>>(x, nullptr, n1g, n1b, nr, ni);
    // QK GEMM: 64x128, grid 768 = 3/CU; XCD owns 8 row-blocks
    cgemm_kernel<64, 128, 0, 3, false><<<dim3(64, 12), 256, 0, stream>>>(
        nr, ni, wqr, wqi, qkvbr, qkvbi, nullptr, nullptr, nullptr, nullptr,
        qkr, qki, HH, E);
    // V^T GEMM: 64x128, grid 384; XCD owns 4 col-blocks
    cgemm_kernel<64, 128, 4, 3, true><<<dim3(12, 32), 256, 0, stream>>>(
        wqr + (size_t)HH * E, wqi + (size_t)HH * E, nr, ni,
        qkvbr + HH, qkvbi + HH, nullptr, nullptr, nullptr, nullptr,
        vtr, vti, M, E);
    // attention: 1D grid 768; per-XCD (h,b) grouping for K/V L2 residency
    cattn_kernel<<<768, 256, 0, stream>>>(qkr, qki, vtr, vti, aor, aoi);
    // proj + interleaved-x residual -> bf16 planes: 128x64, grid 384
    cgemm_kernel<128, 64, 1, 3, false><<<dim3(32, 12), 256, 0, stream>>>(
        aor, aoi, wpr, wpi, projbr, projbi, x, nullptr, nullptr, nullptr,
        xr2, xi2, E, E);
    // LN2 (reads bf16 residual planes)
    cln_kernel<2><<<M, 256, 0, stream>>>(xr2, xi2, n2g, n2b, nr, ni);
    // FC1 + fast GELU: 64x128, grid 768; XCD owns 8 row-blocks
    cgemm_kernel<64, 128, 2, 3, false><<<dim3(64, 12), 256, 0, stream>>>(
        nr, ni, w1r, w1i, fc1br, fc1bi, nullptr, nullptr, nullptr, nullptr,
        hr, hi, HH, E);
    // FC2 + bf16-res -> interleaved f32 d_out: 128x64, grid 384
    cgemm_kernel<128, 64, 3, 3, false><<<dim3(32, 12), 256, 0, stream>>>(
        hr, hi, w2r, w2i, fc2br, fc2bi, xr2, xi2, (float*)d_out, nullptr,
        nullptr, nullptr, E, HH);
}